// Round 5
// baseline (1047.642 us; speedup 1.0000x reference)
//
#include <hip/hip_runtime.h>

#define B_   2
#define S_   1024
#define D_   4096
#define HQ_  32
#define HKV_ 8
#define HD_  128
#define SCALE_ 0.08838834764831845f

typedef unsigned short u16;
typedef __attribute__((ext_vector_type(8))) short s16x8;
typedef __attribute__((ext_vector_type(4))) short s16x4;
typedef __attribute__((ext_vector_type(4))) float f32x4;

#define MFMA(a,b,c) __builtin_amdgcn_mfma_f32_16x16x32_bf16((a),(b),(c),0,0,0)

__device__ __forceinline__ u16 bf16_rne(float x) {
  unsigned u = __float_as_uint(x);
  u += 0x7fffu + ((u >> 16) & 1u);
  return (u16)(u >> 16);
}
__device__ __forceinline__ float bf16_up(u16 h) {
  return __uint_as_float(((unsigned)h) << 16);
}
__device__ __forceinline__ void split2(float x, u16& h, u16& l) {
  h = bf16_rne(x);
  l = bf16_rne(x - bf16_up(h));
}

// packed hi/lo split: 2 elems -> 1 u32 hi + 1 u32 lo
__device__ __forceinline__ void cvt_hi_lo(float a, float b, unsigned& hi, unsigned& lo) {
  unsigned h, l;
  asm("v_cvt_pk_bf16_f32 %0, %1, %2" : "=v"(h) : "v"(a), "v"(b));
  float ra = __uint_as_float(h << 16);
  float rb = __uint_as_float(h & 0xffff0000u);
  float la = a - ra, lb = b - rb;
  asm("v_cvt_pk_bf16_f32 %0, %1, %2" : "=v"(l) : "v"(la), "v"(lb));
  hi = h; lo = l;
}
__device__ __forceinline__ void pack8(float4 x, float4 y, uint4& h, uint4& l) {
  unsigned h0,h1,h2,h3,l0,l1,l2,l3;
  cvt_hi_lo(x.x, x.y, h0, l0);
  cvt_hi_lo(x.z, x.w, h1, l1);
  cvt_hi_lo(y.x, y.y, h2, l2);
  cvt_hi_lo(y.z, y.w, h3, l3);
  h = make_uint4(h0,h1,h2,h3); l = make_uint4(l0,l1,l2,l3);
}

// ---- async global->LDS, 16B per lane (dest = wave-uniform base) ----
typedef const __attribute__((address_space(1))) void* gas_ptr;
typedef __attribute__((address_space(3))) void* las_ptr;
__device__ __forceinline__ void gload_lds16(const void* g, void* l) {
  __builtin_amdgcn_global_load_lds((gas_ptr)g, (las_ptr)l, 16, 0, 0);
}

// ===========================================================================
// frag_b: weights (K x N fp32) -> transposed fragment-ordered hi/lo planes,
// over a column chunk [n0, n0 + Nc16*16).
// ===========================================================================
__global__ __launch_bounds__(256) void frag_b(
    const float* __restrict__ W, u16* __restrict__ dh, u16* __restrict__ dl,
    int N, int n0, int Nc16)
{
  __shared__ float T[32][68];
  const int kt = blockIdx.x, nbk = blockIdx.y;
  const int tid = threadIdx.x;
#pragma unroll
  for (int rep = 0; rep < 2; ++rep) {
    int idx = tid + rep * 256;
    int row = idx >> 4, c4 = (idx & 15) * 4;
    float4 v = *reinterpret_cast<const float4*>(&W[(size_t)(kt*32 + row) * N + n0 + nbk*64 + c4]);
    *reinterpret_cast<float4*>(&T[row][c4]) = v;
  }
  __syncthreads();
  const size_t base = ((size_t)kt * Nc16 + nbk * 4) * 512;
  int c = tid;
  int nt = c >> 6, l = c & 63, kc = l >> 4, r = l & 15;
  u16 hh[8], ll[8];
#pragma unroll
  for (int j = 0; j < 8; ++j) split2(T[kc*8 + j][nt*16 + r], hh[j], ll[j]);
  *reinterpret_cast<s16x8*>(&dh[base + (size_t)c * 8]) =
    (s16x8){(short)hh[0],(short)hh[1],(short)hh[2],(short)hh[3],
            (short)hh[4],(short)hh[5],(short)hh[6],(short)hh[7]};
  *reinterpret_cast<s16x8*>(&dl[base + (size_t)c * 8]) =
    (s16x8){(short)ll[0],(short)ll[1],(short)ll[2],(short)ll[3],
            (short)ll[4],(short)ll[5],(short)ll[6],(short)ll[7]};
}

// ===========================================================================
// frag_kv: post-RoPE K and V (b,s,8,128 fp32) -> fragment-ordered hi/lo planes.
// K plane (B-operand of QK^T): per (bkvh): [st=s>>4][dt=d>>5][512],
//   l = ((d&31)>>3)*16 + (s&15), j = d&7.
// V plane (B-operand of PV):   per (bkvh): [kkt=s>>5][dt16=d>>4][512],
//   l = ((s&31)>>3)*16 + (d&15), j = s&7.
// grid 1024 x 256thr: blocks 0..511 = K (bkvh*32+sc), 512..1023 = V.
// ===========================================================================
__global__ __launch_bounds__(256) void frag_kv(
    const float* __restrict__ kb, const float* __restrict__ vb,
    u16* __restrict__ KFh, u16* __restrict__ KFl,
    u16* __restrict__ VFh, u16* __restrict__ VFl)
{
  __shared__ float T[32][132];
  const int bid  = blockIdx.x;
  const int isV  = bid >> 9;
  const int bkvh = (bid >> 5) & 15;
  const int chnk = bid & 31;            // 32-row chunk
  const int tid  = threadIdx.x;
  const int b    = bkvh >> 3, kvh = bkvh & 7;

  const float* src = isV ? vb : kb;
  // load 32 rows x 128 d
  {
    int r0 = tid >> 5, c4 = (tid & 31) * 4;
#pragma unroll
    for (int it = 0; it < 4; ++it) {
      int row = r0 + it * 8;
      float4 v = *reinterpret_cast<const float4*>(
        &src[(((size_t)(b * S_ + chnk*32 + row)) * HKV_ + kvh) * HD_ + c4]);
      *reinterpret_cast<float4*>(&T[row][c4]) = v;
    }
  }
  __syncthreads();
#pragma unroll
  for (int rep = 0; rep < 2; ++rep) {
    int c2 = tid + rep * 256;            // 0..511
    int l = c2 & 63;
    u16 hh[8], ll[8];
    if (!isV) {
      int f = c2 >> 6, st_loc = f >> 2, dt = f & 3;
#pragma unroll
      for (int j = 0; j < 8; ++j)
        split2(T[st_loc*16 + (l & 15)][dt*32 + (l >> 4)*8 + j], hh[j], ll[j]);
      size_t off = ((size_t)bkvh*64 + chnk*2) * 2048 + (size_t)c2 * 8;
      *reinterpret_cast<s16x8*>(&KFh[off]) =
        (s16x8){(short)hh[0],(short)hh[1],(short)hh[2],(short)hh[3],
                (short)hh[4],(short)hh[5],(short)hh[6],(short)hh[7]};
      *reinterpret_cast<s16x8*>(&KFl[off]) =
        (s16x8){(short)ll[0],(short)ll[1],(short)ll[2],(short)ll[3],
                (short)ll[4],(short)ll[5],(short)ll[6],(short)ll[7]};
    } else {
      int dt16 = c2 >> 6;
#pragma unroll
      for (int j = 0; j < 8; ++j)
        split2(T[(l >> 4)*8 + j][dt16*16 + (l & 15)], hh[j], ll[j]);
      size_t off = ((size_t)bkvh*32 + chnk) * 4096 + (size_t)c2 * 8;
      *reinterpret_cast<s16x8*>(&VFh[off]) =
        (s16x8){(short)hh[0],(short)hh[1],(short)hh[2],(short)hh[3],
                (short)hh[4],(short)hh[5],(short)hh[6],(short)hh[7]};
      *reinterpret_cast<s16x8*>(&VFl[off]) =
        (s16x8){(short)ll[0],(short)ll[1],(short)ll[2],(short)ll[3],
                (short)ll[4],(short)ll[5],(short)ll[6],(short)ll[7]};
    }
  }
}

// ===========================================================================
// attn2: flash attention reading K/V fragments direct global->register
// (L2-resident, coalesced lane*16). No block barriers; P per-wave LDS only.
// grid (8 qtiles, 64 b*h), 512 thr = 8 waves, 16 q-rows/wave.
// ===========================================================================
#define PSTR 68
__global__ __launch_bounds__(512) void attn2(
    const float* __restrict__ qb,
    const u16* __restrict__ KFh, const u16* __restrict__ KFl,
    const u16* __restrict__ VFh, const u16* __restrict__ VFl,
    float* __restrict__ ob)
{
  __shared__ u16 Ph[8][16][PSTR], Pl[8][16][PSTR];

  const int tid  = threadIdx.x;
  const int lane = tid & 63;
  const int wid  = tid >> 6;
  const int lr   = lane & 15;
  const int lg   = lane >> 4;
  const int qt   = blockIdx.x;
  const int bh   = blockIdx.y;
  const int b    = bh >> 5, h = bh & 31;
  const int bkvh = b * 8 + (h >> 2);

  // ---- Q rows -> A-fragments (hi/lo), split once ----
  s16x8 qh[4], ql[4];
  {
    const int qrow = qt * 128 + wid * 16 + lr;
    const float* qp = qb + ((size_t)((b * S_ + qrow) * HQ_ + h)) * HD_;
#pragma unroll
    for (int kc = 0; kc < 4; ++kc) {
      const float* qp2 = qp + kc * 32 + lg * 8;
      float4 v0 = *reinterpret_cast<const float4*>(qp2);
      float4 v1 = *reinterpret_cast<const float4*>(qp2 + 4);
      uint4 h4, l4; pack8(v0, v1, h4, l4);
      qh[kc] = *reinterpret_cast<s16x8*>(&h4);
      ql[kc] = *reinterpret_cast<s16x8*>(&l4);
    }
  }

  f32x4 acc_o[8];
#pragma unroll
  for (int df = 0; df < 8; ++df) acc_o[df] = (f32x4){0.f, 0.f, 0.f, 0.f};
  float m_run[4] = {-1e30f, -1e30f, -1e30f, -1e30f};
  float l_run[4] = {0.f, 0.f, 0.f, 0.f};

  const u16* pkh = KFh + (size_t)bkvh * 131072 + lane * 8;  // 64*2048
  const u16* pkl = KFl + (size_t)bkvh * 131072 + lane * 8;
  const u16* pvh = VFh + (size_t)bkvh * 131072 + lane * 8;  // 32*4096
  const u16* pvl = VFl + (size_t)bkvh * 131072 + lane * 8;

  for (int t = 0; t < S_ / 64; ++t) {
    const size_t kbase = (size_t)t * 8192;   // t*4 st * 2048
    const size_t vbase = (size_t)t * 8192;   // t*2 kkt * 4096

    // ---- QK^T: 16 x 64, B-frags direct from global (L2) ----
    f32x4 accs[4];
#pragma unroll
    for (int nf = 0; nf < 4; ++nf) {
      accs[nf] = (f32x4){0.f, 0.f, 0.f, 0.f};
      s16x8 kh8[4], kl8[4];
#pragma unroll
      for (int kc = 0; kc < 4; ++kc) {
        kh8[kc] = *reinterpret_cast<const s16x8*>(pkh + kbase + nf*2048 + kc*512);
        kl8[kc] = *reinterpret_cast<const s16x8*>(pkl + kbase + nf*2048 + kc*512);
      }
#pragma unroll
      for (int kc = 0; kc < 4; ++kc) {
        accs[nf] = MFMA(qh[kc], kh8[kc], accs[nf]);
        accs[nf] = MFMA(ql[kc], kh8[kc], accs[nf]);
        accs[nf] = MFMA(qh[kc], kl8[kc], accs[nf]);
      }
    }
#pragma unroll
    for (int nf = 0; nf < 4; ++nf) accs[nf] *= SCALE_;

    // ---- online softmax ----
    float corr[4], rsum[4];
#pragma unroll
    for (int r = 0; r < 4; ++r) {
      float t0 = fmaxf(fmaxf(accs[0][r], accs[1][r]), fmaxf(accs[2][r], accs[3][r]));
      t0 = fmaxf(t0, __shfl_xor(t0, 1));
      t0 = fmaxf(t0, __shfl_xor(t0, 2));
      t0 = fmaxf(t0, __shfl_xor(t0, 4));
      t0 = fmaxf(t0, __shfl_xor(t0, 8));
      float mnew = fmaxf(m_run[r], t0);
      corr[r] = __expf(m_run[r] - mnew);
      m_run[r] = mnew;
      rsum[r] = 0.f;
    }
#pragma unroll
    for (int nf = 0; nf < 4; ++nf)
#pragma unroll
      for (int r = 0; r < 4; ++r) {
        float p = __expf(accs[nf][r] - m_run[r]);
        rsum[r] += p;
        u16 ph, pl;
        split2(p, ph, pl);
        Ph[wid][lg*4 + r][nf*16 + lr] = ph;
        Pl[wid][lg*4 + r][nf*16 + lr] = pl;
      }
#pragma unroll
    for (int r = 0; r < 4; ++r) {
      float s = rsum[r];
      s += __shfl_xor(s, 1); s += __shfl_xor(s, 2);
      s += __shfl_xor(s, 4); s += __shfl_xor(s, 8);
      l_run[r] = l_run[r] * corr[r] + s;
    }
#pragma unroll
    for (int df = 0; df < 8; ++df)
#pragma unroll
      for (int r = 0; r < 4; ++r) acc_o[df][r] *= corr[r];

    // ---- PV: A = P (per-wave LDS), B = V frags direct from global ----
    s16x8 pa_h[2], pa_l[2];
#pragma unroll
    for (int kc = 0; kc < 2; ++kc) {
      pa_h[kc] = *reinterpret_cast<const s16x8*>(&Ph[wid][lr][kc*32 + lg*8]);
      pa_l[kc] = *reinterpret_cast<const s16x8*>(&Pl[wid][lr][kc*32 + lg*8]);
    }
#pragma unroll
    for (int df = 0; df < 8; ++df) {
      s16x8 vh8[2], vl8[2];
#pragma unroll
      for (int kc = 0; kc < 2; ++kc) {
        vh8[kc] = *reinterpret_cast<const s16x8*>(pvh + vbase + kc*4096 + df*512);
        vl8[kc] = *reinterpret_cast<const s16x8*>(pvl + vbase + kc*4096 + df*512);
      }
#pragma unroll
      for (int kc = 0; kc < 2; ++kc) {
        acc_o[df] = MFMA(pa_h[kc], vh8[kc], acc_o[df]);
        acc_o[df] = MFMA(pa_l[kc], vh8[kc], acc_o[df]);
        acc_o[df] = MFMA(pa_h[kc], vl8[kc], acc_o[df]);
      }
    }
  }

  float inv_l[4];
#pragma unroll
  for (int r = 0; r < 4; ++r) inv_l[r] = 1.f / l_run[r];
#pragma unroll
  for (int df = 0; df < 8; ++df)
#pragma unroll
    for (int r = 0; r < 4; ++r) {
      int row = qt * 128 + wid * 16 + lg * 4 + r;
      ob[((size_t)((b * S_ + row) * HQ_ + h)) * HD_ + df*16 + lr] = acc_o[df][r] * inv_l[r];
    }
}

// ===========================================================================
// Hybrid GEMM (round-4 verified): A staged in-kernel, B pre-fragmented.
// ===========================================================================
__global__ __launch_bounds__(512) void gemm_p1(
    const float* __restrict__ X, const float* __restrict__ abp,
    const u16* __restrict__ WF,
    float* __restrict__ qb, float* __restrict__ kb, float* __restrict__ vb,
    float* __restrict__ outp, int mode, int col0)
{
  __shared__ __attribute__((aligned(16))) u16 lds[40960];
  u16* ah0 = lds;
  u16* al0 = lds + 4096;
  u16* ah1 = lds + 8192;
  u16* al1 = lds + 12288;
  u16* bh0 = lds + 16384;
  u16* bh1 = lds + 24576;
  u16* blb = lds + 32768;

  const int id   = blockIdx.x;
  const int cpx  = gridDim.x >> 3;
  const int swz  = (id & 7) * cpx + (id >> 3);

  const float* A; const u16* Bh; const u16* Bl; float* C;
  int ldc, Nc16, mb, nb;
  if (mode == 0) {
    if (swz < 128)      { A=X; Bh=WF;          Bl=WF+8388608;  C=qb; ldc=4096; Nc16=128; mb=swz>>3; nb=swz&7; }
    else if (swz < 192) { int u=swz-128; A=X; Bh=WF+16777216; Bl=WF+20971520; C=kb; ldc=1024; Nc16=64; mb=u>>2; nb=u&3; }
    else                { int u=swz-192; A=X; Bh=WF+25165824; Bl=WF+29360128; C=vb; ldc=1024; Nc16=64; mb=u>>2; nb=u&3; }
  } else if (mode == 1) {
    A=X; Bh=WF; Bl=WF+8388608; C=qb+col0; ldc=4096; Nc16=128; mb=swz>>3; nb=swz&7;
  } else if (mode == 2) {
    if (swz < 64) { A=X; Bh=WF;          Bl=WF+4194304;  C=kb; ldc=1024; Nc16=64; mb=swz>>2; nb=swz&3; }
    else          { int u=swz-64; A=X; Bh=WF+8388608; Bl=WF+12582912; C=vb; ldc=1024; Nc16=64; mb=u>>2; nb=u&3; }
  } else if (mode == 3) {
    A=abp; Bh=WF; Bl=WF+16777216; C=outp; ldc=4096; Nc16=256; mb=swz>>4; nb=swz&15;
  } else {
    A=abp; Bh=WF; Bl=WF+8388608; C=outp+col0; ldc=4096; Nc16=128; mb=swz>>3; nb=swz&7;
  }

  const int tid  = threadIdx.x;
  const int lane = tid & 63;
  const int wid  = tid >> 6;
  const int mtb  = (wid >> 2) * 4;
  const int ntb  = (wid & 3) * 4;
  const int loff = lane * 8;

  const int arow = tid >> 2;
  const int akc  = tid & 3;
  const float* aptr = A + (size_t)(mb*128 + arow) * 4096 + akc*8;
  const int awr = (arow >> 4)*512 + (akc*16 + (arow & 15))*8;

  const size_t bStep = (size_t)Nc16 * 512;
  const u16* pBh = Bh + (size_t)nb*16*512 + loff;
  const u16* pBl = Bl + (size_t)nb*16*512 + loff;

  f32x4 acc[4][4];
#pragma unroll
  for (int i = 0; i < 4; ++i)
#pragma unroll
    for (int j = 0; j < 4; ++j) acc[i][j] = (f32x4){0.f, 0.f, 0.f, 0.f};

  float4 ra0 = *reinterpret_cast<const float4*>(aptr);
  float4 ra1 = *reinterpret_cast<const float4*>(aptr + 4);
  {
    uint4 h4, l4; pack8(ra0, ra1, h4, l4);
    *reinterpret_cast<uint4*>(&ah0[awr]) = h4;
    *reinterpret_cast<uint4*>(&al0[awr]) = l4;
  }
  gload_lds16(pBh + (size_t)wid*512,     bh0 + wid*512);
  gload_lds16(pBh + (size_t)(wid+8)*512, bh0 + (wid+8)*512);
  ra0 = *reinterpret_cast<const float4*>(aptr + 32);
  ra1 = *reinterpret_cast<const float4*>(aptr + 36);
  __syncthreads();

  for (int kt = 0; kt < 128; ++kt) {
    u16* cAh = (kt & 1) ? ah1 : ah0;
    u16* cAl = (kt & 1) ? al1 : al0;
    u16* nAh = (kt & 1) ? ah0 : ah1;
    u16* nAl = (kt & 1) ? al0 : al1;
    u16* cBh = (kt & 1) ? bh1 : bh0;
    u16* nBh = (kt & 1) ? bh0 : bh1;

    gload_lds16(pBl + (size_t)kt*bStep + (size_t)wid*512,     blb + wid*512);
    gload_lds16(pBl + (size_t)kt*bStep + (size_t)(wid+8)*512, blb + (wid+8)*512);
    if (kt < 127) {
      gload_lds16(pBh + (size_t)(kt+1)*bStep + (size_t)wid*512,     nBh + wid*512);
      gload_lds16(pBh + (size_t)(kt+1)*bStep + (size_t)(wid+8)*512, nBh + (wid+8)*512);
    }
    s16x8 a_h[4], a_l[4], b_h[4];
#pragma unroll
    for (int mf = 0; mf < 4; ++mf) {
      a_h[mf] = *reinterpret_cast<const s16x8*>(&cAh[(mtb+mf)*512 + loff]);
      a_l[mf] = *reinterpret_cast<const s16x8*>(&cAl[(mtb+mf)*512 + loff]);
    }
#pragma unroll
    for (int nf = 0; nf < 4; ++nf)
      b_h[nf] = *reinterpret_cast<const s16x8*>(&cBh[(ntb+nf)*512 + loff]);
#pragma unroll
    for (int mf = 0; mf < 4; ++mf)
#pragma unroll
      for (int nf = 0; nf < 4; ++nf) {
        acc[mf][nf] = MFMA(a_h[mf], b_h[nf], acc[mf][nf]);
        acc[mf][nf] = MFMA(a_l[mf], b_h[nf], acc[mf][nf]);
      }
    __syncthreads();

    s16x8 b_l[4];
#pragma unroll
    for (int nf = 0; nf < 4; ++nf)
      b_l[nf] = *reinterpret_cast<const s16x8*>(&blb[(ntb+nf)*512 + loff]);
#pragma unroll
    for (int mf = 0; mf < 4; ++mf)
#pragma unroll
      for (int nf = 0; nf < 4; ++nf)
        acc[mf][nf] = MFMA(a_h[mf], b_l[nf], acc[mf][nf]);
    if (kt < 127) {
      uint4 h4, l4; pack8(ra0, ra1, h4, l4);
      *reinterpret_cast<uint4*>(&nAh[awr]) = h4;
      *reinterpret_cast<uint4*>(&nAl[awr]) = l4;
      if (kt < 126) {
        ra0 = *reinterpret_cast<const float4*>(aptr + (kt+2)*32);
        ra1 = *reinterpret_cast<const float4*>(aptr + (kt+2)*32 + 4);
      }
    }
    __syncthreads();
  }

  const int lr = lane & 15, lg = lane >> 4;
  const int row0 = mb*128 + (wid >> 2) * 64;
  const int nloc = nb*256 + (wid & 3) * 64;
#pragma unroll
  for (int mf = 0; mf < 4; ++mf)
#pragma unroll
    for (int nf = 0; nf < 4; ++nf)
#pragma unroll
      for (int r = 0; r < 4; ++r)
        C[(size_t)(row0 + mf*16 + lg*4 + r) * ldc + nloc + nf*16 + lr] = acc[mf][nf][r];
}

// ===========================================================================
// Fallback GEMM (round-1, proven) used only if ws < 112MB.
// ===========================================================================
__device__ __forceinline__ void gemm_core_128x256(
    const float* __restrict__ A, const float* __restrict__ W,
    float* __restrict__ C, int ldw, int m0, int n0)
{
  __shared__ u16 Ah[128][40];
  __shared__ u16 Al[128][40];
  __shared__ u16 Bh[256][40];
  __shared__ u16 Bl[256][40];

  const int tid  = threadIdx.x;
  const int lane = tid & 63;
  const int wid  = tid >> 6;
  const int wm   = (wid >> 2) * 64;
  const int wn   = (wid & 3) * 64;
  const int lr   = lane & 15;
  const int lg   = lane >> 4;

  f32x4 acc[4][4];
#pragma unroll
  for (int i = 0; i < 4; ++i)
#pragma unroll
    for (int j = 0; j < 4; ++j) acc[i][j] = (f32x4){0.f, 0.f, 0.f, 0.f};

  const int ar  = tid >> 3;
  const int ak  = (tid & 7) * 4;
  const int bn  = tid & 255;
  const int bk0 = (tid >> 8) * 16;

  for (int kt = 0; kt < D_ / 32; ++kt) {
    const int k0 = kt * 32;
    __syncthreads();
#pragma unroll
    for (int j = 0; j < 2; ++j) {
      int r = ar + 64 * j;
      float4 v = *reinterpret_cast<const float4*>(&A[(size_t)(m0 + r) * D_ + k0 + ak]);
      u16 h0,h1,h2,h3,l0,l1,l2,l3;
      split2(v.x,h0,l0); split2(v.y,h1,l1); split2(v.z,h2,l2); split2(v.w,h3,l3);
      *reinterpret_cast<s16x4*>(&Ah[r][ak]) = (s16x4){(short)h0,(short)h1,(short)h2,(short)h3};
      *reinterpret_cast<s16x4*>(&Al[r][ak]) = (s16x4){(short)l0,(short)l1,(short)l2,(short)l3};
    }
    {
      const float* wp = W + (size_t)(k0 + bk0) * ldw + (n0 + bn);
#pragma unroll
      for (int q = 0; q < 4; ++q) {
        float v0 = wp[(q*4 + 0) * (size_t)ldw];
        float v1 = wp[(q*4 + 1) * (size_t)ldw];
        float v2 = wp[(q*4 + 2) * (size_t)ldw];
        float v3 = wp[(q*4 + 3) * (size_t)ldw];
        u16 h0,h1,h2,h3,l0,l1,l2,l3;
        split2(v0,h0,l0); split2(v1,h1,l1); split2(v2,h2,l2); split2(v3,h3,l3);
        *reinterpret_cast<s16x4*>(&Bh[bn][bk0 + q*4]) = (s16x4){(short)h0,(short)h1,(short)h2,(short)h3};
        *reinterpret_cast<s16x4*>(&Bl[bn][bk0 + q*4]) = (s16x4){(short)l0,(short)l1,(short)l2,(short)l3};
      }
    }
    __syncthreads();
    s16x8 a_h[4], a_l[4], b_h[4], b_l[4];
#pragma unroll
    for (int mf = 0; mf < 4; ++mf) {
      a_h[mf] = *reinterpret_cast<const s16x8*>(&Ah[wm + mf*16 + lr][lg*8]);
      a_l[mf] = *reinterpret_cast<const s16x8*>(&Al[wm + mf*16 + lr][lg*8]);
    }
#pragma unroll
    for (int nf = 0; nf < 4; ++nf) {
      b_h[nf] = *reinterpret_cast<const s16x8*>(&Bh[wn + nf*16 + lr][lg*8]);
      b_l[nf] = *reinterpret_cast<const s16x8*>(&Bl[wn + nf*16 + lr][lg*8]);
    }
#pragma unroll
    for (int mf = 0; mf < 4; ++mf)
#pragma unroll
      for (int nf = 0; nf < 4; ++nf) {
        acc[mf][nf] = MFMA(a_h[mf], b_h[nf], acc[mf][nf]);
        acc[mf][nf] = MFMA(a_l[mf], b_h[nf], acc[mf][nf]);
        acc[mf][nf] = MFMA(a_h[mf], b_l[nf], acc[mf][nf]);
      }
  }
#pragma unroll
  for (int mf = 0; mf < 4; ++mf)
#pragma unroll
    for (int nf = 0; nf < 4; ++nf)
#pragma unroll
      for (int r = 0; r < 4; ++r) {
        int row = m0 + wm + mf*16 + lg*4 + r;
        int col = n0 + wn + nf*16 + lr;
        C[(size_t)row * ldw + col] = acc[mf][nf][r];
      }
}

__global__ __launch_bounds__(512) void gemm_qkv_kernel(
    const float* __restrict__ X,
    const float* __restrict__ Wq, const float* __restrict__ Wk,
    const float* __restrict__ Wv,
    float* __restrict__ qb, float* __restrict__ kb, float* __restrict__ vb)
{
  int nbv = blockIdx.x;
  int m0 = blockIdx.y * 128;
  const float* W; float* C; int ldw, n0;
  if (nbv < 16)      { W = Wq; C = qb; ldw = HQ_*HD_;  n0 = nbv * 256; }
  else if (nbv < 20) { W = Wk; C = kb; ldw = HKV_*HD_; n0 = (nbv-16) * 256; }
  else               { W = Wv; C = vb; ldw = HKV_*HD_; n0 = (nbv-20) * 256; }
  gemm_core_128x256(X, W, C, ldw, m0, n0);
}

__global__ __launch_bounds__(512) void gemm_out_kernel(
    const float* __restrict__ A, const float* __restrict__ Wo, float* __restrict__ out)
{
  gemm_core_128x256(A, Wo, out, D_, blockIdx.y * 128, blockIdx.x * 256);
}

// ---------------------------------------------------------------------------
// RoPE in-place on q (b,s,32,128) and k (b,s,8,128), fp32.
// ---------------------------------------------------------------------------
__global__ __launch_bounds__(256) void rope_kernel(
    float* __restrict__ qb, float* __restrict__ kb,
    const float* __restrict__ cosT, const float* __restrict__ sinT)
{
  int idx = blockIdx.x * 256 + threadIdx.x;
  const int nq = B_ * S_ * HQ_ * (HD_/2);
  const int nk = B_ * S_ * HKV_ * (HD_/2);
  if (idx < nq) {
    int j = idx & 63;
    int h = (idx >> 6) & (HQ_ - 1);
    int bs = idx >> 11;
    float* p = qb + ((size_t)bs * HQ_ + h) * HD_;
    const float* cp = cosT + (size_t)bs * HD_;
    const float* sp = sinT + (size_t)bs * HD_;
    float x1 = p[j], x2 = p[j + 64];
    p[j]      = x1 * cp[j]      - x2 * sp[j];
    p[j + 64] = x2 * cp[j + 64] + x1 * sp[j + 64];
  } else if (idx < nq + nk) {
    int t2 = idx - nq;
    int j = t2 & 63;
    int h = (t2 >> 6) & (HKV_ - 1);
    int bs = t2 >> 9;
    float* p = kb + ((size_t)bs * HKV_ + h) * HD_;
    const float* cp = cosT + (size_t)bs * HD_;
    const float* sp = sinT + (size_t)bs * HD_;
    float x1 = p[j], x2 = p[j + 64];
    p[j]      = x1 * cp[j]      - x2 * sp[j];
    p[j + 64] = x2 * cp[j + 64] + x1 * sp[j + 64];
  }
}

// ---------------------------------------------------------------------------
// Flash attention (round-1 verified) — fallback tier only.
// ---------------------------------------------------------------------------
__global__ __launch_bounds__(512) void attn_kernel(
    const float* __restrict__ qb, const float* __restrict__ kb,
    const float* __restrict__ vb, float* __restrict__ ob)
{
  __shared__ u16 Kh[64][136], Kl[64][136];
  __shared__ u16 Vh[128][72], Vl[128][72];
  __shared__ u16 Ph[8][16][72], Pl[8][16][72];

  const int tid  = threadIdx.x;
  const int lane = tid & 63;
  const int wid  = tid >> 6;
  const int lr   = lane & 15;
  const int lg   = lane >> 4;
  const int qt   = blockIdx.x;
  const int bh   = blockIdx.y;
  const int b    = bh >> 5, h = bh & 31, kvh = h >> 2;

  s16x8 qh[4], ql[4];
  {
    const int qrow = qt * 128 + wid * 16 + lr;
    const float* qp = qb + ((size_t)((b * S_ + qrow) * HQ_ + h)) * HD_;
#pragma unroll
    for (int kc = 0; kc < 4; ++kc) {
      const float* qp2 = qp + kc * 32 + lg * 8;
      float4 v0 = *reinterpret_cast<const float4*>(qp2);
      float4 v1 = *reinterpret_cast<const float4*>(qp2 + 4);
      u16 hh[8], ll[8];
      split2(v0.x,hh[0],ll[0]); split2(v0.y,hh[1],ll[1]);
      split2(v0.z,hh[2],ll[2]); split2(v0.w,hh[3],ll[3]);
      split2(v1.x,hh[4],ll[4]); split2(v1.y,hh[5],ll[5]);
      split2(v1.z,hh[6],ll[6]); split2(v1.w,hh[7],ll[7]);
      qh[kc] = (s16x8){(short)hh[0],(short)hh[1],(short)hh[2],(short)hh[3],
                       (short)hh[4],(short)hh[5],(short)hh[6],(short)hh[7]};
      ql[kc] = (s16x8){(short)ll[0],(short)ll[1],(short)ll[2],(short)ll[3],
                       (short)ll[4],(short)ll[5],(short)ll[6],(short)ll[7]};
    }
  }

  f32x4 acc_o[8];
#pragma unroll
  for (int df = 0; df < 8; ++df) acc_o[df] = (f32x4){0.f, 0.f, 0.f, 0.f};
  float m_run[4] = {-1e30f, -1e30f, -1e30f, -1e30f};
  float l_run[4] = {0.f, 0.f, 0.f, 0.f};

  const float* kbase = kb + ((size_t)(b * S_) * HKV_ + kvh) * HD_;
  const float* vbase = vb + ((size_t)(b * S_) * HKV_ + kvh) * HD_;

  for (int t = 0; t < S_ / 64; ++t) {
    const int kk0 = t * 64;
    __syncthreads();
#pragma unroll
    for (int j = 0; j < 4; ++j) {
      int idx = tid + 512 * j;
      int kk = idx >> 5, dq = (idx & 31) * 4;
      float4 v = *reinterpret_cast<const float4*>(kbase + (size_t)(kk0 + kk) * (HKV_*HD_) + dq);
      u16 h0,h1,h2,h3,l0,l1,l2,l3;
      split2(v.x,h0,l0); split2(v.y,h1,l1); split2(v.z,h2,l2); split2(v.w,h3,l3);
      *reinterpret_cast<s16x4*>(&Kh[kk][dq]) = (s16x4){(short)h0,(short)h1,(short)h2,(short)h3};
      *reinterpret_cast<s16x4*>(&Kl[kk][dq]) = (s16x4){(short)l0,(short)l1,(short)l2,(short)l3};
    }
    {
      int d = tid & 127;
      int kkb = (tid >> 7) * 16;
      const float* vcol = vbase + d;
#pragma unroll
      for (int jq = 0; jq < 4; ++jq) {
        u16 h4[4], l4[4];
#pragma unroll
        for (int e = 0; e < 4; ++e) {
          float val = vcol[(size_t)(kk0 + kkb + jq*4 + e) * (HKV_*HD_)];
          split2(val, h4[e], l4[e]);
        }
        *reinterpret_cast<s16x4*>(&Vh[d][kkb + jq*4]) = (s16x4){(short)h4[0],(short)h4[1],(short)h4[2],(short)h4[3]};
        *reinterpret_cast<s16x4*>(&Vl[d][kkb + jq*4]) = (s16x4){(short)l4[0],(short)l4[1],(short)l4[2],(short)l4[3]};
      }
    }
    __syncthreads();
    f32x4 accs[4];
#pragma unroll
    for (int nf = 0; nf < 4; ++nf) accs[nf] = (f32x4){0.f, 0.f, 0.f, 0.f};
#pragma unroll
    for (int nf = 0; nf < 4; ++nf) {
      int krow = nf * 16 + lr;
#pragma unroll
      for (int kc = 0; kc < 4; ++kc) {
        s16x8 kh8 = *reinterpret_cast<const s16x8*>(&Kh[krow][kc*32 + lg*8]);
        s16x8 kl8 = *reinterpret_cast<const s16x8*>(&Kl[krow][kc*32 + lg*8]);
        accs[nf] = MFMA(qh[kc], kh8, accs[nf]);
        accs[nf] = MFMA(ql[kc], kh8, accs[nf]);
        accs[nf] = MFMA(qh[kc], kl8, accs[nf]);
      }
    }
#pragma unroll
    for (int nf = 0; nf < 4; ++nf) accs[nf] *= SCALE_;
    float corr[4], rsum[4];
#pragma unroll
    for (int r = 0; r < 4; ++r) {
      float t0 = fmaxf(fmaxf(accs[0][r], accs[1][r]), fmaxf(accs[2][r], accs[3][r]));
      t0 = fmaxf(t0, __shfl_xor(t0, 1));
      t0 = fmaxf(t0, __shfl_xor(t0, 2));
      t0 = fmaxf(t0, __shfl_xor(t0, 4));
      t0 = fmaxf(t0, __shfl_xor(t0, 8));
      float mnew = fmaxf(m_run[r], t0);
      corr[r] = __expf(m_run[r] - mnew);
      m_run[r] = mnew;
      rsum[r] = 0.f;
    }
#pragma unroll
    for (int nf = 0; nf < 4; ++nf)
#pragma unroll
      for (int r = 0; r < 4; ++r) {
        float p = __expf(accs[nf][r] - m_run[r]);
        rsum[r] += p;
        u16 ph, pl;
        split2(p, ph, pl);
        Ph[wid][lg*4 + r][nf*16 + lr] = ph;
        Pl[wid][lg*4 + r][nf*16 + lr] = pl;
      }
#pragma unroll
    for (int r = 0; r < 4; ++r) {
      float s = rsum[r];
      s += __shfl_xor(s, 1); s += __shfl_xor(s, 2);
      s += __shfl_xor(s, 4); s += __shfl_xor(s, 8);
      l_run[r] = l_run[r] * corr[r] + s;
    }
#pragma unroll
    for (int df = 0; df < 8; ++df)
#pragma unroll
      for (int r = 0; r < 4; ++r) acc_o[df][r] *= corr[r];
    s16x8 pa_h[2], pa_l[2];
#pragma unroll
    for (int kc = 0; kc < 2; ++kc) {
      pa_h[kc] = *reinterpret_cast<const s16x8*>(&Ph[wid][lr][kc*32 + lg*8]);
      pa_l[kc] = *reinterpret_cast<const s16x8*>(&Pl[wid][lr][kc*32 + lg*8]);
    }
#pragma unroll
    for (int df = 0; df < 8; ++df) {
      int dcol = df * 16 + lr;
#pragma unroll
      for (int kc = 0; kc < 2; ++kc) {
        s16x8 vh8 = *reinterpret_cast<const s16x8*>(&Vh[dcol][kc*32 + lg*8]);
        s16x8 vl8 = *reinterpret_cast<const s16x8*>(&Vl[dcol][kc*32 + lg*8]);
        acc_o[df] = MFMA(pa_h[kc], vh8, acc_o[df]);
        acc_o[df] = MFMA(pa_l[kc], vh8, acc_o[df]);
        acc_o[df] = MFMA(pa_h[kc], vl8, acc_o[df]);
      }
    }
  }
  float inv_l[4];
#pragma unroll
  for (int r = 0; r < 4; ++r) inv_l[r] = 1.f / l_run[r];
#pragma unroll
  for (int df = 0; df < 8; ++df)
#pragma unroll
    for (int r = 0; r < 4; ++r) {
      int row = qt * 128 + wid * 16 + lg * 4 + r;
      ob[((size_t)((b * S_ + row) * HQ_ + h)) * HD_ + df*16 + lr] = acc_o[df][r] * inv_l[r];
    }
}

// ---------------------------------------------------------------------------
extern "C" void kernel_launch(void* const* d_in, const int* in_sizes, int n_in,
                              void* d_out, int out_size, void* d_ws, size_t ws_size,
                              hipStream_t stream)
{
  const float* hs   = (const float*)d_in[0];
  const float* cosT = (const float*)d_in[1];
  const float* sinT = (const float*)d_in[2];
  const float* Wq   = (const float*)d_in[3];
  const float* Wk   = (const float*)d_in[4];
  const float* Wv   = (const float*)d_in[5];
  const float* Wo   = (const float*)d_in[6];
  float* out = (float*)d_out;

  float* qb = (float*)d_ws;                 // 8388608 f32
  float* kb = qb + 8388608;                 // 2097152
  float* vb = kb + 2097152;                 // 2097152
  float* ab = vb + 2097152;                 // 8388608
  u16*   WF = (u16*)(ab + 8388608);

  const size_t WS144 = 83886080ULL + 67108864ULL;  // 150,994,944
  const size_t WS112 = 83886080ULL + 33554432ULL;  // 117,440,512
  int total = B_*S_*HQ_*(HD_/2) + B_*S_*HKV_*(HD_/2);

  // KV fragment planes (reuse WF arena; written after GEMMs, dead before Wo frag)
  u16* KFh = WF;                   // 2097152 u16 each
  u16* KFl = WF + 2097152;
  u16* VFh = WF + 4194304;
  u16* VFl = WF + 6291456;

  if (ws_size >= WS144) {
    frag_b<<<dim3(128,32), 256, 0, stream>>>(Wq, WF,          WF+8388608,  4096, 0,    128);
    frag_b<<<dim3(128,16), 256, 0, stream>>>(Wk, WF+16777216, WF+20971520, 1024, 0,    64);
    frag_b<<<dim3(128,16), 256, 0, stream>>>(Wv, WF+25165824, WF+29360128, 1024, 0,    64);
    gemm_p1<<<256, 512, 0, stream>>>(hs, ab, WF, qb, kb, vb, out, 0, 0);       // QA + K + V
    frag_b<<<dim3(128,32), 256, 0, stream>>>(Wq, WF,          WF+8388608,  4096, 2048, 128);
    gemm_p1<<<128, 512, 0, stream>>>(hs, ab, WF, qb, kb, vb, out, 1, 2048);    // QB
    rope_kernel<<<dim3((total + 255)/256), 256, 0, stream>>>(qb, kb, cosT, sinT);
    frag_kv<<<1024, 256, 0, stream>>>(kb, vb, KFh, KFl, VFh, VFl);
    attn2<<<dim3(8, 64), 512, 0, stream>>>(qb, KFh, KFl, VFh, VFl, ab);
    frag_b<<<dim3(128,64), 256, 0, stream>>>(Wo, WF,          WF+16777216, 4096, 0,    256);
    gemm_p1<<<256, 512, 0, stream>>>(hs, ab, WF, qb, kb, vb, out, 3, 0);       // OUT
  } else if (ws_size >= WS112) {
    frag_b<<<dim3(128,32), 256, 0, stream>>>(Wq, WF, WF+8388608, 4096, 0, 128);
    gemm_p1<<<128, 512, 0, stream>>>(hs, ab, WF, qb, kb, vb, out, 1, 0);       // QA
    frag_b<<<dim3(128,32), 256, 0, stream>>>(Wq, WF, WF+8388608, 4096, 2048, 128);
    gemm_p1<<<128, 512, 0, stream>>>(hs, ab, WF, qb, kb, vb, out, 1, 2048);    // QB
    frag_b<<<dim3(128,16), 256, 0, stream>>>(Wk, WF,           WF+4194304,  1024, 0, 64);
    frag_b<<<dim3(128,16), 256, 0, stream>>>(Wv, WF+8388608,   WF+12582912, 1024, 0, 64);
    gemm_p1<<<128, 512, 0, stream>>>(hs, ab, WF, qb, kb, vb, out, 2, 0);       // K + V
    rope_kernel<<<dim3((total + 255)/256), 256, 0, stream>>>(qb, kb, cosT, sinT);
    frag_kv<<<1024, 256, 0, stream>>>(kb, vb, KFh, KFl, VFh, VFl);
    attn2<<<dim3(8, 64), 512, 0, stream>>>(qb, KFh, KFl, VFh, VFl, ab);
    frag_b<<<dim3(128,32), 256, 0, stream>>>(Wo, WF, WF+8388608, 4096, 0, 128);
    gemm_p1<<<128, 512, 0, stream>>>(hs, ab, WF, qb, kb, vb, out, 4, 0);       // OUT-A
    frag_b<<<dim3(128,32), 256, 0, stream>>>(Wo, WF, WF+8388608, 4096, 2048, 128);
    gemm_p1<<<128, 512, 0, stream>>>(hs, ab, WF, qb, kb, vb, out, 4, 2048);    // OUT-B
  } else {
    gemm_qkv_kernel<<<dim3(24, 16), 512, 0, stream>>>(hs, Wq, Wk, Wv, qb, kb, vb);
    rope_kernel<<<dim3((total + 255)/256), 256, 0, stream>>>(qb, kb, cosT, sinT);
    attn_kernel<<<dim3(8, 64), 512, 0, stream>>>(qb, kb, vb, ab);
    gemm_out_kernel<<<dim3(16, 16), 512, 0, stream>>>(ab, Wo, out);
  }
}

// Round 6
// 734.311 us; speedup vs baseline: 1.4267x; 1.4267x over previous
//
#include <hip/hip_runtime.h>

#define B_   2
#define S_   1024
#define D_   4096
#define HQ_  32
#define HKV_ 8
#define HD_  128
#define SCALE_ 0.08838834764831845f

typedef unsigned short u16;
typedef __attribute__((ext_vector_type(8))) short s16x8;
typedef __attribute__((ext_vector_type(4))) short s16x4;
typedef __attribute__((ext_vector_type(4))) float f32x4;

#define MFMA(a,b,c) __builtin_amdgcn_mfma_f32_16x16x32_bf16((a),(b),(c),0,0,0)

__device__ __forceinline__ u16 bf16_rne(float x) {
  unsigned u = __float_as_uint(x);
  u += 0x7fffu + ((u >> 16) & 1u);
  return (u16)(u >> 16);
}
__device__ __forceinline__ float bf16_up(u16 h) {
  return __uint_as_float(((unsigned)h) << 16);
}
__device__ __forceinline__ void split2(float x, u16& h, u16& l) {
  h = bf16_rne(x);
  l = bf16_rne(x - bf16_up(h));
}

// packed hi/lo split: 2 elems -> 1 u32 hi + 1 u32 lo
__device__ __forceinline__ void cvt_hi_lo(float a, float b, unsigned& hi, unsigned& lo) {
  unsigned h, l;
  asm("v_cvt_pk_bf16_f32 %0, %1, %2" : "=v"(h) : "v"(a), "v"(b));
  float ra = __uint_as_float(h << 16);
  float rb = __uint_as_float(h & 0xffff0000u);
  float la = a - ra, lb = b - rb;
  asm("v_cvt_pk_bf16_f32 %0, %1, %2" : "=v"(l) : "v"(la), "v"(lb));
  hi = h; lo = l;
}
__device__ __forceinline__ void pack8(float4 x, float4 y, uint4& h, uint4& l) {
  unsigned h0,h1,h2,h3,l0,l1,l2,l3;
  cvt_hi_lo(x.x, x.y, h0, l0);
  cvt_hi_lo(x.z, x.w, h1, l1);
  cvt_hi_lo(y.x, y.y, h2, l2);
  cvt_hi_lo(y.z, y.w, h3, l3);
  h = make_uint4(h0,h1,h2,h3); l = make_uint4(l0,l1,l2,l3);
}

// ---- async global->LDS, 16B per lane (dest = wave-uniform base) ----
typedef const __attribute__((address_space(1))) void* gas_ptr;
typedef __attribute__((address_space(3))) void* las_ptr;
__device__ __forceinline__ void gload_lds16(const void* g, void* l) {
  __builtin_amdgcn_global_load_lds((gas_ptr)g, (las_ptr)l, 16, 0, 0);
}

// ===========================================================================
// frag_b: weights (K x N fp32) -> transposed fragment-ordered hi/lo planes,
// over a column chunk [n0, n0 + Nc16*16).
// ===========================================================================
__global__ __launch_bounds__(256) void frag_b(
    const float* __restrict__ W, u16* __restrict__ dh, u16* __restrict__ dl,
    int N, int n0, int Nc16)
{
  __shared__ float T[32][68];
  const int kt = blockIdx.x, nbk = blockIdx.y;
  const int tid = threadIdx.x;
#pragma unroll
  for (int rep = 0; rep < 2; ++rep) {
    int idx = tid + rep * 256;
    int row = idx >> 4, c4 = (idx & 15) * 4;
    float4 v = *reinterpret_cast<const float4*>(&W[(size_t)(kt*32 + row) * N + n0 + nbk*64 + c4]);
    *reinterpret_cast<float4*>(&T[row][c4]) = v;
  }
  __syncthreads();
  const size_t base = ((size_t)kt * Nc16 + nbk * 4) * 512;
  int c = tid;
  int nt = c >> 6, l = c & 63, kc = l >> 4, r = l & 15;
  u16 hh[8], ll[8];
#pragma unroll
  for (int j = 0; j < 8; ++j) split2(T[kc*8 + j][nt*16 + r], hh[j], ll[j]);
  *reinterpret_cast<s16x8*>(&dh[base + (size_t)c * 8]) =
    (s16x8){(short)hh[0],(short)hh[1],(short)hh[2],(short)hh[3],
            (short)hh[4],(short)hh[5],(short)hh[6],(short)hh[7]};
  *reinterpret_cast<s16x8*>(&dl[base + (size_t)c * 8]) =
    (s16x8){(short)ll[0],(short)ll[1],(short)ll[2],(short)ll[3],
            (short)ll[4],(short)ll[5],(short)ll[6],(short)ll[7]};
}

// ===========================================================================
// frag_kv (round-5 verified): post-RoPE K,V -> fragment-ordered hi/lo planes.
// K per (bkvh): [st=s>>4][dt=d>>5][512]; V per (bkvh): [kkt=s>>5][dt16=d>>4][512]
// ===========================================================================
__global__ __launch_bounds__(256) void frag_kv(
    const float* __restrict__ kb, const float* __restrict__ vb,
    u16* __restrict__ KFh, u16* __restrict__ KFl,
    u16* __restrict__ VFh, u16* __restrict__ VFl)
{
  __shared__ float T[32][132];
  const int bid  = blockIdx.x;
  const int isV  = bid >> 9;
  const int bkvh = (bid >> 5) & 15;
  const int chnk = bid & 31;
  const int tid  = threadIdx.x;
  const int b    = bkvh >> 3, kvh = bkvh & 7;

  const float* src = isV ? vb : kb;
  {
    int r0 = tid >> 5, c4 = (tid & 31) * 4;
#pragma unroll
    for (int it = 0; it < 4; ++it) {
      int row = r0 + it * 8;
      float4 v = *reinterpret_cast<const float4*>(
        &src[(((size_t)(b * S_ + chnk*32 + row)) * HKV_ + kvh) * HD_ + c4]);
      *reinterpret_cast<float4*>(&T[row][c4]) = v;
    }
  }
  __syncthreads();
#pragma unroll
  for (int rep = 0; rep < 2; ++rep) {
    int c2 = tid + rep * 256;
    int l = c2 & 63;
    u16 hh[8], ll[8];
    if (!isV) {
      int f = c2 >> 6, st_loc = f >> 2, dt = f & 3;
#pragma unroll
      for (int j = 0; j < 8; ++j)
        split2(T[st_loc*16 + (l & 15)][dt*32 + (l >> 4)*8 + j], hh[j], ll[j]);
      size_t off = ((size_t)bkvh*64 + chnk*2) * 2048 + (size_t)c2 * 8;
      *reinterpret_cast<s16x8*>(&KFh[off]) =
        (s16x8){(short)hh[0],(short)hh[1],(short)hh[2],(short)hh[3],
                (short)hh[4],(short)hh[5],(short)hh[6],(short)hh[7]};
      *reinterpret_cast<s16x8*>(&KFl[off]) =
        (s16x8){(short)ll[0],(short)ll[1],(short)ll[2],(short)ll[3],
                (short)ll[4],(short)ll[5],(short)ll[6],(short)ll[7]};
    } else {
      int dt16 = c2 >> 6;
#pragma unroll
      for (int j = 0; j < 8; ++j)
        split2(T[(l >> 4)*8 + j][dt16*16 + (l & 15)], hh[j], ll[j]);
      size_t off = ((size_t)bkvh*32 + chnk) * 4096 + (size_t)c2 * 8;
      *reinterpret_cast<s16x8*>(&VFh[off]) =
        (s16x8){(short)hh[0],(short)hh[1],(short)hh[2],(short)hh[3],
                (short)hh[4],(short)hh[5],(short)hh[6],(short)hh[7]};
      *reinterpret_cast<s16x8*>(&VFl[off]) =
        (s16x8){(short)ll[0],(short)ll[1],(short)ll[2],(short)ll[3],
                (short)ll[4],(short)ll[5],(short)ll[6],(short)ll[7]};
    }
  }
}

// ===========================================================================
// attn3: fragment-staged flash attention. K/V hi/lo fragments staged into LDS
// via global_load_lds (linear, conflict-free, zero conversion VALU), software
// pipelined: phaseA {issue V(t) stage; QK^T; softmax} bar; phaseB {issue
// K(t+1) stage; PV} bar. LDS 98KB. grid (8 qtiles, 64 b*h), 512 thr.
// ===========================================================================
__global__ __launch_bounds__(512) void attn3(
    const float* __restrict__ qb,
    const u16* __restrict__ KFh, const u16* __restrict__ KFl,
    const u16* __restrict__ VFh, const u16* __restrict__ VFl,
    float* __restrict__ ob)
{
  __shared__ __attribute__((aligned(16))) u16 Klds[16384]; // hi @0, lo @8192
  __shared__ __attribute__((aligned(16))) u16 Vlds[16384]; // hi @0, lo @8192
  __shared__ u16 Ph[8][16][68], Pl[8][16][68];

  const int tid  = threadIdx.x;
  const int lane = tid & 63;
  const int wid  = tid >> 6;
  const int lr   = lane & 15;
  const int lg   = lane >> 4;
  const int loff = lane * 8;
  const int qt   = blockIdx.x;
  const int bh   = blockIdx.y;
  const int b    = bh >> 5, h = bh & 31;
  const int bkvh = b * 8 + (h >> 2);

  // ---- Q rows -> A-fragments (hi/lo), split once ----
  s16x8 qh[4], ql[4];
  {
    const int qrow = qt * 128 + wid * 16 + lr;
    const float* qp = qb + ((size_t)((b * S_ + qrow) * HQ_ + h)) * HD_;
#pragma unroll
    for (int kc = 0; kc < 4; ++kc) {
      const float* qp2 = qp + kc * 32 + lg * 8;
      float4 v0 = *reinterpret_cast<const float4*>(qp2);
      float4 v1 = *reinterpret_cast<const float4*>(qp2 + 4);
      uint4 h4, l4; pack8(v0, v1, h4, l4);
      qh[kc] = *reinterpret_cast<s16x8*>(&h4);
      ql[kc] = *reinterpret_cast<s16x8*>(&l4);
    }
  }

  f32x4 acc_o[8];
#pragma unroll
  for (int df = 0; df < 8; ++df) acc_o[df] = (f32x4){0.f, 0.f, 0.f, 0.f};
  float m_run[4] = {-1e30f, -1e30f, -1e30f, -1e30f};
  float l_run[4] = {0.f, 0.f, 0.f, 0.f};

  const u16* gKh = KFh + (size_t)bkvh * 131072;
  const u16* gKl = KFl + (size_t)bkvh * 131072;
  const u16* gVh = VFh + (size_t)bkvh * 131072;
  const u16* gVl = VFl + (size_t)bkvh * 131072;

  // ---- prologue: stage K(0) ----
#pragma unroll
  for (int i = 0; i < 4; ++i) {
    int idx = wid * 4 + i;               // 0..31: 16 hi chunks + 16 lo chunks
    const u16* src = (idx < 16) ? (gKh + idx*512) : (gKl + (idx-16)*512);
    u16* dst = Klds + ((idx < 16) ? idx*512 : 8192 + (idx-16)*512);
    gload_lds16(src + loff, dst);
  }
  __syncthreads();

  for (int t = 0; t < 16; ++t) {
    // ======== phase A: issue V(t) stage; QK^T; softmax; P writes ========
#pragma unroll
    for (int i = 0; i < 4; ++i) {
      int idx = wid * 4 + i;
      const u16* src = (idx < 16) ? (gVh + t*8192 + idx*512)
                                  : (gVl + t*8192 + (idx-16)*512);
      u16* dst = Vlds + ((idx < 16) ? idx*512 : 8192 + (idx-16)*512);
      gload_lds16(src + loff, dst);
    }

    f32x4 accs[4];
#pragma unroll
    for (int nf = 0; nf < 4; ++nf) {
      accs[nf] = (f32x4){0.f, 0.f, 0.f, 0.f};
      s16x8 kh8[4], kl8[4];
#pragma unroll
      for (int kc = 0; kc < 4; ++kc) {
        kh8[kc] = *reinterpret_cast<const s16x8*>(&Klds[nf*2048 + kc*512 + loff]);
        kl8[kc] = *reinterpret_cast<const s16x8*>(&Klds[8192 + nf*2048 + kc*512 + loff]);
      }
#pragma unroll
      for (int kc = 0; kc < 4; ++kc) {
        accs[nf] = MFMA(qh[kc], kh8[kc], accs[nf]);
        accs[nf] = MFMA(ql[kc], kh8[kc], accs[nf]);
        accs[nf] = MFMA(qh[kc], kl8[kc], accs[nf]);
      }
    }
#pragma unroll
    for (int nf = 0; nf < 4; ++nf) accs[nf] *= SCALE_;

    float corr[4], rsum[4];
#pragma unroll
    for (int r = 0; r < 4; ++r) {
      float t0 = fmaxf(fmaxf(accs[0][r], accs[1][r]), fmaxf(accs[2][r], accs[3][r]));
      t0 = fmaxf(t0, __shfl_xor(t0, 1));
      t0 = fmaxf(t0, __shfl_xor(t0, 2));
      t0 = fmaxf(t0, __shfl_xor(t0, 4));
      t0 = fmaxf(t0, __shfl_xor(t0, 8));
      float mnew = fmaxf(m_run[r], t0);
      corr[r] = __expf(m_run[r] - mnew);
      m_run[r] = mnew;
      rsum[r] = 0.f;
    }
#pragma unroll
    for (int nf = 0; nf < 4; ++nf)
#pragma unroll
      for (int r = 0; r < 4; ++r) {
        float p = __expf(accs[nf][r] - m_run[r]);
        rsum[r] += p;
        u16 ph, pl;
        split2(p, ph, pl);
        Ph[wid][lg*4 + r][nf*16 + lr] = ph;
        Pl[wid][lg*4 + r][nf*16 + lr] = pl;
      }
#pragma unroll
    for (int r = 0; r < 4; ++r) {
      float s = rsum[r];
      s += __shfl_xor(s, 1); s += __shfl_xor(s, 2);
      s += __shfl_xor(s, 4); s += __shfl_xor(s, 8);
      l_run[r] = l_run[r] * corr[r] + s;
    }
#pragma unroll
    for (int df = 0; df < 8; ++df)
#pragma unroll
      for (int r = 0; r < 4; ++r) acc_o[df][r] *= corr[r];

    __syncthreads();   // V(t) staged + all waves done with Klds

    // ======== phase B: issue K(t+1) stage; PV ========
    if (t < 15) {
#pragma unroll
      for (int i = 0; i < 4; ++i) {
        int idx = wid * 4 + i;
        const u16* src = (idx < 16) ? (gKh + (t+1)*8192 + idx*512)
                                    : (gKl + (t+1)*8192 + (idx-16)*512);
        u16* dst = Klds + ((idx < 16) ? idx*512 : 8192 + (idx-16)*512);
        gload_lds16(src + loff, dst);
      }
    }

    s16x8 pa_h[2], pa_l[2];
#pragma unroll
    for (int kc = 0; kc < 2; ++kc) {
      pa_h[kc] = *reinterpret_cast<const s16x8*>(&Ph[wid][lr][kc*32 + lg*8]);
      pa_l[kc] = *reinterpret_cast<const s16x8*>(&Pl[wid][lr][kc*32 + lg*8]);
    }
#pragma unroll
    for (int df = 0; df < 8; ++df) {
      s16x8 vh8[2], vl8[2];
#pragma unroll
      for (int kc = 0; kc < 2; ++kc) {
        vh8[kc] = *reinterpret_cast<const s16x8*>(&Vlds[kc*4096 + df*512 + loff]);
        vl8[kc] = *reinterpret_cast<const s16x8*>(&Vlds[8192 + kc*4096 + df*512 + loff]);
      }
#pragma unroll
      for (int kc = 0; kc < 2; ++kc) {
        acc_o[df] = MFMA(pa_h[kc], vh8[kc], acc_o[df]);
        acc_o[df] = MFMA(pa_l[kc], vh8[kc], acc_o[df]);
        acc_o[df] = MFMA(pa_h[kc], vl8[kc], acc_o[df]);
      }
    }
    __syncthreads();   // K(t+1) staged + all waves done with Vlds
  }

  float inv_l[4];
#pragma unroll
  for (int r = 0; r < 4; ++r) inv_l[r] = 1.f / l_run[r];
#pragma unroll
  for (int df = 0; df < 8; ++df)
#pragma unroll
    for (int r = 0; r < 4; ++r) {
      int row = qt * 128 + wid * 16 + lg * 4 + r;
      ob[((size_t)((b * S_ + row) * HQ_ + h)) * HD_ + df*16 + lr] = acc_o[df][r] * inv_l[r];
    }
}

// ===========================================================================
// Hybrid GEMM (round-4 verified): A staged in-kernel, B pre-fragmented.
// ===========================================================================
__global__ __launch_bounds__(512) void gemm_p1(
    const float* __restrict__ X, const float* __restrict__ abp,
    const u16* __restrict__ WF,
    float* __restrict__ qb, float* __restrict__ kb, float* __restrict__ vb,
    float* __restrict__ outp, int mode, int col0)
{
  __shared__ __attribute__((aligned(16))) u16 lds[40960];
  u16* ah0 = lds;
  u16* al0 = lds + 4096;
  u16* ah1 = lds + 8192;
  u16* al1 = lds + 12288;
  u16* bh0 = lds + 16384;
  u16* bh1 = lds + 24576;
  u16* blb = lds + 32768;

  const int id   = blockIdx.x;
  const int cpx  = gridDim.x >> 3;
  const int swz  = (id & 7) * cpx + (id >> 3);

  const float* A; const u16* Bh; const u16* Bl; float* C;
  int ldc, Nc16, mb, nb;
  if (mode == 0) {
    if (swz < 128)      { A=X; Bh=WF;          Bl=WF+8388608;  C=qb; ldc=4096; Nc16=128; mb=swz>>3; nb=swz&7; }
    else if (swz < 192) { int u=swz-128; A=X; Bh=WF+16777216; Bl=WF+20971520; C=kb; ldc=1024; Nc16=64; mb=u>>2; nb=u&3; }
    else                { int u=swz-192; A=X; Bh=WF+25165824; Bl=WF+29360128; C=vb; ldc=1024; Nc16=64; mb=u>>2; nb=u&3; }
  } else if (mode == 1) {
    A=X; Bh=WF; Bl=WF+8388608; C=qb+col0; ldc=4096; Nc16=128; mb=swz>>3; nb=swz&7;
  } else if (mode == 2) {
    if (swz < 64) { A=X; Bh=WF;          Bl=WF+4194304;  C=kb; ldc=1024; Nc16=64; mb=swz>>2; nb=swz&3; }
    else          { int u=swz-64; A=X; Bh=WF+8388608; Bl=WF+12582912; C=vb; ldc=1024; Nc16=64; mb=u>>2; nb=u&3; }
  } else if (mode == 3) {
    A=abp; Bh=WF; Bl=WF+16777216; C=outp; ldc=4096; Nc16=256; mb=swz>>4; nb=swz&15;
  } else {
    A=abp; Bh=WF; Bl=WF+8388608; C=outp+col0; ldc=4096; Nc16=128; mb=swz>>3; nb=swz&7;
  }

  const int tid  = threadIdx.x;
  const int lane = tid & 63;
  const int wid  = tid >> 6;
  const int mtb  = (wid >> 2) * 4;
  const int ntb  = (wid & 3) * 4;
  const int loff = lane * 8;

  const int arow = tid >> 2;
  const int akc  = tid & 3;
  const float* aptr = A + (size_t)(mb*128 + arow) * 4096 + akc*8;
  const int awr = (arow >> 4)*512 + (akc*16 + (arow & 15))*8;

  const size_t bStep = (size_t)Nc16 * 512;
  const u16* pBh = Bh + (size_t)nb*16*512 + loff;
  const u16* pBl = Bl + (size_t)nb*16*512 + loff;

  f32x4 acc[4][4];
#pragma unroll
  for (int i = 0; i < 4; ++i)
#pragma unroll
    for (int j = 0; j < 4; ++j) acc[i][j] = (f32x4){0.f, 0.f, 0.f, 0.f};

  float4 ra0 = *reinterpret_cast<const float4*>(aptr);
  float4 ra1 = *reinterpret_cast<const float4*>(aptr + 4);
  {
    uint4 h4, l4; pack8(ra0, ra1, h4, l4);
    *reinterpret_cast<uint4*>(&ah0[awr]) = h4;
    *reinterpret_cast<uint4*>(&al0[awr]) = l4;
  }
  gload_lds16(pBh + (size_t)wid*512,     bh0 + wid*512);
  gload_lds16(pBh + (size_t)(wid+8)*512, bh0 + (wid+8)*512);
  ra0 = *reinterpret_cast<const float4*>(aptr + 32);
  ra1 = *reinterpret_cast<const float4*>(aptr + 36);
  __syncthreads();

  for (int kt = 0; kt < 128; ++kt) {
    u16* cAh = (kt & 1) ? ah1 : ah0;
    u16* cAl = (kt & 1) ? al1 : al0;
    u16* nAh = (kt & 1) ? ah0 : ah1;
    u16* nAl = (kt & 1) ? al0 : al1;
    u16* cBh = (kt & 1) ? bh1 : bh0;
    u16* nBh = (kt & 1) ? bh0 : bh1;

    gload_lds16(pBl + (size_t)kt*bStep + (size_t)wid*512,     blb + wid*512);
    gload_lds16(pBl + (size_t)kt*bStep + (size_t)(wid+8)*512, blb + (wid+8)*512);
    if (kt < 127) {
      gload_lds16(pBh + (size_t)(kt+1)*bStep + (size_t)wid*512,     nBh + wid*512);
      gload_lds16(pBh + (size_t)(kt+1)*bStep + (size_t)(wid+8)*512, nBh + (wid+8)*512);
    }
    s16x8 a_h[4], a_l[4], b_h[4];
#pragma unroll
    for (int mf = 0; mf < 4; ++mf) {
      a_h[mf] = *reinterpret_cast<const s16x8*>(&cAh[(mtb+mf)*512 + loff]);
      a_l[mf] = *reinterpret_cast<const s16x8*>(&cAl[(mtb+mf)*512 + loff]);
    }
#pragma unroll
    for (int nf = 0; nf < 4; ++nf)
      b_h[nf] = *reinterpret_cast<const s16x8*>(&cBh[(ntb+nf)*512 + loff]);
#pragma unroll
    for (int mf = 0; mf < 4; ++mf)
#pragma unroll
      for (int nf = 0; nf < 4; ++nf) {
        acc[mf][nf] = MFMA(a_h[mf], b_h[nf], acc[mf][nf]);
        acc[mf][nf] = MFMA(a_l[mf], b_h[nf], acc[mf][nf]);
      }
    __syncthreads();

    s16x8 b_l[4];
#pragma unroll
    for (int nf = 0; nf < 4; ++nf)
      b_l[nf] = *reinterpret_cast<const s16x8*>(&blb[(ntb+nf)*512 + loff]);
#pragma unroll
    for (int mf = 0; mf < 4; ++mf)
#pragma unroll
      for (int nf = 0; nf < 4; ++nf)
        acc[mf][nf] = MFMA(a_h[mf], b_l[nf], acc[mf][nf]);
    if (kt < 127) {
      uint4 h4, l4; pack8(ra0, ra1, h4, l4);
      *reinterpret_cast<uint4*>(&nAh[awr]) = h4;
      *reinterpret_cast<uint4*>(&nAl[awr]) = l4;
      if (kt < 126) {
        ra0 = *reinterpret_cast<const float4*>(aptr + (kt+2)*32);
        ra1 = *reinterpret_cast<const float4*>(aptr + (kt+2)*32 + 4);
      }
    }
    __syncthreads();
  }

  const int lr = lane & 15, lg = lane >> 4;
  const int row0 = mb*128 + (wid >> 2) * 64;
  const int nloc = nb*256 + (wid & 3) * 64;
#pragma unroll
  for (int mf = 0; mf < 4; ++mf)
#pragma unroll
    for (int nf = 0; nf < 4; ++nf)
#pragma unroll
      for (int r = 0; r < 4; ++r)
        C[(size_t)(row0 + mf*16 + lg*4 + r) * ldc + nloc + nf*16 + lr] = acc[mf][nf][r];
}

// ===========================================================================
// Fallback GEMM (round-1, proven) used only if ws < 112MB.
// ===========================================================================
__device__ __forceinline__ void gemm_core_128x256(
    const float* __restrict__ A, const float* __restrict__ W,
    float* __restrict__ C, int ldw, int m0, int n0)
{
  __shared__ u16 Ah[128][40];
  __shared__ u16 Al[128][40];
  __shared__ u16 Bh[256][40];
  __shared__ u16 Bl[256][40];

  const int tid  = threadIdx.x;
  const int lane = tid & 63;
  const int wid  = tid >> 6;
  const int wm   = (wid >> 2) * 64;
  const int wn   = (wid & 3) * 64;
  const int lr   = lane & 15;
  const int lg   = lane >> 4;

  f32x4 acc[4][4];
#pragma unroll
  for (int i = 0; i < 4; ++i)
#pragma unroll
    for (int j = 0; j < 4; ++j) acc[i][j] = (f32x4){0.f, 0.f, 0.f, 0.f};

  const int ar  = tid >> 3;
  const int ak  = (tid & 7) * 4;
  const int bn  = tid & 255;
  const int bk0 = (tid >> 8) * 16;

  for (int kt = 0; kt < D_ / 32; ++kt) {
    const int k0 = kt * 32;
    __syncthreads();
#pragma unroll
    for (int j = 0; j < 2; ++j) {
      int r = ar + 64 * j;
      float4 v = *reinterpret_cast<const float4*>(&A[(size_t)(m0 + r) * D_ + k0 + ak]);
      u16 h0,h1,h2,h3,l0,l1,l2,l3;
      split2(v.x,h0,l0); split2(v.y,h1,l1); split2(v.z,h2,l2); split2(v.w,h3,l3);
      *reinterpret_cast<s16x4*>(&Ah[r][ak]) = (s16x4){(short)h0,(short)h1,(short)h2,(short)h3};
      *reinterpret_cast<s16x4*>(&Al[r][ak]) = (s16x4){(short)l0,(short)l1,(short)l2,(short)l3};
    }
    {
      const float* wp = W + (size_t)(k0 + bk0) * ldw + (n0 + bn);
#pragma unroll
      for (int q = 0; q < 4; ++q) {
        float v0 = wp[(q*4 + 0) * (size_t)ldw];
        float v1 = wp[(q*4 + 1) * (size_t)ldw];
        float v2 = wp[(q*4 + 2) * (size_t)ldw];
        float v3 = wp[(q*4 + 3) * (size_t)ldw];
        u16 h0,h1,h2,h3,l0,l1,l2,l3;
        split2(v0,h0,l0); split2(v1,h1,l1); split2(v2,h2,l2); split2(v3,h3,l3);
        *reinterpret_cast<s16x4*>(&Bh[bn][bk0 + q*4]) = (s16x4){(short)h0,(short)h1,(short)h2,(short)h3};
        *reinterpret_cast<s16x4*>(&Bl[bn][bk0 + q*4]) = (s16x4){(short)l0,(short)l1,(short)l2,(short)l3};
      }
    }
    __syncthreads();
    s16x8 a_h[4], a_l[4], b_h[4], b_l[4];
#pragma unroll
    for (int mf = 0; mf < 4; ++mf) {
      a_h[mf] = *reinterpret_cast<const s16x8*>(&Ah[wm + mf*16 + lr][lg*8]);
      a_l[mf] = *reinterpret_cast<const s16x8*>(&Al[wm + mf*16 + lr][lg*8]);
    }
#pragma unroll
    for (int nf = 0; nf < 4; ++nf) {
      b_h[nf] = *reinterpret_cast<const s16x8*>(&Bh[wn + nf*16 + lr][lg*8]);
      b_l[nf] = *reinterpret_cast<const s16x8*>(&Bl[wn + nf*16 + lr][lg*8]);
    }
#pragma unroll
    for (int mf = 0; mf < 4; ++mf)
#pragma unroll
      for (int nf = 0; nf < 4; ++nf) {
        acc[mf][nf] = MFMA(a_h[mf], b_h[nf], acc[mf][nf]);
        acc[mf][nf] = MFMA(a_l[mf], b_h[nf], acc[mf][nf]);
        acc[mf][nf] = MFMA(a_h[mf], b_l[nf], acc[mf][nf]);
      }
  }
#pragma unroll
  for (int mf = 0; mf < 4; ++mf)
#pragma unroll
    for (int nf = 0; nf < 4; ++nf)
#pragma unroll
      for (int r = 0; r < 4; ++r) {
        int row = m0 + wm + mf*16 + lg*4 + r;
        int col = n0 + wn + nf*16 + lr;
        C[(size_t)row * ldw + col] = acc[mf][nf][r];
      }
}

__global__ __launch_bounds__(512) void gemm_qkv_kernel(
    const float* __restrict__ X,
    const float* __restrict__ Wq, const float* __restrict__ Wk,
    const float* __restrict__ Wv,
    float* __restrict__ qb, float* __restrict__ kb, float* __restrict__ vb)
{
  int nbv = blockIdx.x;
  int m0 = blockIdx.y * 128;
  const float* W; float* C; int ldw, n0;
  if (nbv < 16)      { W = Wq; C = qb; ldw = HQ_*HD_;  n0 = nbv * 256; }
  else if (nbv < 20) { W = Wk; C = kb; ldw = HKV_*HD_; n0 = (nbv-16) * 256; }
  else               { W = Wv; C = vb; ldw = HKV_*HD_; n0 = (nbv-20) * 256; }
  gemm_core_128x256(X, W, C, ldw, m0, n0);
}

__global__ __launch_bounds__(512) void gemm_out_kernel(
    const float* __restrict__ A, const float* __restrict__ Wo, float* __restrict__ out)
{
  gemm_core_128x256(A, Wo, out, D_, blockIdx.y * 128, blockIdx.x * 256);
}

// ---------------------------------------------------------------------------
// RoPE in-place on q (b,s,32,128) and k (b,s,8,128), fp32.
// ---------------------------------------------------------------------------
__global__ __launch_bounds__(256) void rope_kernel(
    float* __restrict__ qb, float* __restrict__ kb,
    const float* __restrict__ cosT, const float* __restrict__ sinT)
{
  int idx = blockIdx.x * 256 + threadIdx.x;
  const int nq = B_ * S_ * HQ_ * (HD_/2);
  const int nk = B_ * S_ * HKV_ * (HD_/2);
  if (idx < nq) {
    int j = idx & 63;
    int h = (idx >> 6) & (HQ_ - 1);
    int bs = idx >> 11;
    float* p = qb + ((size_t)bs * HQ_ + h) * HD_;
    const float* cp = cosT + (size_t)bs * HD_;
    const float* sp = sinT + (size_t)bs * HD_;
    float x1 = p[j], x2 = p[j + 64];
    p[j]      = x1 * cp[j]      - x2 * sp[j];
    p[j + 64] = x2 * cp[j + 64] + x1 * sp[j + 64];
  } else if (idx < nq + nk) {
    int t2 = idx - nq;
    int j = t2 & 63;
    int h = (t2 >> 6) & (HKV_ - 1);
    int bs = t2 >> 9;
    float* p = kb + ((size_t)bs * HKV_ + h) * HD_;
    const float* cp = cosT + (size_t)bs * HD_;
    const float* sp = sinT + (size_t)bs * HD_;
    float x1 = p[j], x2 = p[j + 64];
    p[j]      = x1 * cp[j]      - x2 * sp[j];
    p[j + 64] = x2 * cp[j + 64] + x1 * sp[j + 64];
  }
}

// ---------------------------------------------------------------------------
// Flash attention (round-1 verified) — fallback tier only.
// ---------------------------------------------------------------------------
__global__ __launch_bounds__(512) void attn_kernel(
    const float* __restrict__ qb, const float* __restrict__ kb,
    const float* __restrict__ vb, float* __restrict__ ob)
{
  __shared__ u16 Kh[64][136], Kl[64][136];
  __shared__ u16 Vh[128][72], Vl[128][72];
  __shared__ u16 Ph[8][16][72], Pl[8][16][72];

  const int tid  = threadIdx.x;
  const int lane = tid & 63;
  const int wid  = tid >> 6;
  const int lr   = lane & 15;
  const int lg   = lane >> 4;
  const int qt   = blockIdx.x;
  const int bh   = blockIdx.y;
  const int b    = bh >> 5, h = bh & 31, kvh = h >> 2;

  s16x8 qh[4], ql[4];
  {
    const int qrow = qt * 128 + wid * 16 + lr;
    const float* qp = qb + ((size_t)((b * S_ + qrow) * HQ_ + h)) * HD_;
#pragma unroll
    for (int kc = 0; kc < 4; ++kc) {
      const float* qp2 = qp + kc * 32 + lg * 8;
      float4 v0 = *reinterpret_cast<const float4*>(qp2);
      float4 v1 = *reinterpret_cast<const float4*>(qp2 + 4);
      u16 hh[8], ll[8];
      split2(v0.x,hh[0],ll[0]); split2(v0.y,hh[1],ll[1]);
      split2(v0.z,hh[2],ll[2]); split2(v0.w,hh[3],ll[3]);
      split2(v1.x,hh[4],ll[4]); split2(v1.y,hh[5],ll[5]);
      split2(v1.z,hh[6],ll[6]); split2(v1.w,hh[7],ll[7]);
      qh[kc] = (s16x8){(short)hh[0],(short)hh[1],(short)hh[2],(short)hh[3],
                       (short)hh[4],(short)hh[5],(short)hh[6],(short)hh[7]};
      ql[kc] = (s16x8){(short)ll[0],(short)ll[1],(short)ll[2],(short)ll[3],
                       (short)ll[4],(short)ll[5],(short)ll[6],(short)ll[7]};
    }
  }

  f32x4 acc_o[8];
#pragma unroll
  for (int df = 0; df < 8; ++df) acc_o[df] = (f32x4){0.f, 0.f, 0.f, 0.f};
  float m_run[4] = {-1e30f, -1e30f, -1e30f, -1e30f};
  float l_run[4] = {0.f, 0.f, 0.f, 0.f};

  const float* kbase = kb + ((size_t)(b * S_) * HKV_ + kvh) * HD_;
  const float* vbase = vb + ((size_t)(b * S_) * HKV_ + kvh) * HD_;

  for (int t = 0; t < S_ / 64; ++t) {
    const int kk0 = t * 64;
    __syncthreads();
#pragma unroll
    for (int j = 0; j < 4; ++j) {
      int idx = tid + 512 * j;
      int kk = idx >> 5, dq = (idx & 31) * 4;
      float4 v = *reinterpret_cast<const float4*>(kbase + (size_t)(kk0 + kk) * (HKV_*HD_) + dq);
      u16 h0,h1,h2,h3,l0,l1,l2,l3;
      split2(v.x,h0,l0); split2(v.y,h1,l1); split2(v.z,h2,l2); split2(v.w,h3,l3);
      *reinterpret_cast<s16x4*>(&Kh[kk][dq]) = (s16x4){(short)h0,(short)h1,(short)h2,(short)h3};
      *reinterpret_cast<s16x4*>(&Kl[kk][dq]) = (s16x4){(short)l0,(short)l1,(short)l2,(short)l3};
    }
    {
      int d = tid & 127;
      int kkb = (tid >> 7) * 16;
      const float* vcol = vbase + d;
#pragma unroll
      for (int jq = 0; jq < 4; ++jq) {
        u16 h4[4], l4[4];
#pragma unroll
        for (int e = 0; e < 4; ++e) {
          float val = vcol[(size_t)(kk0 + kkb + jq*4 + e) * (HKV_*HD_)];
          split2(val, h4[e], l4[e]);
        }
        *reinterpret_cast<s16x4*>(&Vh[d][kkb + jq*4]) = (s16x4){(short)h4[0],(short)h4[1],(short)h4[2],(short)h4[3]};
        *reinterpret_cast<s16x4*>(&Vl[d][kkb + jq*4]) = (s16x4){(short)l4[0],(short)l4[1],(short)l4[2],(short)l4[3]};
      }
    }
    __syncthreads();
    f32x4 accs[4];
#pragma unroll
    for (int nf = 0; nf < 4; ++nf) accs[nf] = (f32x4){0.f, 0.f, 0.f, 0.f};
#pragma unroll
    for (int nf = 0; nf < 4; ++nf) {
      int krow = nf * 16 + lr;
#pragma unroll
      for (int kc = 0; kc < 4; ++kc) {
        s16x8 kh8 = *reinterpret_cast<const s16x8*>(&Kh[krow][kc*32 + lg*8]);
        s16x8 kl8 = *reinterpret_cast<const s16x8*>(&Kl[krow][kc*32 + lg*8]);
        accs[nf] = MFMA(qh[kc], kh8, accs[nf]);
        accs[nf] = MFMA(ql[kc], kh8, accs[nf]);
        accs[nf] = MFMA(qh[kc], kl8, accs[nf]);
      }
    }
#pragma unroll
    for (int nf = 0; nf < 4; ++nf) accs[nf] *= SCALE_;
    float corr[4], rsum[4];
#pragma unroll
    for (int r = 0; r < 4; ++r) {
      float t0 = fmaxf(fmaxf(accs[0][r], accs[1][r]), fmaxf(accs[2][r], accs[3][r]));
      t0 = fmaxf(t0, __shfl_xor(t0, 1));
      t0 = fmaxf(t0, __shfl_xor(t0, 2));
      t0 = fmaxf(t0, __shfl_xor(t0, 4));
      t0 = fmaxf(t0, __shfl_xor(t0, 8));
      float mnew = fmaxf(m_run[r], t0);
      corr[r] = __expf(m_run[r] - mnew);
      m_run[r] = mnew;
      rsum[r] = 0.f;
    }
#pragma unroll
    for (int nf = 0; nf < 4; ++nf)
#pragma unroll
      for (int r = 0; r < 4; ++r) {
        float p = __expf(accs[nf][r] - m_run[r]);
        rsum[r] += p;
        u16 ph, pl;
        split2(p, ph, pl);
        Ph[wid][lg*4 + r][nf*16 + lr] = ph;
        Pl[wid][lg*4 + r][nf*16 + lr] = pl;
      }
#pragma unroll
    for (int r = 0; r < 4; ++r) {
      float s = rsum[r];
      s += __shfl_xor(s, 1); s += __shfl_xor(s, 2);
      s += __shfl_xor(s, 4); s += __shfl_xor(s, 8);
      l_run[r] = l_run[r] * corr[r] + s;
    }
#pragma unroll
    for (int df = 0; df < 8; ++df)
#pragma unroll
      for (int r = 0; r < 4; ++r) acc_o[df][r] *= corr[r];
    s16x8 pa_h[2], pa_l[2];
#pragma unroll
    for (int kc = 0; kc < 2; ++kc) {
      pa_h[kc] = *reinterpret_cast<const s16x8*>(&Ph[wid][lr][kc*32 + lg*8]);
      pa_l[kc] = *reinterpret_cast<const s16x8*>(&Pl[wid][lr][kc*32 + lg*8]);
    }
#pragma unroll
    for (int df = 0; df < 8; ++df) {
      int dcol = df * 16 + lr;
#pragma unroll
      for (int kc = 0; kc < 2; ++kc) {
        s16x8 vh8 = *reinterpret_cast<const s16x8*>(&Vh[dcol][kc*32 + lg*8]);
        s16x8 vl8 = *reinterpret_cast<const s16x8*>(&Vl[dcol][kc*32 + lg*8]);
        acc_o[df] = MFMA(pa_h[kc], vh8, acc_o[df]);
        acc_o[df] = MFMA(pa_l[kc], vh8, acc_o[df]);
        acc_o[df] = MFMA(pa_h[kc], vl8, acc_o[df]);
      }
    }
  }
  float inv_l[4];
#pragma unroll
  for (int r = 0; r < 4; ++r) inv_l[r] = 1.f / l_run[r];
#pragma unroll
  for (int df = 0; df < 8; ++df)
#pragma unroll
    for (int r = 0; r < 4; ++r) {
      int row = qt * 128 + wid * 16 + lg * 4 + r;
      ob[((size_t)((b * S_ + row) * HQ_ + h)) * HD_ + df*16 + lr] = acc_o[df][r] * inv_l[r];
    }
}

// ---------------------------------------------------------------------------
extern "C" void kernel_launch(void* const* d_in, const int* in_sizes, int n_in,
                              void* d_out, int out_size, void* d_ws, size_t ws_size,
                              hipStream_t stream)
{
  const float* hs   = (const float*)d_in[0];
  const float* cosT = (const float*)d_in[1];
  const float* sinT = (const float*)d_in[2];
  const float* Wq   = (const float*)d_in[3];
  const float* Wk   = (const float*)d_in[4];
  const float* Wv   = (const float*)d_in[5];
  const float* Wo   = (const float*)d_in[6];
  float* out = (float*)d_out;

  float* qb = (float*)d_ws;                 // 8388608 f32
  float* kb = qb + 8388608;                 // 2097152
  float* vb = kb + 2097152;                 // 2097152
  float* ab = vb + 2097152;                 // 8388608
  u16*   WF = (u16*)(ab + 8388608);

  const size_t WS144 = 83886080ULL + 67108864ULL;  // 150,994,944
  const size_t WS112 = 83886080ULL + 33554432ULL;  // 117,440,512
  int total = B_*S_*HQ_*(HD_/2) + B_*S_*HKV_*(HD_/2);

  // KV fragment planes (reuse WF arena; written after GEMMs, dead before Wo frag)
  u16* KFh = WF;                   // 2097152 u16 each
  u16* KFl = WF + 2097152;
  u16* VFh = WF + 4194304;
  u16* VFl = WF + 6291456;

  if (ws_size >= WS144) {
    frag_b<<<dim3(128,32), 256, 0, stream>>>(Wq, WF,          WF+8388608,  4096, 0,    128);
    frag_b<<<dim3(128,16), 256, 0, stream>>>(Wk, WF+16777216, WF+20971520, 1024, 0,    64);
    frag_b<<<dim3(128,16), 256, 0, stream>>>(Wv, WF+25165824, WF+29360128, 1024, 0,    64);
    gemm_p1<<<256, 512, 0, stream>>>(hs, ab, WF, qb, kb, vb, out, 0, 0);       // QA + K + V
    frag_b<<<dim3(128,32), 256, 0, stream>>>(Wq, WF,          WF+8388608,  4096, 2048, 128);
    gemm_p1<<<128, 512, 0, stream>>>(hs, ab, WF, qb, kb, vb, out, 1, 2048);    // QB
    rope_kernel<<<dim3((total + 255)/256), 256, 0, stream>>>(qb, kb, cosT, sinT);
    frag_kv<<<1024, 256, 0, stream>>>(kb, vb, KFh, KFl, VFh, VFl);
    attn3<<<dim3(8, 64), 512, 0, stream>>>(qb, KFh, KFl, VFh, VFl, ab);
    frag_b<<<dim3(128,64), 256, 0, stream>>>(Wo, WF,          WF+16777216, 4096, 0,    256);
    gemm_p1<<<256, 512, 0, stream>>>(hs, ab, WF, qb, kb, vb, out, 3, 0);       // OUT
  } else if (ws_size >= WS112) {
    frag_b<<<dim3(128,32), 256, 0, stream>>>(Wq, WF, WF+8388608, 4096, 0, 128);
    gemm_p1<<<128, 512, 0, stream>>>(hs, ab, WF, qb, kb, vb, out, 1, 0);       // QA
    frag_b<<<dim3(128,32), 256, 0, stream>>>(Wq, WF, WF+8388608, 4096, 2048, 128);
    gemm_p1<<<128, 512, 0, stream>>>(hs, ab, WF, qb, kb, vb, out, 1, 2048);    // QB
    frag_b<<<dim3(128,16), 256, 0, stream>>>(Wk, WF,           WF+4194304,  1024, 0, 64);
    frag_b<<<dim3(128,16), 256, 0, stream>>>(Wv, WF+8388608,   WF+12582912, 1024, 0, 64);
    gemm_p1<<<128, 512, 0, stream>>>(hs, ab, WF, qb, kb, vb, out, 2, 0);       // K + V
    rope_kernel<<<dim3((total + 255)/256), 256, 0, stream>>>(qb, kb, cosT, sinT);
    frag_kv<<<1024, 256, 0, stream>>>(kb, vb, KFh, KFl, VFh, VFl);
    attn3<<<dim3(8, 64), 512, 0, stream>>>(qb, KFh, KFl, VFh, VFl, ab);
    frag_b<<<dim3(128,32), 256, 0, stream>>>(Wo, WF, WF+8388608, 4096, 0, 128);
    gemm_p1<<<128, 512, 0, stream>>>(hs, ab, WF, qb, kb, vb, out, 4, 0);       // OUT-A
    frag_b<<<dim3(128,32), 256, 0, stream>>>(Wo, WF, WF+8388608, 4096, 2048, 128);
    gemm_p1<<<128, 512, 0, stream>>>(hs, ab, WF, qb, kb, vb, out, 4, 2048);    // OUT-B
  } else {
    gemm_qkv_kernel<<<dim3(24, 16), 512, 0, stream>>>(hs, Wq, Wk, Wv, qb, kb, vb);
    rope_kernel<<<dim3((total + 255)/256), 256, 0, stream>>>(qb, kb, cosT, sinT);
    attn_kernel<<<dim3(8, 64), 512, 0, stream>>>(qb, kb, vb, ab);
    gemm_out_kernel<<<dim3(16, 16), 512, 0, stream>>>(ab, Wo, out);
  }
}

// Round 7
// 712.599 us; speedup vs baseline: 1.4702x; 1.0305x over previous
//
#include <hip/hip_runtime.h>

#define B_   2
#define S_   1024
#define D_   4096
#define HQ_  32
#define HKV_ 8
#define HD_  128
#define SCALE_ 0.08838834764831845f

typedef unsigned short u16;
typedef __attribute__((ext_vector_type(8))) short s16x8;
typedef __attribute__((ext_vector_type(4))) short s16x4;
typedef __attribute__((ext_vector_type(4))) float f32x4;

#define MFMA(a,b,c) __builtin_amdgcn_mfma_f32_16x16x32_bf16((a),(b),(c),0,0,0)

__device__ __forceinline__ u16 bf16_rne(float x) {
  unsigned u = __float_as_uint(x);
  u += 0x7fffu + ((u >> 16) & 1u);
  return (u16)(u >> 16);
}
__device__ __forceinline__ float bf16_up(u16 h) {
  return __uint_as_float(((unsigned)h) << 16);
}
__device__ __forceinline__ void split2(float x, u16& h, u16& l) {
  h = bf16_rne(x);
  l = bf16_rne(x - bf16_up(h));
}

// packed hi/lo split: 2 elems -> 1 u32 hi + 1 u32 lo
__device__ __forceinline__ void cvt_hi_lo(float a, float b, unsigned& hi, unsigned& lo) {
  unsigned h, l;
  asm("v_cvt_pk_bf16_f32 %0, %1, %2" : "=v"(h) : "v"(a), "v"(b));
  float ra = __uint_as_float(h << 16);
  float rb = __uint_as_float(h & 0xffff0000u);
  float la = a - ra, lb = b - rb;
  asm("v_cvt_pk_bf16_f32 %0, %1, %2" : "=v"(l) : "v"(la), "v"(lb));
  hi = h; lo = l;
}
__device__ __forceinline__ void pack8(float4 x, float4 y, uint4& h, uint4& l) {
  unsigned h0,h1,h2,h3,l0,l1,l2,l3;
  cvt_hi_lo(x.x, x.y, h0, l0);
  cvt_hi_lo(x.z, x.w, h1, l1);
  cvt_hi_lo(y.x, y.y, h2, l2);
  cvt_hi_lo(y.z, y.w, h3, l3);
  h = make_uint4(h0,h1,h2,h3); l = make_uint4(l0,l1,l2,l3);
}

// ---- async global->LDS, 16B per lane (dest = wave-uniform base) ----
typedef const __attribute__((address_space(1))) void* gas_ptr;
typedef __attribute__((address_space(3))) void* las_ptr;
__device__ __forceinline__ void gload_lds16(const void* g, void* l) {
  __builtin_amdgcn_global_load_lds((gas_ptr)g, (las_ptr)l, 16, 0, 0);
}

// ===========================================================================
// frag_b: weights (K x N fp32) -> transposed fragment-ordered hi/lo planes,
// over a column chunk [n0, n0 + Nc16*16). Plane = 128*Nc16*512 u16.
// ===========================================================================
__global__ __launch_bounds__(256) void frag_b(
    const float* __restrict__ W, u16* __restrict__ dh, u16* __restrict__ dl,
    int N, int n0, int Nc16)
{
  __shared__ float T[32][68];
  const int kt = blockIdx.x, nbk = blockIdx.y;
  const int tid = threadIdx.x;
#pragma unroll
  for (int rep = 0; rep < 2; ++rep) {
    int idx = tid + rep * 256;
    int row = idx >> 4, c4 = (idx & 15) * 4;
    float4 v = *reinterpret_cast<const float4*>(&W[(size_t)(kt*32 + row) * N + n0 + nbk*64 + c4]);
    *reinterpret_cast<float4*>(&T[row][c4]) = v;
  }
  __syncthreads();
  const size_t base = ((size_t)kt * Nc16 + nbk * 4) * 512;
  int c = tid;
  int nt = c >> 6, l = c & 63, kc = l >> 4, r = l & 15;
  u16 hh[8], ll[8];
#pragma unroll
  for (int j = 0; j < 8; ++j) split2(T[kc*8 + j][nt*16 + r], hh[j], ll[j]);
  *reinterpret_cast<s16x8*>(&dh[base + (size_t)c * 8]) =
    (s16x8){(short)hh[0],(short)hh[1],(short)hh[2],(short)hh[3],
            (short)hh[4],(short)hh[5],(short)hh[6],(short)hh[7]};
  *reinterpret_cast<s16x8*>(&dl[base + (size_t)c * 8]) =
    (s16x8){(short)ll[0],(short)ll[1],(short)ll[2],(short)ll[3],
            (short)ll[4],(short)ll[5],(short)ll[6],(short)ll[7]};
}

// ===========================================================================
// frag_kv: post-RoPE layout pass with K-RoPE FUSED at load (V unroped).
// K per (bkvh): [st=s>>4][dt=d>>5][512]; V per (bkvh): [kkt=s>>5][dt16=d>>4][512]
// ===========================================================================
__global__ __launch_bounds__(256) void frag_kv(
    const float* __restrict__ kb, const float* __restrict__ vb,
    const float* __restrict__ cosT, const float* __restrict__ sinT,
    u16* __restrict__ KFh, u16* __restrict__ KFl,
    u16* __restrict__ VFh, u16* __restrict__ VFl)
{
  __shared__ float T[32][132];
  const int bid  = blockIdx.x;
  const int isV  = bid >> 9;
  const int bkvh = (bid >> 5) & 15;
  const int chnk = bid & 31;
  const int tid  = threadIdx.x;
  const int b    = bkvh >> 3, kvh = bkvh & 7;

  const float* src = isV ? vb : kb;
  {
    int r0 = tid >> 5, c4 = (tid & 31) * 4;
    float sgn = (c4 < 64) ? -1.f : 1.f;
#pragma unroll
    for (int it = 0; it < 4; ++it) {
      int row = r0 + it * 8;
      int srow = chnk*32 + row;
      const float* rp = &src[(((size_t)(b * S_ + srow)) * HKV_ + kvh) * HD_];
      float4 v = *reinterpret_cast<const float4*>(rp + c4);
      if (!isV) {   // rope K
        float4 p  = *reinterpret_cast<const float4*>(rp + (c4 ^ 64));
        float4 cc = *reinterpret_cast<const float4*>(&cosT[((size_t)(b*S_ + srow))*HD_ + c4]);
        float4 ss = *reinterpret_cast<const float4*>(&sinT[((size_t)(b*S_ + srow))*HD_ + c4]);
        v.x = v.x*cc.x + sgn*p.x*ss.x;
        v.y = v.y*cc.y + sgn*p.y*ss.y;
        v.z = v.z*cc.z + sgn*p.z*ss.z;
        v.w = v.w*cc.w + sgn*p.w*ss.w;
      }
      *reinterpret_cast<float4*>(&T[row][c4]) = v;
    }
  }
  __syncthreads();
#pragma unroll
  for (int rep = 0; rep < 2; ++rep) {
    int c2 = tid + rep * 256;
    int l = c2 & 63;
    u16 hh[8], ll[8];
    if (!isV) {
      int f = c2 >> 6, st_loc = f >> 2, dt = f & 3;
#pragma unroll
      for (int j = 0; j < 8; ++j)
        split2(T[st_loc*16 + (l & 15)][dt*32 + (l >> 4)*8 + j], hh[j], ll[j]);
      size_t off = ((size_t)bkvh*64 + chnk*2) * 2048 + (size_t)c2 * 8;
      *reinterpret_cast<s16x8*>(&KFh[off]) =
        (s16x8){(short)hh[0],(short)hh[1],(short)hh[2],(short)hh[3],
                (short)hh[4],(short)hh[5],(short)hh[6],(short)hh[7]};
      *reinterpret_cast<s16x8*>(&KFl[off]) =
        (s16x8){(short)ll[0],(short)ll[1],(short)ll[2],(short)ll[3],
                (short)ll[4],(short)ll[5],(short)ll[6],(short)ll[7]};
    } else {
      int dt16 = c2 >> 6;
#pragma unroll
      for (int j = 0; j < 8; ++j)
        split2(T[(l >> 4)*8 + j][dt16*16 + (l & 15)], hh[j], ll[j]);
      size_t off = ((size_t)bkvh*32 + chnk) * 4096 + (size_t)c2 * 8;
      *reinterpret_cast<s16x8*>(&VFh[off]) =
        (s16x8){(short)hh[0],(short)hh[1],(short)hh[2],(short)hh[3],
                (short)hh[4],(short)hh[5],(short)hh[6],(short)hh[7]};
      *reinterpret_cast<s16x8*>(&VFl[off]) =
        (s16x8){(short)ll[0],(short)ll[1],(short)ll[2],(short)ll[3],
                (short)ll[4],(short)ll[5],(short)ll[6],(short)ll[7]};
    }
  }
}

// ===========================================================================
// attn3 (round-6 verified structure) + Q-RoPE fused at the one-time Q load.
// ===========================================================================
__global__ __launch_bounds__(512) void attn3(
    const float* __restrict__ qb,
    const float* __restrict__ cosT, const float* __restrict__ sinT,
    const u16* __restrict__ KFh, const u16* __restrict__ KFl,
    const u16* __restrict__ VFh, const u16* __restrict__ VFl,
    float* __restrict__ ob)
{
  __shared__ __attribute__((aligned(16))) u16 Klds[16384];
  __shared__ __attribute__((aligned(16))) u16 Vlds[16384];
  __shared__ u16 Ph[8][16][68], Pl[8][16][68];

  const int tid  = threadIdx.x;
  const int lane = tid & 63;
  const int wid  = tid >> 6;
  const int lr   = lane & 15;
  const int lg   = lane >> 4;
  const int loff = lane * 8;
  const int qt   = blockIdx.x;
  const int bh   = blockIdx.y;
  const int b    = bh >> 5, h = bh & 31;
  const int bkvh = b * 8 + (h >> 2);

  // ---- Q rows -> A-fragments with fused RoPE, split once ----
  s16x8 qh[4], ql[4];
  {
    const int qrow = qt * 128 + wid * 16 + lr;
    const float* qp = qb + ((size_t)((b * S_ + qrow) * HQ_ + h)) * HD_;
    const float* cp = cosT + ((size_t)(b * S_ + qrow)) * HD_;
    const float* sp = sinT + ((size_t)(b * S_ + qrow)) * HD_;
#pragma unroll
    for (int kc = 0; kc < 4; ++kc) {
      const int d0 = kc * 32 + lg * 8;
      const float sgn = (d0 < 64) ? -1.f : 1.f;
      float4 v0 = *reinterpret_cast<const float4*>(qp + d0);
      float4 v1 = *reinterpret_cast<const float4*>(qp + d0 + 4);
      float4 p0 = *reinterpret_cast<const float4*>(qp + (d0 ^ 64));
      float4 p1 = *reinterpret_cast<const float4*>(qp + (d0 ^ 64) + 4);
      float4 c0 = *reinterpret_cast<const float4*>(cp + d0);
      float4 c1 = *reinterpret_cast<const float4*>(cp + d0 + 4);
      float4 s0 = *reinterpret_cast<const float4*>(sp + d0);
      float4 s1 = *reinterpret_cast<const float4*>(sp + d0 + 4);
      float4 r0, r1;
      r0.x = v0.x*c0.x + sgn*p0.x*s0.x;  r0.y = v0.y*c0.y + sgn*p0.y*s0.y;
      r0.z = v0.z*c0.z + sgn*p0.z*s0.z;  r0.w = v0.w*c0.w + sgn*p0.w*s0.w;
      r1.x = v1.x*c1.x + sgn*p1.x*s1.x;  r1.y = v1.y*c1.y + sgn*p1.y*s1.y;
      r1.z = v1.z*c1.z + sgn*p1.z*s1.z;  r1.w = v1.w*c1.w + sgn*p1.w*s1.w;
      uint4 h4, l4; pack8(r0, r1, h4, l4);
      qh[kc] = *reinterpret_cast<s16x8*>(&h4);
      ql[kc] = *reinterpret_cast<s16x8*>(&l4);
    }
  }

  f32x4 acc_o[8];
#pragma unroll
  for (int df = 0; df < 8; ++df) acc_o[df] = (f32x4){0.f, 0.f, 0.f, 0.f};
  float m_run[4] = {-1e30f, -1e30f, -1e30f, -1e30f};
  float l_run[4] = {0.f, 0.f, 0.f, 0.f};

  const u16* gKh = KFh + (size_t)bkvh * 131072;
  const u16* gKl = KFl + (size_t)bkvh * 131072;
  const u16* gVh = VFh + (size_t)bkvh * 131072;
  const u16* gVl = VFl + (size_t)bkvh * 131072;

#pragma unroll
  for (int i = 0; i < 4; ++i) {
    int idx = wid * 4 + i;
    const u16* src = (idx < 16) ? (gKh + idx*512) : (gKl + (idx-16)*512);
    u16* dst = Klds + ((idx < 16) ? idx*512 : 8192 + (idx-16)*512);
    gload_lds16(src + loff, dst);
  }
  __syncthreads();

  for (int t = 0; t < 16; ++t) {
    // phase A: issue V(t) stage; QK^T; softmax; P writes
#pragma unroll
    for (int i = 0; i < 4; ++i) {
      int idx = wid * 4 + i;
      const u16* src = (idx < 16) ? (gVh + t*8192 + idx*512)
                                  : (gVl + t*8192 + (idx-16)*512);
      u16* dst = Vlds + ((idx < 16) ? idx*512 : 8192 + (idx-16)*512);
      gload_lds16(src + loff, dst);
    }

    f32x4 accs[4];
#pragma unroll
    for (int nf = 0; nf < 4; ++nf) {
      accs[nf] = (f32x4){0.f, 0.f, 0.f, 0.f};
      s16x8 kh8[4], kl8[4];
#pragma unroll
      for (int kc = 0; kc < 4; ++kc) {
        kh8[kc] = *reinterpret_cast<const s16x8*>(&Klds[nf*2048 + kc*512 + loff]);
        kl8[kc] = *reinterpret_cast<const s16x8*>(&Klds[8192 + nf*2048 + kc*512 + loff]);
      }
#pragma unroll
      for (int kc = 0; kc < 4; ++kc) {
        accs[nf] = MFMA(qh[kc], kh8[kc], accs[nf]);
        accs[nf] = MFMA(ql[kc], kh8[kc], accs[nf]);
        accs[nf] = MFMA(qh[kc], kl8[kc], accs[nf]);
      }
    }
#pragma unroll
    for (int nf = 0; nf < 4; ++nf) accs[nf] *= SCALE_;

    float corr[4], rsum[4];
#pragma unroll
    for (int r = 0; r < 4; ++r) {
      float t0 = fmaxf(fmaxf(accs[0][r], accs[1][r]), fmaxf(accs[2][r], accs[3][r]));
      t0 = fmaxf(t0, __shfl_xor(t0, 1));
      t0 = fmaxf(t0, __shfl_xor(t0, 2));
      t0 = fmaxf(t0, __shfl_xor(t0, 4));
      t0 = fmaxf(t0, __shfl_xor(t0, 8));
      float mnew = fmaxf(m_run[r], t0);
      corr[r] = __expf(m_run[r] - mnew);
      m_run[r] = mnew;
      rsum[r] = 0.f;
    }
#pragma unroll
    for (int nf = 0; nf < 4; ++nf)
#pragma unroll
      for (int r = 0; r < 4; ++r) {
        float p = __expf(accs[nf][r] - m_run[r]);
        rsum[r] += p;
        u16 ph, pl;
        split2(p, ph, pl);
        Ph[wid][lg*4 + r][nf*16 + lr] = ph;
        Pl[wid][lg*4 + r][nf*16 + lr] = pl;
      }
#pragma unroll
    for (int r = 0; r < 4; ++r) {
      float s = rsum[r];
      s += __shfl_xor(s, 1); s += __shfl_xor(s, 2);
      s += __shfl_xor(s, 4); s += __shfl_xor(s, 8);
      l_run[r] = l_run[r] * corr[r] + s;
    }
#pragma unroll
    for (int df = 0; df < 8; ++df)
#pragma unroll
      for (int r = 0; r < 4; ++r) acc_o[df][r] *= corr[r];

    __syncthreads();

    // phase B: issue K(t+1) stage; PV
    if (t < 15) {
#pragma unroll
      for (int i = 0; i < 4; ++i) {
        int idx = wid * 4 + i;
        const u16* src = (idx < 16) ? (gKh + (t+1)*8192 + idx*512)
                                    : (gKl + (t+1)*8192 + (idx-16)*512);
        u16* dst = Klds + ((idx < 16) ? idx*512 : 8192 + (idx-16)*512);
        gload_lds16(src + loff, dst);
      }
    }

    s16x8 pa_h[2], pa_l[2];
#pragma unroll
    for (int kc = 0; kc < 2; ++kc) {
      pa_h[kc] = *reinterpret_cast<const s16x8*>(&Ph[wid][lr][kc*32 + lg*8]);
      pa_l[kc] = *reinterpret_cast<const s16x8*>(&Pl[wid][lr][kc*32 + lg*8]);
    }
#pragma unroll
    for (int df = 0; df < 8; ++df) {
      s16x8 vh8[2], vl8[2];
#pragma unroll
      for (int kc = 0; kc < 2; ++kc) {
        vh8[kc] = *reinterpret_cast<const s16x8*>(&Vlds[kc*4096 + df*512 + loff]);
        vl8[kc] = *reinterpret_cast<const s16x8*>(&Vlds[8192 + kc*4096 + df*512 + loff]);
      }
#pragma unroll
      for (int kc = 0; kc < 2; ++kc) {
        acc_o[df] = MFMA(pa_h[kc], vh8[kc], acc_o[df]);
        acc_o[df] = MFMA(pa_l[kc], vh8[kc], acc_o[df]);
        acc_o[df] = MFMA(pa_h[kc], vl8[kc], acc_o[df]);
      }
    }
    __syncthreads();
  }

  float inv_l[4];
#pragma unroll
  for (int r = 0; r < 4; ++r) inv_l[r] = 1.f / l_run[r];
#pragma unroll
  for (int df = 0; df < 8; ++df)
#pragma unroll
    for (int r = 0; r < 4; ++r) {
      int row = qt * 128 + wid * 16 + lg * 4 + r;
      ob[((size_t)((b * S_ + row) * HQ_ + h)) * HD_ + df*16 + lr] = acc_o[df][r] * inv_l[r];
    }
}

// ===========================================================================
// Hybrid GEMM. A staged in-kernel (swizzled granule: g' = akc*16+((r+4akc)&15)
// -> 2-way write banks, free), B pre-fragmented (gload_lds).
// modes: 0=QA+K+V(256, WS144) 1=Q-half(128) 2=K+V(128) 3=OUT(256)
//        4=OUT-half(128) 5=MERGED QKV (384 blocks, WS185 layout)
// WS185 WF u16 offsets: WqA 0/8388608; WqB 16777216/25165824;
//   Wk 33554432/37748736; Wv 41943040/46137344.
// ===========================================================================
__global__ __launch_bounds__(512) void gemm_p1(
    const float* __restrict__ X, const float* __restrict__ abp,
    const u16* __restrict__ WF,
    float* __restrict__ qb, float* __restrict__ kb, float* __restrict__ vb,
    float* __restrict__ outp, int mode, int col0)
{
  __shared__ __attribute__((aligned(16))) u16 lds[40960];
  u16* ah0 = lds;
  u16* al0 = lds + 4096;
  u16* ah1 = lds + 8192;
  u16* al1 = lds + 12288;
  u16* bh0 = lds + 16384;
  u16* bh1 = lds + 24576;
  u16* blb = lds + 32768;

  const int id   = blockIdx.x;
  const int cpx  = gridDim.x >> 3;
  const int swz  = (id & 7) * cpx + (id >> 3);

  const float* A; const u16* Bh; const u16* Bl; float* C;
  int ldc, Nc16, mb, nb;
  if (mode == 0) {
    if (swz < 128)      { A=X; Bh=WF;          Bl=WF+8388608;  C=qb; ldc=4096; Nc16=128; mb=swz>>3; nb=swz&7; }
    else if (swz < 192) { int u=swz-128; A=X; Bh=WF+16777216; Bl=WF+20971520; C=kb; ldc=1024; Nc16=64; mb=u>>2; nb=u&3; }
    else                { int u=swz-192; A=X; Bh=WF+25165824; Bl=WF+29360128; C=vb; ldc=1024; Nc16=64; mb=u>>2; nb=u&3; }
  } else if (mode == 1) {
    A=X; Bh=WF; Bl=WF+8388608; C=qb+col0; ldc=4096; Nc16=128; mb=swz>>3; nb=swz&7;
  } else if (mode == 2) {
    if (swz < 64) { A=X; Bh=WF;          Bl=WF+4194304;  C=kb; ldc=1024; Nc16=64; mb=swz>>2; nb=swz&3; }
    else          { int u=swz-64; A=X; Bh=WF+8388608; Bl=WF+12582912; C=vb; ldc=1024; Nc16=64; mb=u>>2; nb=u&3; }
  } else if (mode == 3) {
    A=abp; Bh=WF; Bl=WF+16777216; C=outp; ldc=4096; Nc16=256; mb=swz>>4; nb=swz&15;
  } else if (mode == 4) {
    A=abp; Bh=WF; Bl=WF+8388608; C=outp+col0; ldc=4096; Nc16=128; mb=swz>>3; nb=swz&7;
  } else {  // mode 5: merged QKV, 384 blocks
    if (swz < 128)      { A=X; Bh=WF;          Bl=WF+8388608;  C=qb;      ldc=4096; Nc16=128; mb=swz>>3; nb=swz&7; }
    else if (swz < 256) { int u=swz-128; A=X; Bh=WF+16777216; Bl=WF+25165824; C=qb+2048; ldc=4096; Nc16=128; mb=u>>3; nb=u&7; }
    else if (swz < 320) { int u=swz-256; A=X; Bh=WF+33554432; Bl=WF+37748736; C=kb; ldc=1024; Nc16=64; mb=u>>2; nb=u&3; }
    else                { int u=swz-320; A=X; Bh=WF+41943040; Bl=WF+46137344; C=vb; ldc=1024; Nc16=64; mb=u>>2; nb=u&3; }
  }

  const int tid  = threadIdx.x;
  const int lane = tid & 63;
  const int wid  = tid >> 6;
  const int mtb  = (wid >> 2) * 4;
  const int ntb  = (wid & 3) * 4;
  const int loff = lane * 8;
  const int lg   = lane >> 4;
  const int lr_  = lane & 15;
  // swizzled A granule for reads: (akc=lg, r=lr) stored at akc*16+((r+4akc)&15)
  const int aoff = (lg*16 + ((lr_ + 4*lg) & 15)) * 8;

  const int arow = tid >> 2;
  const int akc  = tid & 3;
  const float* aptr = A + (size_t)(mb*128 + arow) * 4096 + akc*8;
  const int awr = (arow >> 4)*512 + (akc*16 + (((arow & 15) + 4*akc) & 15))*8;

  const size_t bStep = (size_t)Nc16 * 512;
  const u16* pBh = Bh + (size_t)nb*16*512 + loff;
  const u16* pBl = Bl + (size_t)nb*16*512 + loff;

  f32x4 acc[4][4];
#pragma unroll
  for (int i = 0; i < 4; ++i)
#pragma unroll
    for (int j = 0; j < 4; ++j) acc[i][j] = (f32x4){0.f, 0.f, 0.f, 0.f};

  float4 ra0 = *reinterpret_cast<const float4*>(aptr);
  float4 ra1 = *reinterpret_cast<const float4*>(aptr + 4);
  {
    uint4 h4, l4; pack8(ra0, ra1, h4, l4);
    *reinterpret_cast<uint4*>(&ah0[awr]) = h4;
    *reinterpret_cast<uint4*>(&al0[awr]) = l4;
  }
  gload_lds16(pBh + (size_t)wid*512,     bh0 + wid*512);
  gload_lds16(pBh + (size_t)(wid+8)*512, bh0 + (wid+8)*512);
  ra0 = *reinterpret_cast<const float4*>(aptr + 32);
  ra1 = *reinterpret_cast<const float4*>(aptr + 36);
  __syncthreads();

  for (int kt = 0; kt < 128; ++kt) {
    u16* cAh = (kt & 1) ? ah1 : ah0;
    u16* cAl = (kt & 1) ? al1 : al0;
    u16* nAh = (kt & 1) ? ah0 : ah1;
    u16* nAl = (kt & 1) ? al0 : al1;
    u16* cBh = (kt & 1) ? bh1 : bh0;
    u16* nBh = (kt & 1) ? bh0 : bh1;

    gload_lds16(pBl + (size_t)kt*bStep + (size_t)wid*512,     blb + wid*512);
    gload_lds16(pBl + (size_t)kt*bStep + (size_t)(wid+8)*512, blb + (wid+8)*512);
    if (kt < 127) {
      gload_lds16(pBh + (size_t)(kt+1)*bStep + (size_t)wid*512,     nBh + wid*512);
      gload_lds16(pBh + (size_t)(kt+1)*bStep + (size_t)(wid+8)*512, nBh + (wid+8)*512);
    }
    s16x8 a_h[4], a_l[4], b_h[4];
#pragma unroll
    for (int mf = 0; mf < 4; ++mf) {
      a_h[mf] = *reinterpret_cast<const s16x8*>(&cAh[(mtb+mf)*512 + aoff]);
      a_l[mf] = *reinterpret_cast<const s16x8*>(&cAl[(mtb+mf)*512 + aoff]);
    }
#pragma unroll
    for (int nf = 0; nf < 4; ++nf)
      b_h[nf] = *reinterpret_cast<const s16x8*>(&cBh[(ntb+nf)*512 + loff]);
#pragma unroll
    for (int mf = 0; mf < 4; ++mf)
#pragma unroll
      for (int nf = 0; nf < 4; ++nf) {
        acc[mf][nf] = MFMA(a_h[mf], b_h[nf], acc[mf][nf]);
        acc[mf][nf] = MFMA(a_l[mf], b_h[nf], acc[mf][nf]);
      }
    __syncthreads();

    s16x8 b_l[4];
#pragma unroll
    for (int nf = 0; nf < 4; ++nf)
      b_l[nf] = *reinterpret_cast<const s16x8*>(&blb[(ntb+nf)*512 + loff]);
#pragma unroll
    for (int mf = 0; mf < 4; ++mf)
#pragma unroll
      for (int nf = 0; nf < 4; ++nf)
        acc[mf][nf] = MFMA(a_h[mf], b_l[nf], acc[mf][nf]);
    if (kt < 127) {
      uint4 h4, l4; pack8(ra0, ra1, h4, l4);
      *reinterpret_cast<uint4*>(&nAh[awr]) = h4;
      *reinterpret_cast<uint4*>(&nAl[awr]) = l4;
      if (kt < 126) {
        ra0 = *reinterpret_cast<const float4*>(aptr + (kt+2)*32);
        ra1 = *reinterpret_cast<const float4*>(aptr + (kt+2)*32 + 4);
      }
    }
    __syncthreads();
  }

  const int row0 = mb*128 + (wid >> 2) * 64;
  const int nloc = nb*256 + (wid & 3) * 64;
#pragma unroll
  for (int mf = 0; mf < 4; ++mf)
#pragma unroll
    for (int nf = 0; nf < 4; ++nf)
#pragma unroll
      for (int r = 0; r < 4; ++r)
        C[(size_t)(row0 + mf*16 + lg*4 + r) * ldc + nloc + nf*16 + lr_] = acc[mf][nf][r];
}

// ===========================================================================
// Fallback GEMM (round-1, proven) used only if ws < 112MB.
// ===========================================================================
__device__ __forceinline__ void gemm_core_128x256(
    const float* __restrict__ A, const float* __restrict__ W,
    float* __restrict__ C, int ldw, int m0, int n0)
{
  __shared__ u16 Ah[128][40];
  __shared__ u16 Al[128][40];
  __shared__ u16 Bh[256][40];
  __shared__ u16 Bl[256][40];

  const int tid  = threadIdx.x;
  const int lane = tid & 63;
  const int wid  = tid >> 6;
  const int wm   = (wid >> 2) * 64;
  const int wn   = (wid & 3) * 64;
  const int lr   = lane & 15;
  const int lg   = lane >> 4;

  f32x4 acc[4][4];
#pragma unroll
  for (int i = 0; i < 4; ++i)
#pragma unroll
    for (int j = 0; j < 4; ++j) acc[i][j] = (f32x4){0.f, 0.f, 0.f, 0.f};

  const int ar  = tid >> 3;
  const int ak  = (tid & 7) * 4;
  const int bn  = tid & 255;
  const int bk0 = (tid >> 8) * 16;

  for (int kt = 0; kt < D_ / 32; ++kt) {
    const int k0 = kt * 32;
    __syncthreads();
#pragma unroll
    for (int j = 0; j < 2; ++j) {
      int r = ar + 64 * j;
      float4 v = *reinterpret_cast<const float4*>(&A[(size_t)(m0 + r) * D_ + k0 + ak]);
      u16 h0,h1,h2,h3,l0,l1,l2,l3;
      split2(v.x,h0,l0); split2(v.y,h1,l1); split2(v.z,h2,l2); split2(v.w,h3,l3);
      *reinterpret_cast<s16x4*>(&Ah[r][ak]) = (s16x4){(short)h0,(short)h1,(short)h2,(short)h3};
      *reinterpret_cast<s16x4*>(&Al[r][ak]) = (s16x4){(short)l0,(short)l1,(short)l2,(short)l3};
    }
    {
      const float* wp = W + (size_t)(k0 + bk0) * ldw + (n0 + bn);
#pragma unroll
      for (int q = 0; q < 4; ++q) {
        float v0 = wp[(q*4 + 0) * (size_t)ldw];
        float v1 = wp[(q*4 + 1) * (size_t)ldw];
        float v2 = wp[(q*4 + 2) * (size_t)ldw];
        float v3 = wp[(q*4 + 3) * (size_t)ldw];
        u16 h0,h1,h2,h3,l0,l1,l2,l3;
        split2(v0,h0,l0); split2(v1,h1,l1); split2(v2,h2,l2); split2(v3,h3,l3);
        *reinterpret_cast<s16x4*>(&Bh[bn][bk0 + q*4]) = (s16x4){(short)h0,(short)h1,(short)h2,(short)h3};
        *reinterpret_cast<s16x4*>(&Bl[bn][bk0 + q*4]) = (s16x4){(short)l0,(short)l1,(short)l2,(short)l3};
      }
    }
    __syncthreads();
    s16x8 a_h[4], a_l[4], b_h[4], b_l[4];
#pragma unroll
    for (int mf = 0; mf < 4; ++mf) {
      a_h[mf] = *reinterpret_cast<const s16x8*>(&Ah[wm + mf*16 + lr][lg*8]);
      a_l[mf] = *reinterpret_cast<const s16x8*>(&Al[wm + mf*16 + lr][lg*8]);
    }
#pragma unroll
    for (int nf = 0; nf < 4; ++nf) {
      b_h[nf] = *reinterpret_cast<const s16x8*>(&Bh[wn + nf*16 + lr][lg*8]);
      b_l[nf] = *reinterpret_cast<const s16x8*>(&Bl[wn + nf*16 + lr][lg*8]);
    }
#pragma unroll
    for (int mf = 0; mf < 4; ++mf)
#pragma unroll
      for (int nf = 0; nf < 4; ++nf) {
        acc[mf][nf] = MFMA(a_h[mf], b_h[nf], acc[mf][nf]);
        acc[mf][nf] = MFMA(a_l[mf], b_h[nf], acc[mf][nf]);
        acc[mf][nf] = MFMA(a_h[mf], b_l[nf], acc[mf][nf]);
      }
  }
#pragma unroll
  for (int mf = 0; mf < 4; ++mf)
#pragma unroll
    for (int nf = 0; nf < 4; ++nf)
#pragma unroll
      for (int r = 0; r < 4; ++r) {
        int row = m0 + wm + mf*16 + lg*4 + r;
        int col = n0 + wn + nf*16 + lr;
        C[(size_t)row * ldw + col] = acc[mf][nf][r];
      }
}

__global__ __launch_bounds__(512) void gemm_qkv_kernel(
    const float* __restrict__ X,
    const float* __restrict__ Wq, const float* __restrict__ Wk,
    const float* __restrict__ Wv,
    float* __restrict__ qb, float* __restrict__ kb, float* __restrict__ vb)
{
  int nbv = blockIdx.x;
  int m0 = blockIdx.y * 128;
  const float* W; float* C; int ldw, n0;
  if (nbv < 16)      { W = Wq; C = qb; ldw = HQ_*HD_;  n0 = nbv * 256; }
  else if (nbv < 20) { W = Wk; C = kb; ldw = HKV_*HD_; n0 = (nbv-16) * 256; }
  else               { W = Wv; C = vb; ldw = HKV_*HD_; n0 = (nbv-20) * 256; }
  gemm_core_128x256(X, W, C, ldw, m0, n0);
}

__global__ __launch_bounds__(512) void gemm_out_kernel(
    const float* __restrict__ A, const float* __restrict__ Wo, float* __restrict__ out)
{
  gemm_core_128x256(A, Wo, out, D_, blockIdx.y * 128, blockIdx.x * 256);
}

// ---------------------------------------------------------------------------
// RoPE in-place (fallback tier only).
// ---------------------------------------------------------------------------
__global__ __launch_bounds__(256) void rope_kernel(
    float* __restrict__ qb, float* __restrict__ kb,
    const float* __restrict__ cosT, const float* __restrict__ sinT)
{
  int idx = blockIdx.x * 256 + threadIdx.x;
  const int nq = B_ * S_ * HQ_ * (HD_/2);
  const int nk = B_ * S_ * HKV_ * (HD_/2);
  if (idx < nq) {
    int j = idx & 63;
    int h = (idx >> 6) & (HQ_ - 1);
    int bs = idx >> 11;
    float* p = qb + ((size_t)bs * HQ_ + h) * HD_;
    const float* cp = cosT + (size_t)bs * HD_;
    const float* sp = sinT + (size_t)bs * HD_;
    float x1 = p[j], x2 = p[j + 64];
    p[j]      = x1 * cp[j]      - x2 * sp[j];
    p[j + 64] = x2 * cp[j + 64] + x1 * sp[j + 64];
  } else if (idx < nq + nk) {
    int t2 = idx - nq;
    int j = t2 & 63;
    int h = (t2 >> 6) & (HKV_ - 1);
    int bs = t2 >> 9;
    float* p = kb + ((size_t)bs * HKV_ + h) * HD_;
    const float* cp = cosT + (size_t)bs * HD_;
    const float* sp = sinT + (size_t)bs * HD_;
    float x1 = p[j], x2 = p[j + 64];
    p[j]      = x1 * cp[j]      - x2 * sp[j];
    p[j + 64] = x2 * cp[j + 64] + x1 * sp[j + 64];
  }
}

// ---------------------------------------------------------------------------
// Flash attention (round-1 verified) — fallback tier only.
// ---------------------------------------------------------------------------
__global__ __launch_bounds__(512) void attn_kernel(
    const float* __restrict__ qb, const float* __restrict__ kb,
    const float* __restrict__ vb, float* __restrict__ ob)
{
  __shared__ u16 Kh[64][136], Kl[64][136];
  __shared__ u16 Vh[128][72], Vl[128][72];
  __shared__ u16 Ph[8][16][72], Pl[8][16][72];

  const int tid  = threadIdx.x;
  const int lane = tid & 63;
  const int wid  = tid >> 6;
  const int lr   = lane & 15;
  const int lg   = lane >> 4;
  const int qt   = blockIdx.x;
  const int bh   = blockIdx.y;
  const int b    = bh >> 5, h = bh & 31, kvh = h >> 2;

  s16x8 qh[4], ql[4];
  {
    const int qrow = qt * 128 + wid * 16 + lr;
    const float* qp = qb + ((size_t)((b * S_ + qrow) * HQ_ + h)) * HD_;
#pragma unroll
    for (int kc = 0; kc < 4; ++kc) {
      const float* qp2 = qp + kc * 32 + lg * 8;
      float4 v0 = *reinterpret_cast<const float4*>(qp2);
      float4 v1 = *reinterpret_cast<const float4*>(qp2 + 4);
      u16 hh[8], ll[8];
      split2(v0.x,hh[0],ll[0]); split2(v0.y,hh[1],ll[1]);
      split2(v0.z,hh[2],ll[2]); split2(v0.w,hh[3],ll[3]);
      split2(v1.x,hh[4],ll[4]); split2(v1.y,hh[5],ll[5]);
      split2(v1.z,hh[6],ll[6]); split2(v1.w,hh[7],ll[7]);
      qh[kc] = (s16x8){(short)hh[0],(short)hh[1],(short)hh[2],(short)hh[3],
                       (short)hh[4],(short)hh[5],(short)hh[6],(short)hh[7]};
      ql[kc] = (s16x8){(short)ll[0],(short)ll[1],(short)ll[2],(short)ll[3],
                       (short)ll[4],(short)ll[5],(short)ll[6],(short)ll[7]};
    }
  }

  f32x4 acc_o[8];
#pragma unroll
  for (int df = 0; df < 8; ++df) acc_o[df] = (f32x4){0.f, 0.f, 0.f, 0.f};
  float m_run[4] = {-1e30f, -1e30f, -1e30f, -1e30f};
  float l_run[4] = {0.f, 0.f, 0.f, 0.f};

  const float* kbase = kb + ((size_t)(b * S_) * HKV_ + kvh) * HD_;
  const float* vbase = vb + ((size_t)(b * S_) * HKV_ + kvh) * HD_;

  for (int t = 0; t < S_ / 64; ++t) {
    const int kk0 = t * 64;
    __syncthreads();
#pragma unroll
    for (int j = 0; j < 4; ++j) {
      int idx = tid + 512 * j;
      int kk = idx >> 5, dq = (idx & 31) * 4;
      float4 v = *reinterpret_cast<const float4*>(kbase + (size_t)(kk0 + kk) * (HKV_*HD_) + dq);
      u16 h0,h1,h2,h3,l0,l1,l2,l3;
      split2(v.x,h0,l0); split2(v.y,h1,l1); split2(v.z,h2,l2); split2(v.w,h3,l3);
      *reinterpret_cast<s16x4*>(&Kh[kk][dq]) = (s16x4){(short)h0,(short)h1,(short)h2,(short)h3};
      *reinterpret_cast<s16x4*>(&Kl[kk][dq]) = (s16x4){(short)l0,(short)l1,(short)l2,(short)l3};
    }
    {
      int d = tid & 127;
      int kkb = (tid >> 7) * 16;
      const float* vcol = vbase + d;
#pragma unroll
      for (int jq = 0; jq < 4; ++jq) {
        u16 h4[4], l4[4];
#pragma unroll
        for (int e = 0; e < 4; ++e) {
          float val = vcol[(size_t)(kk0 + kkb + jq*4 + e) * (HKV_*HD_)];
          split2(val, h4[e], l4[e]);
        }
        *reinterpret_cast<s16x4*>(&Vh[d][kkb + jq*4]) = (s16x4){(short)h4[0],(short)h4[1],(short)h4[2],(short)h4[3]};
        *reinterpret_cast<s16x4*>(&Vl[d][kkb + jq*4]) = (s16x4){(short)l4[0],(short)l4[1],(short)l4[2],(short)l4[3]};
      }
    }
    __syncthreads();
    f32x4 accs[4];
#pragma unroll
    for (int nf = 0; nf < 4; ++nf) accs[nf] = (f32x4){0.f, 0.f, 0.f, 0.f};
#pragma unroll
    for (int nf = 0; nf < 4; ++nf) {
      int krow = nf * 16 + lr;
#pragma unroll
      for (int kc = 0; kc < 4; ++kc) {
        s16x8 kh8 = *reinterpret_cast<const s16x8*>(&Kh[krow][kc*32 + lg*8]);
        s16x8 kl8 = *reinterpret_cast<const s16x8*>(&Kl[krow][kc*32 + lg*8]);
        accs[nf] = MFMA(qh[kc], kh8, accs[nf]);
        accs[nf] = MFMA(ql[kc], kh8, accs[nf]);
        accs[nf] = MFMA(qh[kc], kl8, accs[nf]);
      }
    }
#pragma unroll
    for (int nf = 0; nf < 4; ++nf) accs[nf] *= SCALE_;
    float corr[4], rsum[4];
#pragma unroll
    for (int r = 0; r < 4; ++r) {
      float t0 = fmaxf(fmaxf(accs[0][r], accs[1][r]), fmaxf(accs[2][r], accs[3][r]));
      t0 = fmaxf(t0, __shfl_xor(t0, 1));
      t0 = fmaxf(t0, __shfl_xor(t0, 2));
      t0 = fmaxf(t0, __shfl_xor(t0, 4));
      t0 = fmaxf(t0, __shfl_xor(t0, 8));
      float mnew = fmaxf(m_run[r], t0);
      corr[r] = __expf(m_run[r] - mnew);
      m_run[r] = mnew;
      rsum[r] = 0.f;
    }
#pragma unroll
    for (int nf = 0; nf < 4; ++nf)
#pragma unroll
      for (int r = 0; r < 4; ++r) {
        float p = __expf(accs[nf][r] - m_run[r]);
        rsum[r] += p;
        u16 ph, pl;
        split2(p, ph, pl);
        Ph[wid][lg*4 + r][nf*16 + lr] = ph;
        Pl[wid][lg*4 + r][nf*16 + lr] = pl;
      }
#pragma unroll
    for (int r = 0; r < 4; ++r) {
      float s = rsum[r];
      s += __shfl_xor(s, 1); s += __shfl_xor(s, 2);
      s += __shfl_xor(s, 4); s += __shfl_xor(s, 8);
      l_run[r] = l_run[r] * corr[r] + s;
    }
#pragma unroll
    for (int df = 0; df < 8; ++df)
#pragma unroll
      for (int r = 0; r < 4; ++r) acc_o[df][r] *= corr[r];
    s16x8 pa_h[2], pa_l[2];
#pragma unroll
    for (int kc = 0; kc < 2; ++kc) {
      pa_h[kc] = *reinterpret_cast<const s16x8*>(&Ph[wid][lr][kc*32 + lg*8]);
      pa_l[kc] = *reinterpret_cast<const s16x8*>(&Pl[wid][lr][kc*32 + lg*8]);
    }
#pragma unroll
    for (int df = 0; df < 8; ++df) {
      int dcol = df * 16 + lr;
#pragma unroll
      for (int kc = 0; kc < 2; ++kc) {
        s16x8 vh8 = *reinterpret_cast<const s16x8*>(&Vh[dcol][kc*32 + lg*8]);
        s16x8 vl8 = *reinterpret_cast<const s16x8*>(&Vl[dcol][kc*32 + lg*8]);
        acc_o[df] = MFMA(pa_h[kc], vh8, acc_o[df]);
        acc_o[df] = MFMA(pa_l[kc], vh8, acc_o[df]);
        acc_o[df] = MFMA(pa_h[kc], vl8, acc_o[df]);
      }
    }
  }
  float inv_l[4];
#pragma unroll
  for (int r = 0; r < 4; ++r) inv_l[r] = 1.f / l_run[r];
#pragma unroll
  for (int df = 0; df < 8; ++df)
#pragma unroll
    for (int r = 0; r < 4; ++r) {
      int row = qt * 128 + wid * 16 + lg * 4 + r;
      ob[((size_t)((b * S_ + row) * HQ_ + h)) * HD_ + df*16 + lr] = acc_o[df][r] * inv_l[r];
    }
}

// ---------------------------------------------------------------------------
extern "C" void kernel_launch(void* const* d_in, const int* in_sizes, int n_in,
                              void* d_out, int out_size, void* d_ws, size_t ws_size,
                              hipStream_t stream)
{
  const float* hs   = (const float*)d_in[0];
  const float* cosT = (const float*)d_in[1];
  const float* sinT = (const float*)d_in[2];
  const float* Wq   = (const float*)d_in[3];
  const float* Wk   = (const float*)d_in[4];
  const float* Wv   = (const float*)d_in[5];
  const float* Wo   = (const float*)d_in[6];
  float* out = (float*)d_out;

  float* qb = (float*)d_ws;                 // 8388608 f32
  float* kb = qb + 8388608;                 // 2097152
  float* vb = kb + 2097152;                 // 2097152
  float* ab = vb + 2097152;                 // 8388608
  u16*   WF = (u16*)(ab + 8388608);

  const size_t WS185 = 184549376ULL;        // base 84MB + 100.6MB WF
  const size_t WS144 = 150994944ULL;
  const size_t WS112 = 117440512ULL;
  int total = B_*S_*HQ_*(HD_/2) + B_*S_*HKV_*(HD_/2);

  u16* KFh = WF;
  u16* KFl = WF + 2097152;
  u16* VFh = WF + 4194304;
  u16* VFl = WF + 6291456;

  if (ws_size >= WS185) {
    // merged QKV: WqA 0/8388608, WqB 16777216/25165824, Wk 33554432/37748736,
    // Wv 41943040/46137344
    frag_b<<<dim3(128,32), 256, 0, stream>>>(Wq, WF,          WF+8388608,  4096, 0,    128);
    frag_b<<<dim3(128,32), 256, 0, stream>>>(Wq, WF+16777216, WF+25165824, 4096, 2048, 128);
    frag_b<<<dim3(128,16), 256, 0, stream>>>(Wk, WF+33554432, WF+37748736, 1024, 0,    64);
    frag_b<<<dim3(128,16), 256, 0, stream>>>(Wv, WF+41943040, WF+46137344, 1024, 0,    64);
    gemm_p1<<<384, 512, 0, stream>>>(hs, ab, WF, qb, kb, vb, out, 5, 0);       // QKV merged
    frag_kv<<<1024, 256, 0, stream>>>(kb, vb, cosT, sinT, KFh, KFl, VFh, VFl);
    attn3<<<dim3(8, 64), 512, 0, stream>>>(qb, cosT, sinT, KFh, KFl, VFh, VFl, ab);
    frag_b<<<dim3(128,64), 256, 0, stream>>>(Wo, WF, WF+16777216, 4096, 0, 256);
    gemm_p1<<<256, 512, 0, stream>>>(hs, ab, WF, qb, kb, vb, out, 3, 0);       // OUT
  } else if (ws_size >= WS144) {
    frag_b<<<dim3(128,32), 256, 0, stream>>>(Wq, WF,          WF+8388608,  4096, 0,    128);
    frag_b<<<dim3(128,16), 256, 0, stream>>>(Wk, WF+16777216, WF+20971520, 1024, 0,    64);
    frag_b<<<dim3(128,16), 256, 0, stream>>>(Wv, WF+25165824, WF+29360128, 1024, 0,    64);
    gemm_p1<<<256, 512, 0, stream>>>(hs, ab, WF, qb, kb, vb, out, 0, 0);       // QA + K + V
    frag_b<<<dim3(128,32), 256, 0, stream>>>(Wq, WF,          WF+8388608,  4096, 2048, 128);
    gemm_p1<<<128, 512, 0, stream>>>(hs, ab, WF, qb, kb, vb, out, 1, 2048);    // QB
    frag_kv<<<1024, 256, 0, stream>>>(kb, vb, cosT, sinT, KFh, KFl, VFh, VFl);
    attn3<<<dim3(8, 64), 512, 0, stream>>>(qb, cosT, sinT, KFh, KFl, VFh, VFl, ab);
    frag_b<<<dim3(128,64), 256, 0, stream>>>(Wo, WF,          WF+16777216, 4096, 0,    256);
    gemm_p1<<<256, 512, 0, stream>>>(hs, ab, WF, qb, kb, vb, out, 3, 0);       // OUT
  } else if (ws_size >= WS112) {
    frag_b<<<dim3(128,32), 256, 0, stream>>>(Wq, WF, WF+8388608, 4096, 0, 128);
    gemm_p1<<<128, 512, 0, stream>>>(hs, ab, WF, qb, kb, vb, out, 1, 0);       // QA
    frag_b<<<dim3(128,32), 256, 0, stream>>>(Wq, WF, WF+8388608, 4096, 2048, 128);
    gemm_p1<<<128, 512, 0, stream>>>(hs, ab, WF, qb, kb, vb, out, 1, 2048);    // QB
    frag_b<<<dim3(128,16), 256, 0, stream>>>(Wk, WF,           WF+4194304,  1024, 0, 64);
    frag_b<<<dim3(128,16), 256, 0, stream>>>(Wv, WF+8388608,   WF+12582912, 1024, 0, 64);
    gemm_p1<<<128, 512, 0, stream>>>(hs, ab, WF, qb, kb, vb, out, 2, 0);       // K + V
    frag_kv<<<1024, 256, 0, stream>>>(kb, vb, cosT, sinT, KFh, KFl, VFh, VFl);
    attn3<<<dim3(8, 64), 512, 0, stream>>>(qb, cosT, sinT, KFh, KFl, VFh, VFl, ab);
    frag_b<<<dim3(128,32), 256, 0, stream>>>(Wo, WF, WF+8388608, 4096, 0, 128);
    gemm_p1<<<128, 512, 0, stream>>>(hs, ab, WF, qb, kb, vb, out, 4, 0);       // OUT-A
    frag_b<<<dim3(128,32), 256, 0, stream>>>(Wo, WF, WF+8388608, 4096, 2048, 128);
    gemm_p1<<<128, 512, 0, stream>>>(hs, ab, WF, qb, kb, vb, out, 4, 2048);    // OUT-B
  } else {
    gemm_qkv_kernel<<<dim3(24, 16), 512, 0, stream>>>(hs, Wq, Wk, Wv, qb, kb, vb);
    rope_kernel<<<dim3((total + 255)/256), 256, 0, stream>>>(qb, kb, cosT, sinT);
    attn_kernel<<<dim3(8, 64), 512, 0, stream>>>(qb, kb, vb, ab);
    gemm_out_kernel<<<dim3(16, 16), 512, 0, stream>>>(ab, Wo, out);
  }
}

// Round 8
// 698.152 us; speedup vs baseline: 1.5006x; 1.0207x over previous
//
#include <hip/hip_runtime.h>

#define B_   2
#define S_   1024
#define D_   4096
#define HQ_  32
#define HKV_ 8
#define HD_  128
#define SCALE_ 0.08838834764831845f

typedef unsigned short u16;
typedef __attribute__((ext_vector_type(8))) short s16x8;
typedef __attribute__((ext_vector_type(4))) short s16x4;
typedef __attribute__((ext_vector_type(4))) float f32x4;

#define MFMA(a,b,c) __builtin_amdgcn_mfma_f32_16x16x32_bf16((a),(b),(c),0,0,0)

__device__ __forceinline__ u16 bf16_rne(float x) {
  unsigned u = __float_as_uint(x);
  u += 0x7fffu + ((u >> 16) & 1u);
  return (u16)(u >> 16);
}
__device__ __forceinline__ float bf16_up(u16 h) {
  return __uint_as_float(((unsigned)h) << 16);
}
__device__ __forceinline__ void split2(float x, u16& h, u16& l) {
  h = bf16_rne(x);
  l = bf16_rne(x - bf16_up(h));
}

// packed hi/lo split: 2 elems -> 1 u32 hi + 1 u32 lo
__device__ __forceinline__ void cvt_hi_lo(float a, float b, unsigned& hi, unsigned& lo) {
  unsigned h, l;
  asm("v_cvt_pk_bf16_f32 %0, %1, %2" : "=v"(h) : "v"(a), "v"(b));
  float ra = __uint_as_float(h << 16);
  float rb = __uint_as_float(h & 0xffff0000u);
  float la = a - ra, lb = b - rb;
  asm("v_cvt_pk_bf16_f32 %0, %1, %2" : "=v"(l) : "v"(la), "v"(lb));
  hi = h; lo = l;
}
__device__ __forceinline__ void pack8(float4 x, float4 y, uint4& h, uint4& l) {
  unsigned h0,h1,h2,h3,l0,l1,l2,l3;
  cvt_hi_lo(x.x, x.y, h0, l0);
  cvt_hi_lo(x.z, x.w, h1, l1);
  cvt_hi_lo(y.x, y.y, h2, l2);
  cvt_hi_lo(y.z, y.w, h3, l3);
  h = make_uint4(h0,h1,h2,h3); l = make_uint4(l0,l1,l2,l3);
}

// ---- async global->LDS, 16B per lane (dest = wave-uniform base) ----
typedef const __attribute__((address_space(1))) void* gas_ptr;
typedef __attribute__((address_space(3))) void* las_ptr;
__device__ __forceinline__ void gload_lds16(const void* g, void* l) {
  __builtin_amdgcn_global_load_lds((gas_ptr)g, (las_ptr)l, 16, 0, 0);
}

// ===========================================================================
// frag_b1 (round-7 layout, WS185 fallback): [kt32][nt][512]
// ===========================================================================
__global__ __launch_bounds__(256) void frag_b1(
    const float* __restrict__ W, u16* __restrict__ dh, u16* __restrict__ dl,
    int N, int n0, int Nc16)
{
  __shared__ float T[32][68];
  const int kt = blockIdx.x, nbk = blockIdx.y;
  const int tid = threadIdx.x;
#pragma unroll
  for (int rep = 0; rep < 2; ++rep) {
    int idx = tid + rep * 256;
    int row = idx >> 4, c4 = (idx & 15) * 4;
    float4 v = *reinterpret_cast<const float4*>(&W[(size_t)(kt*32 + row) * N + n0 + nbk*64 + c4]);
    *reinterpret_cast<float4*>(&T[row][c4]) = v;
  }
  __syncthreads();
  const size_t base = ((size_t)kt * Nc16 + nbk * 4) * 512;
  int c = tid;
  int nt = c >> 6, l = c & 63, kc = l >> 4, r = l & 15;
  u16 hh[8], ll[8];
#pragma unroll
  for (int j = 0; j < 8; ++j) split2(T[kc*8 + j][nt*16 + r], hh[j], ll[j]);
  *reinterpret_cast<s16x8*>(&dh[base + (size_t)c * 8]) =
    (s16x8){(short)hh[0],(short)hh[1],(short)hh[2],(short)hh[3],
            (short)hh[4],(short)hh[5],(short)hh[6],(short)hh[7]};
  *reinterpret_cast<s16x8*>(&dl[base + (size_t)c * 8]) =
    (s16x8){(short)ll[0],(short)ll[1],(short)ll[2],(short)ll[3],
            (short)ll[4],(short)ll[5],(short)ll[6],(short)ll[7]};
}

// ===========================================================================
// frag_b2 (NEW layout for 256-core): [kt64][nt][kk2][512]
// Element (k, n0+nc): off = ((kt64*Nc16 + nt)*2 + kk)*512 + l*8 + j
//   kt64=k>>6, kk=(k>>5)&1, l=((k&31)>>3)*16+(nc&15), j=k&7.
// grid (128 kt32, Nc/64), 256 thr.
// ===========================================================================
__global__ __launch_bounds__(256) void frag_b2(
    const float* __restrict__ W, u16* __restrict__ dh, u16* __restrict__ dl,
    int N, int n0, int Nc16)
{
  __shared__ float T[32][68];
  const int kt = blockIdx.x, nbk = blockIdx.y;
  const int tid = threadIdx.x;
#pragma unroll
  for (int rep = 0; rep < 2; ++rep) {
    int idx = tid + rep * 256;
    int row = idx >> 4, c4 = (idx & 15) * 4;
    float4 v = *reinterpret_cast<const float4*>(&W[(size_t)(kt*32 + row) * N + n0 + nbk*64 + c4]);
    *reinterpret_cast<float4*>(&T[row][c4]) = v;
  }
  __syncthreads();
  int c = tid;
  int nt = c >> 6, l = c & 63;
  const size_t base = (((size_t)(kt >> 1) * Nc16 + nbk*4 + nt) * 2 + (kt & 1)) * 512;
  u16 hh[8], ll[8];
#pragma unroll
  for (int j = 0; j < 8; ++j) split2(T[(l >> 4)*8 + j][nt*16 + (l & 15)], hh[j], ll[j]);
  *reinterpret_cast<s16x8*>(&dh[base + (size_t)l * 8]) =
    (s16x8){(short)hh[0],(short)hh[1],(short)hh[2],(short)hh[3],
            (short)hh[4],(short)hh[5],(short)hh[6],(short)hh[7]};
  *reinterpret_cast<s16x8*>(&dl[base + (size_t)l * 8]) =
    (s16x8){(short)ll[0],(short)ll[1],(short)ll[2],(short)ll[3],
            (short)ll[4],(short)ll[5],(short)ll[6],(short)ll[7]};
}

// ===========================================================================
// frag_a (NEW): A-side (M x 4096 fp32, row-major) -> [kt64][mt][kk2][512]
// Element (m,k): off = ((kt64*128 + mt)*2 + kk)*512 + l*8 + j,
//   mt=m>>4, l=((k&31)>>3)*16+(m&15), j=k&7.  grid (64 kt, 16 mb128), 256 thr.
// ===========================================================================
__global__ __launch_bounds__(256) void frag_a(
    const float* __restrict__ src, u16* __restrict__ dh, u16* __restrict__ dl)
{
  __shared__ float T[128][68];
  const int kt = blockIdx.x;
  const int mb = blockIdx.y;
  const int tid = threadIdx.x;
#pragma unroll
  for (int rep = 0; rep < 8; ++rep) {
    int idx = tid + rep * 256;
    int row = idx >> 4, c4 = (idx & 15) * 4;
    float4 v = *reinterpret_cast<const float4*>(&src[(size_t)(mb*128 + row) * 4096 + kt*64 + c4]);
    *reinterpret_cast<float4*>(&T[row][c4]) = v;
  }
  __syncthreads();
#pragma unroll
  for (int rep = 0; rep < 4; ++rep) {
    int c = tid + rep * 256;            // 0..1023
    int mt = c >> 7, rem = c & 127, kk = rem >> 6, l = rem & 63;
    u16 hh[8], ll[8];
#pragma unroll
    for (int j = 0; j < 8; ++j)
      split2(T[mt*16 + (l & 15)][kk*32 + (l >> 4)*8 + j], hh[j], ll[j]);
    size_t off = (((size_t)(kt*128 + mb*8 + mt)) * 2 + kk) * 512 + (size_t)l * 8;
    *reinterpret_cast<s16x8*>(&dh[off]) =
      (s16x8){(short)hh[0],(short)hh[1],(short)hh[2],(short)hh[3],
              (short)hh[4],(short)hh[5],(short)hh[6],(short)hh[7]};
    *reinterpret_cast<s16x8*>(&dl[off]) =
      (s16x8){(short)ll[0],(short)ll[1],(short)ll[2],(short)ll[3],
              (short)ll[4],(short)ll[5],(short)ll[6],(short)ll[7]};
  }
}

// ===========================================================================
// gemm256_core: 256x256 tile, 8 waves (2m x 4n), wave tile 128x64, BK=64.
// Virtual K = 192 steps: p0 (Ah,Bh) p1 (Al,Bh) p2 (Ah,Bl).
// One barrier per step; stage(t+1) issued at iteration top (long window).
// LDS 128KB dbuf. All LDS ops lane-linear 16B -> conflict-free.
// ===========================================================================
__device__ __forceinline__ void gemm256_core(
    const u16* __restrict__ PAh, const u16* __restrict__ PAl,
    const u16* __restrict__ PBh, const u16* __restrict__ PBl,
    float* __restrict__ C, int ldc, int Nc16,
    int mb, int nb, int vk0, int nvk, u16* L)
{
  const int tid  = threadIdx.x;
  const int lane = tid & 63;
  const int wid  = tid >> 6;
  const int loff = lane * 8;
  const int wm8  = (wid >> 2) * 8;
  const int wn4  = (wid & 3) * 4;

  f32x4 acc[8][4];
#pragma unroll
  for (int i = 0; i < 8; ++i)
#pragma unroll
    for (int j = 0; j < 4; ++j) acc[i][j] = (f32x4){0.f,0.f,0.f,0.f};

  const size_t aBase = (size_t)mb * 16384;
  const size_t bBase = (size_t)nb * 16384;

#define STAGE256(v, la_, lb_)                                                  \
  {                                                                            \
    int p_ = (v) >> 6, vk_ = (v) & 63;                                         \
    const u16* sa_ = ((p_ == 1) ? PAl : PAh) + (size_t)vk_ * 131072 + aBase;   \
    const u16* sb_ = ((p_ == 2) ? PBl : PBh) + (size_t)vk_ * ((size_t)Nc16 * 1024) + bBase; \
    _Pragma("unroll")                                                          \
    for (int s_ = 0; s_ < 4; ++s_) {                                           \
      int ch_ = wid * 4 + s_;                                                  \
      gload_lds16(sa_ + ch_*512 + loff, (la_) + ch_*512);                      \
      gload_lds16(sb_ + ch_*512 + loff, (lb_) + ch_*512);                      \
    }                                                                          \
  }

  {
    u16* la = L + ((vk0 & 1) ? 16384 : 0);
    u16* lb = L + 32768 + ((vk0 & 1) ? 16384 : 0);
    STAGE256(vk0, la, lb);
  }
  __syncthreads();

  for (int t = vk0; t < vk0 + nvk; ++t) {
    u16* la = L + ((t & 1) ? 16384 : 0);
    u16* lb = L + 32768 + ((t & 1) ? 16384 : 0);
    if (t + 1 < vk0 + nvk) {
      u16* na = L + (((t+1) & 1) ? 16384 : 0);
      u16* nbuf = L + 32768 + (((t+1) & 1) ? 16384 : 0);
      STAGE256(t+1, na, nbuf);
    }
#pragma unroll
    for (int kk = 0; kk < 2; ++kk) {
      s16x8 a[8];
#pragma unroll
      for (int mf = 0; mf < 8; ++mf)
        a[mf] = *reinterpret_cast<const s16x8*>(&la[((wm8+mf)*2 + kk)*512 + loff]);
      __builtin_amdgcn_s_setprio(1);
#pragma unroll
      for (int nf = 0; nf < 4; ++nf) {
        s16x8 b = *reinterpret_cast<const s16x8*>(&lb[((wn4+nf)*2 + kk)*512 + loff]);
#pragma unroll
        for (int mf = 0; mf < 8; ++mf)
          acc[mf][nf] = MFMA(a[mf], b, acc[mf][nf]);
      }
      __builtin_amdgcn_s_setprio(0);
    }
    __syncthreads();
  }
#undef STAGE256

  const int lg = lane >> 4, lr = lane & 15;
  const int row0 = mb*256 + (wid >> 2) * 128;
  const int col0 = nb*256 + (wid & 3) * 64;
#pragma unroll
  for (int mf = 0; mf < 8; ++mf)
#pragma unroll
    for (int nf = 0; nf < 4; ++nf)
#pragma unroll
      for (int r = 0; r < 4; ++r)
        C[(size_t)(row0 + mf*16 + lg*4 + r) * ldc + col0 + nf*16 + lr] = acc[mf][nf][r];
}

// QKV merged: 192 blocks. Q: 128 (mb 0..7 x nb 0..15); K: 32; V: 32.
// W arena u16 offsets: WQh 0, WQl 16777216, WKh 33554432, WKl 37748736,
//                      WVh 41943040, WVl 46137344.
__global__ __launch_bounds__(512) void gemm_qkv2(
    const u16* __restrict__ XAh, const u16* __restrict__ XAl,
    const u16* __restrict__ WA,
    float* __restrict__ qb, float* __restrict__ kb, float* __restrict__ vb)
{
  __shared__ __attribute__((aligned(16))) u16 L[65536];
  int id = blockIdx.x;
  int swz = (id & 7) * 24 + (id >> 3);     // bijective: 192 = 8*24
  const u16 *Bh, *Bl; float* C; int ldc, Nc16, mb, nb;
  if (swz < 128)      { Bh = WA;          Bl = WA+16777216; C = qb; ldc = 4096; Nc16 = 256; mb = swz & 7;  nb = swz >> 3; }
  else if (swz < 160) { int u = swz-128; Bh = WA+33554432; Bl = WA+37748736; C = kb; ldc = 1024; Nc16 = 64; mb = u & 7; nb = u >> 3; }
  else                { int u = swz-160; Bh = WA+41943040; Bl = WA+46137344; C = vb; ldc = 1024; Nc16 = 64; mb = u & 7; nb = u >> 3; }
  gemm256_core(XAh, XAl, Bh, Bl, C, ldc, Nc16, mb, nb, 0, 192, L);
}

// OUT: 256 blocks, K-split x2 (s=0 -> out, s=1 -> c2), then add pass.
__global__ __launch_bounds__(512) void gemm_out2(
    const u16* __restrict__ ABh, const u16* __restrict__ ABl,
    const u16* __restrict__ WOh, const u16* __restrict__ WOl,
    float* __restrict__ outp, float* __restrict__ c2)
{
  __shared__ __attribute__((aligned(16))) u16 L[65536];
  int id = blockIdx.x;
  int swz = (id & 7) * 32 + (id >> 3);     // bijective: 256 = 8*32
  int u = swz & 127, s = swz >> 7;
  int mb = u & 7, nb = u >> 3;
  gemm256_core(ABh, ABl, WOh, WOl, s ? c2 : outp, 4096, 256, mb, nb, s*96, 96, L);
}

__global__ __launch_bounds__(256) void add_out(
    float* __restrict__ o, const float* __restrict__ c2)
{
  int i = blockIdx.x * 256 + threadIdx.x;
  float4 a = reinterpret_cast<float4*>(o)[i];
  float4 b = reinterpret_cast<const float4*>(c2)[i];
  a.x += b.x; a.y += b.y; a.z += b.z; a.w += b.w;
  reinterpret_cast<float4*>(o)[i] = a;
}

// ===========================================================================
// frag_kv (verified): post-GEMM K,V -> fragment planes, K-RoPE fused.
// ===========================================================================
__global__ __launch_bounds__(256) void frag_kv(
    const float* __restrict__ kb, const float* __restrict__ vb,
    const float* __restrict__ cosT, const float* __restrict__ sinT,
    u16* __restrict__ KFh, u16* __restrict__ KFl,
    u16* __restrict__ VFh, u16* __restrict__ VFl)
{
  __shared__ float T[32][132];
  const int bid  = blockIdx.x;
  const int isV  = bid >> 9;
  const int bkvh = (bid >> 5) & 15;
  const int chnk = bid & 31;
  const int tid  = threadIdx.x;
  const int b    = bkvh >> 3, kvh = bkvh & 7;

  const float* src = isV ? vb : kb;
  {
    int r0 = tid >> 5, c4 = (tid & 31) * 4;
    float sgn = (c4 < 64) ? -1.f : 1.f;
#pragma unroll
    for (int it = 0; it < 4; ++it) {
      int row = r0 + it * 8;
      int srow = chnk*32 + row;
      const float* rp = &src[(((size_t)(b * S_ + srow)) * HKV_ + kvh) * HD_];
      float4 v = *reinterpret_cast<const float4*>(rp + c4);
      if (!isV) {
        float4 p  = *reinterpret_cast<const float4*>(rp + (c4 ^ 64));
        float4 cc = *reinterpret_cast<const float4*>(&cosT[((size_t)(b*S_ + srow))*HD_ + c4]);
        float4 ss = *reinterpret_cast<const float4*>(&sinT[((size_t)(b*S_ + srow))*HD_ + c4]);
        v.x = v.x*cc.x + sgn*p.x*ss.x;
        v.y = v.y*cc.y + sgn*p.y*ss.y;
        v.z = v.z*cc.z + sgn*p.z*ss.z;
        v.w = v.w*cc.w + sgn*p.w*ss.w;
      }
      *reinterpret_cast<float4*>(&T[row][c4]) = v;
    }
  }
  __syncthreads();
#pragma unroll
  for (int rep = 0; rep < 2; ++rep) {
    int c2 = tid + rep * 256;
    int l = c2 & 63;
    u16 hh[8], ll[8];
    if (!isV) {
      int f = c2 >> 6, st_loc = f >> 2, dt = f & 3;
#pragma unroll
      for (int j = 0; j < 8; ++j)
        split2(T[st_loc*16 + (l & 15)][dt*32 + (l >> 4)*8 + j], hh[j], ll[j]);
      size_t off = ((size_t)bkvh*64 + chnk*2) * 2048 + (size_t)c2 * 8;
      *reinterpret_cast<s16x8*>(&KFh[off]) =
        (s16x8){(short)hh[0],(short)hh[1],(short)hh[2],(short)hh[3],
                (short)hh[4],(short)hh[5],(short)hh[6],(short)hh[7]};
      *reinterpret_cast<s16x8*>(&KFl[off]) =
        (s16x8){(short)ll[0],(short)ll[1],(short)ll[2],(short)ll[3],
                (short)ll[4],(short)ll[5],(short)ll[6],(short)ll[7]};
    } else {
      int dt16 = c2 >> 6;
#pragma unroll
      for (int j = 0; j < 8; ++j)
        split2(T[(l >> 4)*8 + j][dt16*16 + (l & 15)], hh[j], ll[j]);
      size_t off = ((size_t)bkvh*32 + chnk) * 4096 + (size_t)c2 * 8;
      *reinterpret_cast<s16x8*>(&VFh[off]) =
        (s16x8){(short)hh[0],(short)hh[1],(short)hh[2],(short)hh[3],
                (short)hh[4],(short)hh[5],(short)hh[6],(short)hh[7]};
      *reinterpret_cast<s16x8*>(&VFl[off]) =
        (s16x8){(short)ll[0],(short)ll[1],(short)ll[2],(short)ll[3],
                (short)ll[4],(short)ll[5],(short)ll[6],(short)ll[7]};
    }
  }
}

// ===========================================================================
// attn3 (verified): fragment-staged flash attention, Q-RoPE fused.
// ===========================================================================
__global__ __launch_bounds__(512) void attn3(
    const float* __restrict__ qb,
    const float* __restrict__ cosT, const float* __restrict__ sinT,
    const u16* __restrict__ KFh, const u16* __restrict__ KFl,
    const u16* __restrict__ VFh, const u16* __restrict__ VFl,
    float* __restrict__ ob)
{
  __shared__ __attribute__((aligned(16))) u16 Klds[16384];
  __shared__ __attribute__((aligned(16))) u16 Vlds[16384];
  __shared__ u16 Ph[8][16][68], Pl[8][16][68];

  const int tid  = threadIdx.x;
  const int lane = tid & 63;
  const int wid  = tid >> 6;
  const int lr   = lane & 15;
  const int lg   = lane >> 4;
  const int loff = lane * 8;
  const int qt   = blockIdx.x;
  const int bh   = blockIdx.y;
  const int b    = bh >> 5, h = bh & 31;
  const int bkvh = b * 8 + (h >> 2);

  s16x8 qh[4], ql[4];
  {
    const int qrow = qt * 128 + wid * 16 + lr;
    const float* qp = qb + ((size_t)((b * S_ + qrow) * HQ_ + h)) * HD_;
    const float* cp = cosT + ((size_t)(b * S_ + qrow)) * HD_;
    const float* sp = sinT + ((size_t)(b * S_ + qrow)) * HD_;
#pragma unroll
    for (int kc = 0; kc < 4; ++kc) {
      const int d0 = kc * 32 + lg * 8;
      const float sgn = (d0 < 64) ? -1.f : 1.f;
      float4 v0 = *reinterpret_cast<const float4*>(qp + d0);
      float4 v1 = *reinterpret_cast<const float4*>(qp + d0 + 4);
      float4 p0 = *reinterpret_cast<const float4*>(qp + (d0 ^ 64));
      float4 p1 = *reinterpret_cast<const float4*>(qp + (d0 ^ 64) + 4);
      float4 c0 = *reinterpret_cast<const float4*>(cp + d0);
      float4 c1 = *reinterpret_cast<const float4*>(cp + d0 + 4);
      float4 s0 = *reinterpret_cast<const float4*>(sp + d0);
      float4 s1 = *reinterpret_cast<const float4*>(sp + d0 + 4);
      float4 r0, r1;
      r0.x = v0.x*c0.x + sgn*p0.x*s0.x;  r0.y = v0.y*c0.y + sgn*p0.y*s0.y;
      r0.z = v0.z*c0.z + sgn*p0.z*s0.z;  r0.w = v0.w*c0.w + sgn*p0.w*s0.w;
      r1.x = v1.x*c1.x + sgn*p1.x*s1.x;  r1.y = v1.y*c1.y + sgn*p1.y*s1.y;
      r1.z = v1.z*c1.z + sgn*p1.z*s1.z;  r1.w = v1.w*c1.w + sgn*p1.w*s1.w;
      uint4 h4, l4; pack8(r0, r1, h4, l4);
      qh[kc] = *reinterpret_cast<s16x8*>(&h4);
      ql[kc] = *reinterpret_cast<s16x8*>(&l4);
    }
  }

  f32x4 acc_o[8];
#pragma unroll
  for (int df = 0; df < 8; ++df) acc_o[df] = (f32x4){0.f, 0.f, 0.f, 0.f};
  float m_run[4] = {-1e30f, -1e30f, -1e30f, -1e30f};
  float l_run[4] = {0.f, 0.f, 0.f, 0.f};

  const u16* gKh = KFh + (size_t)bkvh * 131072;
  const u16* gKl = KFl + (size_t)bkvh * 131072;
  const u16* gVh = VFh + (size_t)bkvh * 131072;
  const u16* gVl = VFl + (size_t)bkvh * 131072;

#pragma unroll
  for (int i = 0; i < 4; ++i) {
    int idx = wid * 4 + i;
    const u16* src = (idx < 16) ? (gKh + idx*512) : (gKl + (idx-16)*512);
    u16* dst = Klds + ((idx < 16) ? idx*512 : 8192 + (idx-16)*512);
    gload_lds16(src + loff, dst);
  }
  __syncthreads();

  for (int t = 0; t < 16; ++t) {
#pragma unroll
    for (int i = 0; i < 4; ++i) {
      int idx = wid * 4 + i;
      const u16* src = (idx < 16) ? (gVh + t*8192 + idx*512)
                                  : (gVl + t*8192 + (idx-16)*512);
      u16* dst = Vlds + ((idx < 16) ? idx*512 : 8192 + (idx-16)*512);
      gload_lds16(src + loff, dst);
    }

    f32x4 accs[4];
#pragma unroll
    for (int nf = 0; nf < 4; ++nf) {
      accs[nf] = (f32x4){0.f, 0.f, 0.f, 0.f};
      s16x8 kh8[4], kl8[4];
#pragma unroll
      for (int kc = 0; kc < 4; ++kc) {
        kh8[kc] = *reinterpret_cast<const s16x8*>(&Klds[nf*2048 + kc*512 + loff]);
        kl8[kc] = *reinterpret_cast<const s16x8*>(&Klds[8192 + nf*2048 + kc*512 + loff]);
      }
#pragma unroll
      for (int kc = 0; kc < 4; ++kc) {
        accs[nf] = MFMA(qh[kc], kh8[kc], accs[nf]);
        accs[nf] = MFMA(ql[kc], kh8[kc], accs[nf]);
        accs[nf] = MFMA(qh[kc], kl8[kc], accs[nf]);
      }
    }
#pragma unroll
    for (int nf = 0; nf < 4; ++nf) accs[nf] *= SCALE_;

    float corr[4], rsum[4];
#pragma unroll
    for (int r = 0; r < 4; ++r) {
      float t0 = fmaxf(fmaxf(accs[0][r], accs[1][r]), fmaxf(accs[2][r], accs[3][r]));
      t0 = fmaxf(t0, __shfl_xor(t0, 1));
      t0 = fmaxf(t0, __shfl_xor(t0, 2));
      t0 = fmaxf(t0, __shfl_xor(t0, 4));
      t0 = fmaxf(t0, __shfl_xor(t0, 8));
      float mnew = fmaxf(m_run[r], t0);
      corr[r] = __expf(m_run[r] - mnew);
      m_run[r] = mnew;
      rsum[r] = 0.f;
    }
#pragma unroll
    for (int nf = 0; nf < 4; ++nf)
#pragma unroll
      for (int r = 0; r < 4; ++r) {
        float p = __expf(accs[nf][r] - m_run[r]);
        rsum[r] += p;
        u16 ph, pl;
        split2(p, ph, pl);
        Ph[wid][lg*4 + r][nf*16 + lr] = ph;
        Pl[wid][lg*4 + r][nf*16 + lr] = pl;
      }
#pragma unroll
    for (int r = 0; r < 4; ++r) {
      float s = rsum[r];
      s += __shfl_xor(s, 1); s += __shfl_xor(s, 2);
      s += __shfl_xor(s, 4); s += __shfl_xor(s, 8);
      l_run[r] = l_run[r] * corr[r] + s;
    }
#pragma unroll
    for (int df = 0; df < 8; ++df)
#pragma unroll
      for (int r = 0; r < 4; ++r) acc_o[df][r] *= corr[r];

    __syncthreads();

    if (t < 15) {
#pragma unroll
      for (int i = 0; i < 4; ++i) {
        int idx = wid * 4 + i;
        const u16* src = (idx < 16) ? (gKh + (t+1)*8192 + idx*512)
                                    : (gKl + (t+1)*8192 + (idx-16)*512);
        u16* dst = Klds + ((idx < 16) ? idx*512 : 8192 + (idx-16)*512);
        gload_lds16(src + loff, dst);
      }
    }

    s16x8 pa_h[2], pa_l[2];
#pragma unroll
    for (int kc = 0; kc < 2; ++kc) {
      pa_h[kc] = *reinterpret_cast<const s16x8*>(&Ph[wid][lr][kc*32 + lg*8]);
      pa_l[kc] = *reinterpret_cast<const s16x8*>(&Pl[wid][lr][kc*32 + lg*8]);
    }
#pragma unroll
    for (int df = 0; df < 8; ++df) {
      s16x8 vh8[2], vl8[2];
#pragma unroll
      for (int kc = 0; kc < 2; ++kc) {
        vh8[kc] = *reinterpret_cast<const s16x8*>(&Vlds[kc*4096 + df*512 + loff]);
        vl8[kc] = *reinterpret_cast<const s16x8*>(&Vlds[8192 + kc*4096 + df*512 + loff]);
      }
#pragma unroll
      for (int kc = 0; kc < 2; ++kc) {
        acc_o[df] = MFMA(pa_h[kc], vh8[kc], acc_o[df]);
        acc_o[df] = MFMA(pa_l[kc], vh8[kc], acc_o[df]);
        acc_o[df] = MFMA(pa_h[kc], vl8[kc], acc_o[df]);
      }
    }
    __syncthreads();
  }

  float inv_l[4];
#pragma unroll
  for (int r = 0; r < 4; ++r) inv_l[r] = 1.f / l_run[r];
#pragma unroll
  for (int df = 0; df < 8; ++df)
#pragma unroll
    for (int r = 0; r < 4; ++r) {
      int row = qt * 128 + wid * 16 + lg * 4 + r;
      ob[((size_t)((b * S_ + row) * HQ_ + h)) * HD_ + df*16 + lr] = acc_o[df][r] * inv_l[r];
    }
}

// ===========================================================================
// gemm_p1 (round-7 verified, WS185 fallback)
// ===========================================================================
__global__ __launch_bounds__(512) void gemm_p1(
    const float* __restrict__ X, const float* __restrict__ abp,
    const u16* __restrict__ WF,
    float* __restrict__ qb, float* __restrict__ kb, float* __restrict__ vb,
    float* __restrict__ outp, int mode, int col0)
{
  __shared__ __attribute__((aligned(16))) u16 lds[40960];
  u16* ah0 = lds;
  u16* al0 = lds + 4096;
  u16* ah1 = lds + 8192;
  u16* al1 = lds + 12288;
  u16* bh0 = lds + 16384;
  u16* bh1 = lds + 24576;
  u16* blb = lds + 32768;

  const int id   = blockIdx.x;
  const int cpx  = gridDim.x >> 3;
  const int swz  = (id & 7) * cpx + (id >> 3);

  const float* A; const u16* Bh; const u16* Bl; float* C;
  int ldc, Nc16, mb, nb;
  if (mode == 3) {
    A=abp; Bh=WF; Bl=WF+16777216; C=outp; ldc=4096; Nc16=256; mb=swz>>4; nb=swz&15;
  } else {  // mode 5: merged QKV, 384 blocks
    if (swz < 128)      { A=X; Bh=WF;          Bl=WF+8388608;  C=qb;      ldc=4096; Nc16=128; mb=swz>>3; nb=swz&7; }
    else if (swz < 256) { int u=swz-128; A=X; Bh=WF+16777216; Bl=WF+25165824; C=qb+2048; ldc=4096; Nc16=128; mb=u>>3; nb=u&7; }
    else if (swz < 320) { int u=swz-256; A=X; Bh=WF+33554432; Bl=WF+37748736; C=kb; ldc=1024; Nc16=64; mb=u>>2; nb=u&3; }
    else                { int u=swz-320; A=X; Bh=WF+41943040; Bl=WF+46137344; C=vb; ldc=1024; Nc16=64; mb=u>>2; nb=u&3; }
  }

  const int tid  = threadIdx.x;
  const int lane = tid & 63;
  const int wid  = tid >> 6;
  const int mtb  = (wid >> 2) * 4;
  const int ntb  = (wid & 3) * 4;
  const int loff = lane * 8;
  const int lg   = lane >> 4;
  const int lr_  = lane & 15;
  const int aoff = (lg*16 + ((lr_ + 4*lg) & 15)) * 8;

  const int arow = tid >> 2;
  const int akc  = tid & 3;
  const float* aptr = A + (size_t)(mb*128 + arow) * 4096 + akc*8;
  const int awr = (arow >> 4)*512 + (akc*16 + (((arow & 15) + 4*akc) & 15))*8;

  const size_t bStep = (size_t)Nc16 * 512;
  const u16* pBh = Bh + (size_t)nb*16*512 + loff;
  const u16* pBl = Bl + (size_t)nb*16*512 + loff;

  f32x4 acc[4][4];
#pragma unroll
  for (int i = 0; i < 4; ++i)
#pragma unroll
    for (int j = 0; j < 4; ++j) acc[i][j] = (f32x4){0.f, 0.f, 0.f, 0.f};

  float4 ra0 = *reinterpret_cast<const float4*>(aptr);
  float4 ra1 = *reinterpret_cast<const float4*>(aptr + 4);
  {
    uint4 h4, l4; pack8(ra0, ra1, h4, l4);
    *reinterpret_cast<uint4*>(&ah0[awr]) = h4;
    *reinterpret_cast<uint4*>(&al0[awr]) = l4;
  }
  gload_lds16(pBh + (size_t)wid*512,     bh0 + wid*512);
  gload_lds16(pBh + (size_t)(wid+8)*512, bh0 + (wid+8)*512);
  ra0 = *reinterpret_cast<const float4*>(aptr + 32);
  ra1 = *reinterpret_cast<const float4*>(aptr + 36);
  __syncthreads();

  for (int kt = 0; kt < 128; ++kt) {
    u16* cAh = (kt & 1) ? ah1 : ah0;
    u16* cAl = (kt & 1) ? al1 : al0;
    u16* nAh = (kt & 1) ? ah0 : ah1;
    u16* nAl = (kt & 1) ? al0 : al1;
    u16* cBh = (kt & 1) ? bh1 : bh0;
    u16* nBh = (kt & 1) ? bh0 : bh1;

    gload_lds16(pBl + (size_t)kt*bStep + (size_t)wid*512,     blb + wid*512);
    gload_lds16(pBl + (size_t)kt*bStep + (size_t)(wid+8)*512, blb + (wid+8)*512);
    if (kt < 127) {
      gload_lds16(pBh + (size_t)(kt+1)*bStep + (size_t)wid*512,     nBh + wid*512);
      gload_lds16(pBh + (size_t)(kt+1)*bStep + (size_t)(wid+8)*512, nBh + (wid+8)*512);
    }
    s16x8 a_h[4], a_l[4], b_h[4];
#pragma unroll
    for (int mf = 0; mf < 4; ++mf) {
      a_h[mf] = *reinterpret_cast<const s16x8*>(&cAh[(mtb+mf)*512 + aoff]);
      a_l[mf] = *reinterpret_cast<const s16x8*>(&cAl[(mtb+mf)*512 + aoff]);
    }
#pragma unroll
    for (int nf = 0; nf < 4; ++nf)
      b_h[nf] = *reinterpret_cast<const s16x8*>(&cBh[(ntb+nf)*512 + loff]);
#pragma unroll
    for (int mf = 0; mf < 4; ++mf)
#pragma unroll
      for (int nf = 0; nf < 4; ++nf) {
        acc[mf][nf] = MFMA(a_h[mf], b_h[nf], acc[mf][nf]);
        acc[mf][nf] = MFMA(a_l[mf], b_h[nf], acc[mf][nf]);
      }
    __syncthreads();

    s16x8 b_l[4];
#pragma unroll
    for (int nf = 0; nf < 4; ++nf)
      b_l[nf] = *reinterpret_cast<const s16x8*>(&blb[(ntb+nf)*512 + loff]);
#pragma unroll
    for (int mf = 0; mf < 4; ++mf)
#pragma unroll
      for (int nf = 0; nf < 4; ++nf)
        acc[mf][nf] = MFMA(a_h[mf], b_l[nf], acc[mf][nf]);
    if (kt < 127) {
      uint4 h4, l4; pack8(ra0, ra1, h4, l4);
      *reinterpret_cast<uint4*>(&nAh[awr]) = h4;
      *reinterpret_cast<uint4*>(&nAl[awr]) = l4;
      if (kt < 126) {
        ra0 = *reinterpret_cast<const float4*>(aptr + (kt+2)*32);
        ra1 = *reinterpret_cast<const float4*>(aptr + (kt+2)*32 + 4);
      }
    }
    __syncthreads();
  }

  const int row0 = mb*128 + (wid >> 2) * 64;
  const int nloc = nb*256 + (wid & 3) * 64;
#pragma unroll
  for (int mf = 0; mf < 4; ++mf)
#pragma unroll
    for (int nf = 0; nf < 4; ++nf)
#pragma unroll
      for (int r = 0; r < 4; ++r)
        C[(size_t)(row0 + mf*16 + lg*4 + r) * ldc + nloc + nf*16 + lr_] = acc[mf][nf][r];
}

// ---------------------------------------------------------------------------
extern "C" void kernel_launch(void* const* d_in, const int* in_sizes, int n_in,
                              void* d_out, int out_size, void* d_ws, size_t ws_size,
                              hipStream_t stream)
{
  const float* hs   = (const float*)d_in[0];
  const float* cosT = (const float*)d_in[1];
  const float* sinT = (const float*)d_in[2];
  const float* Wq   = (const float*)d_in[3];
  const float* Wk   = (const float*)d_in[4];
  const float* Wv   = (const float*)d_in[5];
  const float* Wo   = (const float*)d_in[6];
  float* out = (float*)d_out;

  float* qb = (float*)d_ws;                 // 8388608 f32
  float* kb = qb + 8388608;                 // 2097152
  float* vb = kb + 2097152;                 // 2097152
  float* ab = vb + 2097152;                 // 8388608
  u16*   FR = (u16*)(ab + 8388608);

  const size_t WS208 = 218103808ULL;        // 84MB base + 32MB A-planes + 96MB W arena
  const size_t WS185 = 184549376ULL;        // round-7 tier

  if (ws_size >= WS208) {
    u16* XAh = FR;                          // 8388608 u16
    u16* XAl = FR + 8388608;
    u16* WA  = FR + 16777216;               // 50331648 u16 arena
    // fragmentize A-side and weights (new layout)
    frag_a<<<dim3(64,16), 256, 0, stream>>>(hs, XAh, XAl);
    frag_b2<<<dim3(128,64), 256, 0, stream>>>(Wq, WA,           WA+16777216, 4096, 0, 256);
    frag_b2<<<dim3(128,16), 256, 0, stream>>>(Wk, WA+33554432,  WA+37748736, 1024, 0, 64);
    frag_b2<<<dim3(128,16), 256, 0, stream>>>(Wv, WA+41943040,  WA+46137344, 1024, 0, 64);
    // QKV: 192 blocks, 256x256 tiles
    gemm_qkv2<<<192, 512, 0, stream>>>(XAh, XAl, WA, qb, kb, vb);
    // KV fragment planes (W arena head, Wq region dead) + Wo planes (tail)
    frag_kv<<<1024, 256, 0, stream>>>(kb, vb, cosT, sinT,
                                      WA, WA+2097152, WA+4194304, WA+6291456);
    frag_b2<<<dim3(128,64), 256, 0, stream>>>(Wo, WA+8388608, WA+25165824, 4096, 0, 256);
    attn3<<<dim3(8, 64), 512, 0, stream>>>(qb, cosT, sinT,
                                           WA, WA+2097152, WA+4194304, WA+6291456, ab);
    // OUT: re-fragment ab into XA arena, K-split x2, add pass (C2 = dead qb)
    frag_a<<<dim3(64,16), 256, 0, stream>>>(ab, XAh, XAl);
    gemm_out2<<<256, 512, 0, stream>>>(XAh, XAl, WA+8388608, WA+25165824, out, qb);
    add_out<<<8192, 256, 0, stream>>>(out, qb);
  } else {
    // round-7 path (verified at 712us): merged QKV 128-tile + OUT + frag attn
    u16* WF = FR;
    u16* KFh = WF;
    u16* KFl = WF + 2097152;
    u16* VFh = WF + 4194304;
    u16* VFl = WF + 6291456;
    frag_b1<<<dim3(128,32), 256, 0, stream>>>(Wq, WF,          WF+8388608,  4096, 0,    128);
    frag_b1<<<dim3(128,32), 256, 0, stream>>>(Wq, WF+16777216, WF+25165824, 4096, 2048, 128);
    frag_b1<<<dim3(128,16), 256, 0, stream>>>(Wk, WF+33554432, WF+37748736, 1024, 0,    64);
    frag_b1<<<dim3(128,16), 256, 0, stream>>>(Wv, WF+41943040, WF+46137344, 1024, 0,    64);
    gemm_p1<<<384, 512, 0, stream>>>(hs, ab, WF, qb, kb, vb, out, 5, 0);
    frag_kv<<<1024, 256, 0, stream>>>(kb, vb, cosT, sinT, KFh, KFl, VFh, VFl);
    attn3<<<dim3(8, 64), 512, 0, stream>>>(qb, cosT, sinT, KFh, KFl, VFh, VFl, ab);
    frag_b1<<<dim3(128,64), 256, 0, stream>>>(Wo, WF, WF+16777216, 4096, 0, 256);
    gemm_p1<<<256, 512, 0, stream>>>(hs, ab, WF, qb, kb, vb, out, 3, 0);
  }
}

// Round 9
// 690.509 us; speedup vs baseline: 1.5172x; 1.0111x over previous
//
#include <hip/hip_runtime.h>

#define B_   2
#define S_   1024
#define D_   4096
#define HQ_  32
#define HKV_ 8
#define HD_  128
#define SCALE_ 0.08838834764831845f

typedef unsigned short u16;
typedef __attribute__((ext_vector_type(8))) short s16x8;
typedef __attribute__((ext_vector_type(4))) short s16x4;
typedef __attribute__((ext_vector_type(4))) float f32x4;

#define MFMA(a,b,c) __builtin_amdgcn_mfma_f32_16x16x32_bf16((a),(b),(c),0,0,0)

__device__ __forceinline__ u16 bf16_rne(float x) {
  unsigned u = __float_as_uint(x);
  u += 0x7fffu + ((u >> 16) & 1u);
  return (u16)(u >> 16);
}
__device__ __forceinline__ float bf16_up(u16 h) {
  return __uint_as_float(((unsigned)h) << 16);
}
__device__ __forceinline__ void split2(float x, u16& h, u16& l) {
  h = bf16_rne(x);
  l = bf16_rne(x - bf16_up(h));
}

__device__ __forceinline__ void cvt_hi_lo(float a, float b, unsigned& hi, unsigned& lo) {
  unsigned h, l;
  asm("v_cvt_pk_bf16_f32 %0, %1, %2" : "=v"(h) : "v"(a), "v"(b));
  float ra = __uint_as_float(h << 16);
  float rb = __uint_as_float(h & 0xffff0000u);
  float la = a - ra, lb = b - rb;
  asm("v_cvt_pk_bf16_f32 %0, %1, %2" : "=v"(l) : "v"(la), "v"(lb));
  hi = h; lo = l;
}
__device__ __forceinline__ void pack8(float4 x, float4 y, uint4& h, uint4& l) {
  unsigned h0,h1,h2,h3,l0,l1,l2,l3;
  cvt_hi_lo(x.x, x.y, h0, l0);
  cvt_hi_lo(x.z, x.w, h1, l1);
  cvt_hi_lo(y.x, y.y, h2, l2);
  cvt_hi_lo(y.z, y.w, h3, l3);
  h = make_uint4(h0,h1,h2,h3); l = make_uint4(l0,l1,l2,l3);
}

typedef const __attribute__((address_space(1))) void* gas_ptr;
typedef __attribute__((address_space(3))) void* las_ptr;
__device__ __forceinline__ void gload_lds16(const void* g, void* l) {
  __builtin_amdgcn_global_load_lds((gas_ptr)g, (las_ptr)l, 16, 0, 0);
}

// ===========================================================================
// frag_b2: weights (K x N fp32) -> [kt64][nt-global][kk2][512] hi/lo planes.
// Reads source cols [n0, n0+gridDim.y*64); writes dest nt starting at ntoff
// within a plane of Ntot16 total n-tiles. grid (128 kt32, Nc/64), 256 thr.
// ===========================================================================
__global__ __launch_bounds__(256) void frag_b2(
    const float* __restrict__ W, u16* __restrict__ dh, u16* __restrict__ dl,
    int N, int n0, int Ntot16, int ntoff)
{
  __shared__ float T[32][68];
  const int kt = blockIdx.x, nbk = blockIdx.y;
  const int tid = threadIdx.x;
#pragma unroll
  for (int rep = 0; rep < 2; ++rep) {
    int idx = tid + rep * 256;
    int row = idx >> 4, c4 = (idx & 15) * 4;
    float4 v = *reinterpret_cast<const float4*>(&W[(size_t)(kt*32 + row) * N + n0 + nbk*64 + c4]);
    *reinterpret_cast<float4*>(&T[row][c4]) = v;
  }
  __syncthreads();
  int c = tid;
  int nt = c >> 6, l = c & 63;
  const size_t base = (((size_t)(kt >> 1) * Ntot16 + ntoff + nbk*4 + nt) * 2 + (kt & 1)) * 512;
  u16 hh[8], ll[8];
#pragma unroll
  for (int j = 0; j < 8; ++j) split2(T[(l >> 4)*8 + j][nt*16 + (l & 15)], hh[j], ll[j]);
  *reinterpret_cast<s16x8*>(&dh[base + (size_t)l * 8]) =
    (s16x8){(short)hh[0],(short)hh[1],(short)hh[2],(short)hh[3],
            (short)hh[4],(short)hh[5],(short)hh[6],(short)hh[7]};
  *reinterpret_cast<s16x8*>(&dl[base + (size_t)l * 8]) =
    (s16x8){(short)ll[0],(short)ll[1],(short)ll[2],(short)ll[3],
            (short)ll[4],(short)ll[5],(short)ll[6],(short)ll[7]};
}

// ===========================================================================
// frag_a (verified): A (M x 4096 fp32) -> [kt64][mt 128][kk2][512] planes.
// ===========================================================================
__global__ __launch_bounds__(256) void frag_a(
    const float* __restrict__ src, u16* __restrict__ dh, u16* __restrict__ dl)
{
  __shared__ float T[128][68];
  const int kt = blockIdx.x;
  const int mb = blockIdx.y;
  const int tid = threadIdx.x;
#pragma unroll
  for (int rep = 0; rep < 8; ++rep) {
    int idx = tid + rep * 256;
    int row = idx >> 4, c4 = (idx & 15) * 4;
    float4 v = *reinterpret_cast<const float4*>(&src[(size_t)(mb*128 + row) * 4096 + kt*64 + c4]);
    *reinterpret_cast<float4*>(&T[row][c4]) = v;
  }
  __syncthreads();
#pragma unroll
  for (int rep = 0; rep < 4; ++rep) {
    int c = tid + rep * 256;
    int mt = c >> 7, rem = c & 127, kk = rem >> 6, l = rem & 63;
    u16 hh[8], ll[8];
#pragma unroll
    for (int j = 0; j < 8; ++j)
      split2(T[mt*16 + (l & 15)][kk*32 + (l >> 4)*8 + j], hh[j], ll[j]);
    size_t off = (((size_t)(kt*128 + mb*8 + mt)) * 2 + kk) * 512 + (size_t)l * 8;
    *reinterpret_cast<s16x8*>(&dh[off]) =
      (s16x8){(short)hh[0],(short)hh[1],(short)hh[2],(short)hh[3],
              (short)hh[4],(short)hh[5],(short)hh[6],(short)hh[7]};
    *reinterpret_cast<s16x8*>(&dl[off]) =
      (s16x8){(short)ll[0],(short)ll[1],(short)ll[2],(short)ll[3],
              (short)ll[4],(short)ll[5],(short)ll[6],(short)ll[7]};
  }
}

// ===========================================================================
// gemm256_core<NF,RQ>: 256 x (NF*64) tile, 8 waves (2m x 4n), wave tile
// 128 x (NF*16), BK=64, virtual K = 3 panels. Double-buffered LDS, stage via
// gload_lds (lane-linear, conflict-free). RQ=true routes 16-col fragments to
// qb/kb/vb across the concatenated N=6144 (boundaries 16-aligned).
// ===========================================================================
template<int NF, bool RQ>
__device__ __forceinline__ void gemm256_core(
    const u16* __restrict__ PAh, const u16* __restrict__ PAl,
    const u16* __restrict__ PBh, const u16* __restrict__ PBl,
    float* __restrict__ C0, float* __restrict__ C1, float* __restrict__ C2,
    int ldc0, int Nt16, int mb, int nb, int vk0, int nvk, u16* L)
{
  const int tid  = threadIdx.x;
  const int lane = tid & 63;
  const int wid  = tid >> 6;
  const int loff = lane * 8;
  const int wm8  = (wid >> 2) * 8;
  const int wnf  = (wid & 3) * NF;

  u16* A0 = L;
  u16* A1 = L + 16384;
  u16* B0 = L + 32768;
  u16* B1 = L + 32768 + NF*4096;

  f32x4 acc[8][NF];
#pragma unroll
  for (int i = 0; i < 8; ++i)
#pragma unroll
    for (int j = 0; j < NF; ++j) acc[i][j] = (f32x4){0.f,0.f,0.f,0.f};

  const size_t aBase = (size_t)mb * 16384;
  const size_t bBase = (size_t)nb * (NF * 4096);
  const size_t bSlab = (size_t)Nt16 * 1024;

  auto STAGE = [&](int v, u16* la_, u16* lb_) {
    int p = v >> 6, k = v & 63;
    const u16* sa = ((p == 1) ? PAl : PAh) + (size_t)k * 131072 + aBase + loff;
    const u16* sb = ((p == 2) ? PBl : PBh) + (size_t)k * bSlab + bBase + loff;
#pragma unroll
    for (int s = 0; s < 4; ++s)
      gload_lds16(sa + (wid*4 + s)*512, la_ + (wid*4 + s)*512);
#pragma unroll
    for (int s = 0; s < NF; ++s)
      gload_lds16(sb + (wid*NF + s)*512, lb_ + (wid*NF + s)*512);
  };

  STAGE(vk0, (vk0 & 1) ? A1 : A0, (vk0 & 1) ? B1 : B0);
  __syncthreads();

  for (int t = vk0; t < vk0 + nvk; ++t) {
    u16* la = (t & 1) ? A1 : A0;
    u16* lb = (t & 1) ? B1 : B0;
    if (t + 1 < vk0 + nvk)
      STAGE(t + 1, (t & 1) ? A0 : A1, (t & 1) ? B0 : B1);
#pragma unroll
    for (int kk = 0; kk < 2; ++kk) {
      s16x8 a[8];
#pragma unroll
      for (int mf = 0; mf < 8; ++mf)
        a[mf] = *reinterpret_cast<const s16x8*>(&la[((wm8+mf)*2 + kk)*512 + loff]);
      __builtin_amdgcn_s_setprio(1);
#pragma unroll
      for (int nf = 0; nf < NF; ++nf) {
        s16x8 b = *reinterpret_cast<const s16x8*>(&lb[((wnf+nf)*2 + kk)*512 + loff]);
#pragma unroll
        for (int mf = 0; mf < 8; ++mf)
          acc[mf][nf] = MFMA(a[mf], b, acc[mf][nf]);
      }
      __builtin_amdgcn_s_setprio(0);
    }
    __syncthreads();
  }

  const int lg = lane >> 4, lr = lane & 15;
  const int rowb = mb*256 + (wid >> 2) * 128;
#pragma unroll
  for (int mf = 0; mf < 8; ++mf)
#pragma unroll
    for (int nf = 0; nf < NF; ++nf)
#pragma unroll
      for (int r = 0; r < 4; ++r) {
        int row = rowb + mf*16 + lg*4 + r;
        float v = acc[mf][nf][r];
        if constexpr (RQ) {
          int gcol = nb*(NF*64) + (wid & 3)*(NF*16) + nf*16 + lr;
          if (gcol < 4096)      C0[(size_t)row * 4096 + gcol] = v;
          else if (gcol < 5120) C1[(size_t)row * 1024 + (gcol - 4096)] = v;
          else                  C2[(size_t)row * 1024 + (gcol - 5120)] = v;
        } else {
          int col = nb*(NF*64) + (wid & 3)*(NF*16) + nf*16 + lr;
          C0[(size_t)row * ldc0 + col] = v;
        }
      }
}

// ---- NEW: fused-N QKV, 256x192 tiles, 256 blocks, perfect balance ----
__global__ __launch_bounds__(512) void gemm_qkv3(
    const u16* __restrict__ XAh, const u16* __restrict__ XAl,
    const u16* __restrict__ WBh, const u16* __restrict__ WBl,
    float* __restrict__ qb, float* __restrict__ kb, float* __restrict__ vb)
{
  __shared__ __attribute__((aligned(16))) u16 L[57344];
  int id = blockIdx.x;
  int swz = (id & 7) * 32 + (id >> 3);
  int mb = swz >> 5, nb = swz & 31;
  gemm256_core<3, true>(XAh, XAl, WBh, WBl, qb, kb, vb, 0, 384, mb, nb, 0, 192, L);
}

// ---- round-8 verified QKV (fallback tier) ----
__global__ __launch_bounds__(512) void gemm_qkv2(
    const u16* __restrict__ XAh, const u16* __restrict__ XAl,
    const u16* __restrict__ WA,
    float* __restrict__ qb, float* __restrict__ kb, float* __restrict__ vb)
{
  __shared__ __attribute__((aligned(16))) u16 L[65536];
  int id = blockIdx.x;
  int swz = (id & 7) * 24 + (id >> 3);
  const u16 *Bh, *Bl; float* C; int ldc, Nt16, mb, nb;
  if (swz < 128)      { Bh = WA;          Bl = WA+16777216; C = qb; ldc = 4096; Nt16 = 256; mb = swz & 7;  nb = swz >> 3; }
  else if (swz < 160) { int u = swz-128; Bh = WA+33554432; Bl = WA+37748736; C = kb; ldc = 1024; Nt16 = 64; mb = u & 7; nb = u >> 3; }
  else                { int u = swz-160; Bh = WA+41943040; Bl = WA+46137344; C = vb; ldc = 1024; Nt16 = 64; mb = u & 7; nb = u >> 3; }
  gemm256_core<4, false>(XAh, XAl, Bh, Bl, C, nullptr, nullptr, ldc, Nt16, mb, nb, 0, 192, L);
}

// ---- OUT: 256 blocks, K-split x2, add pass ----
__global__ __launch_bounds__(512) void gemm_out2(
    const u16* __restrict__ ABh, const u16* __restrict__ ABl,
    const u16* __restrict__ WOh, const u16* __restrict__ WOl,
    float* __restrict__ outp, float* __restrict__ c2)
{
  __shared__ __attribute__((aligned(16))) u16 L[65536];
  int id = blockIdx.x;
  int swz = (id & 7) * 32 + (id >> 3);
  int u = swz & 127, s = swz >> 7;
  int mb = u & 7, nb = u >> 3;
  gemm256_core<4, false>(ABh, ABl, WOh, WOl, s ? c2 : outp, nullptr, nullptr,
                         4096, 256, mb, nb, s*96, 96, L);
}

__global__ __launch_bounds__(256) void add_out(
    float* __restrict__ o, const float* __restrict__ c2)
{
  int i = blockIdx.x * 256 + threadIdx.x;
  float4 a = reinterpret_cast<float4*>(o)[i];
  float4 b = reinterpret_cast<const float4*>(c2)[i];
  a.x += b.x; a.y += b.y; a.z += b.z; a.w += b.w;
  reinterpret_cast<float4*>(o)[i] = a;
}

// ===========================================================================
// frag_kv (verified): post-GEMM K,V -> fragment planes, K-RoPE fused.
// ===========================================================================
__global__ __launch_bounds__(256) void frag_kv(
    const float* __restrict__ kb, const float* __restrict__ vb,
    const float* __restrict__ cosT, const float* __restrict__ sinT,
    u16* __restrict__ KFh, u16* __restrict__ KFl,
    u16* __restrict__ VFh, u16* __restrict__ VFl)
{
  __shared__ float T[32][132];
  const int bid  = blockIdx.x;
  const int isV  = bid >> 9;
  const int bkvh = (bid >> 5) & 15;
  const int chnk = bid & 31;
  const int tid  = threadIdx.x;
  const int b    = bkvh >> 3, kvh = bkvh & 7;

  const float* src = isV ? vb : kb;
  {
    int r0 = tid >> 5, c4 = (tid & 31) * 4;
    float sgn = (c4 < 64) ? -1.f : 1.f;
#pragma unroll
    for (int it = 0; it < 4; ++it) {
      int row = r0 + it * 8;
      int srow = chnk*32 + row;
      const float* rp = &src[(((size_t)(b * S_ + srow)) * HKV_ + kvh) * HD_];
      float4 v = *reinterpret_cast<const float4*>(rp + c4);
      if (!isV) {
        float4 p  = *reinterpret_cast<const float4*>(rp + (c4 ^ 64));
        float4 cc = *reinterpret_cast<const float4*>(&cosT[((size_t)(b*S_ + srow))*HD_ + c4]);
        float4 ss = *reinterpret_cast<const float4*>(&sinT[((size_t)(b*S_ + srow))*HD_ + c4]);
        v.x = v.x*cc.x + sgn*p.x*ss.x;
        v.y = v.y*cc.y + sgn*p.y*ss.y;
        v.z = v.z*cc.z + sgn*p.z*ss.z;
        v.w = v.w*cc.w + sgn*p.w*ss.w;
      }
      *reinterpret_cast<float4*>(&T[row][c4]) = v;
    }
  }
  __syncthreads();
#pragma unroll
  for (int rep = 0; rep < 2; ++rep) {
    int c2 = tid + rep * 256;
    int l = c2 & 63;
    u16 hh[8], ll[8];
    if (!isV) {
      int f = c2 >> 6, st_loc = f >> 2, dt = f & 3;
#pragma unroll
      for (int j = 0; j < 8; ++j)
        split2(T[st_loc*16 + (l & 15)][dt*32 + (l >> 4)*8 + j], hh[j], ll[j]);
      size_t off = ((size_t)bkvh*64 + chnk*2) * 2048 + (size_t)c2 * 8;
      *reinterpret_cast<s16x8*>(&KFh[off]) =
        (s16x8){(short)hh[0],(short)hh[1],(short)hh[2],(short)hh[3],
                (short)hh[4],(short)hh[5],(short)hh[6],(short)hh[7]};
      *reinterpret_cast<s16x8*>(&KFl[off]) =
        (s16x8){(short)ll[0],(short)ll[1],(short)ll[2],(short)ll[3],
                (short)ll[4],(short)ll[5],(short)ll[6],(short)ll[7]};
    } else {
      int dt16 = c2 >> 6;
#pragma unroll
      for (int j = 0; j < 8; ++j)
        split2(T[(l >> 4)*8 + j][dt16*16 + (l & 15)], hh[j], ll[j]);
      size_t off = ((size_t)bkvh*32 + chnk) * 4096 + (size_t)c2 * 8;
      *reinterpret_cast<s16x8*>(&VFh[off]) =
        (s16x8){(short)hh[0],(short)hh[1],(short)hh[2],(short)hh[3],
                (short)hh[4],(short)hh[5],(short)hh[6],(short)hh[7]};
      *reinterpret_cast<s16x8*>(&VFl[off]) =
        (s16x8){(short)ll[0],(short)ll[1],(short)ll[2],(short)ll[3],
                (short)ll[4],(short)ll[5],(short)ll[6],(short)ll[7]};
    }
  }
}

// ===========================================================================
// attn3 (verified): fragment-staged flash attention, Q-RoPE fused.
// ===========================================================================
__global__ __launch_bounds__(512) void attn3(
    const float* __restrict__ qb,
    const float* __restrict__ cosT, const float* __restrict__ sinT,
    const u16* __restrict__ KFh, const u16* __restrict__ KFl,
    const u16* __restrict__ VFh, const u16* __restrict__ VFl,
    float* __restrict__ ob)
{
  __shared__ __attribute__((aligned(16))) u16 Klds[16384];
  __shared__ __attribute__((aligned(16))) u16 Vlds[16384];
  __shared__ u16 Ph[8][16][68], Pl[8][16][68];

  const int tid  = threadIdx.x;
  const int lane = tid & 63;
  const int wid  = tid >> 6;
  const int lr   = lane & 15;
  const int lg   = lane >> 4;
  const int loff = lane * 8;
  const int qt   = blockIdx.x;
  const int bh   = blockIdx.y;
  const int b    = bh >> 5, h = bh & 31;
  const int bkvh = b * 8 + (h >> 2);

  s16x8 qh[4], ql[4];
  {
    const int qrow = qt * 128 + wid * 16 + lr;
    const float* qp = qb + ((size_t)((b * S_ + qrow) * HQ_ + h)) * HD_;
    const float* cp = cosT + ((size_t)(b * S_ + qrow)) * HD_;
    const float* sp = sinT + ((size_t)(b * S_ + qrow)) * HD_;
#pragma unroll
    for (int kc = 0; kc < 4; ++kc) {
      const int d0 = kc * 32 + lg * 8;
      const float sgn = (d0 < 64) ? -1.f : 1.f;
      float4 v0 = *reinterpret_cast<const float4*>(qp + d0);
      float4 v1 = *reinterpret_cast<const float4*>(qp + d0 + 4);
      float4 p0 = *reinterpret_cast<const float4*>(qp + (d0 ^ 64));
      float4 p1 = *reinterpret_cast<const float4*>(qp + (d0 ^ 64) + 4);
      float4 c0 = *reinterpret_cast<const float4*>(cp + d0);
      float4 c1 = *reinterpret_cast<const float4*>(cp + d0 + 4);
      float4 s0 = *reinterpret_cast<const float4*>(sp + d0);
      float4 s1 = *reinterpret_cast<const float4*>(sp + d0 + 4);
      float4 r0, r1;
      r0.x = v0.x*c0.x + sgn*p0.x*s0.x;  r0.y = v0.y*c0.y + sgn*p0.y*s0.y;
      r0.z = v0.z*c0.z + sgn*p0.z*s0.z;  r0.w = v0.w*c0.w + sgn*p0.w*s0.w;
      r1.x = v1.x*c1.x + sgn*p1.x*s1.x;  r1.y = v1.y*c1.y + sgn*p1.y*s1.y;
      r1.z = v1.z*c1.z + sgn*p1.z*s1.z;  r1.w = v1.w*c1.w + sgn*p1.w*s1.w;
      uint4 h4, l4; pack8(r0, r1, h4, l4);
      qh[kc] = *reinterpret_cast<s16x8*>(&h4);
      ql[kc] = *reinterpret_cast<s16x8*>(&l4);
    }
  }

  f32x4 acc_o[8];
#pragma unroll
  for (int df = 0; df < 8; ++df) acc_o[df] = (f32x4){0.f, 0.f, 0.f, 0.f};
  float m_run[4] = {-1e30f, -1e30f, -1e30f, -1e30f};
  float l_run[4] = {0.f, 0.f, 0.f, 0.f};

  const u16* gKh = KFh + (size_t)bkvh * 131072;
  const u16* gKl = KFl + (size_t)bkvh * 131072;
  const u16* gVh = VFh + (size_t)bkvh * 131072;
  const u16* gVl = VFl + (size_t)bkvh * 131072;

#pragma unroll
  for (int i = 0; i < 4; ++i) {
    int idx = wid * 4 + i;
    const u16* src = (idx < 16) ? (gKh + idx*512) : (gKl + (idx-16)*512);
    u16* dst = Klds + ((idx < 16) ? idx*512 : 8192 + (idx-16)*512);
    gload_lds16(src + loff, dst);
  }
  __syncthreads();

  for (int t = 0; t < 16; ++t) {
#pragma unroll
    for (int i = 0; i < 4; ++i) {
      int idx = wid * 4 + i;
      const u16* src = (idx < 16) ? (gVh + t*8192 + idx*512)
                                  : (gVl + t*8192 + (idx-16)*512);
      u16* dst = Vlds + ((idx < 16) ? idx*512 : 8192 + (idx-16)*512);
      gload_lds16(src + loff, dst);
    }

    f32x4 accs[4];
#pragma unroll
    for (int nf = 0; nf < 4; ++nf) {
      accs[nf] = (f32x4){0.f, 0.f, 0.f, 0.f};
      s16x8 kh8[4], kl8[4];
#pragma unroll
      for (int kc = 0; kc < 4; ++kc) {
        kh8[kc] = *reinterpret_cast<const s16x8*>(&Klds[nf*2048 + kc*512 + loff]);
        kl8[kc] = *reinterpret_cast<const s16x8*>(&Klds[8192 + nf*2048 + kc*512 + loff]);
      }
#pragma unroll
      for (int kc = 0; kc < 4; ++kc) {
        accs[nf] = MFMA(qh[kc], kh8[kc], accs[nf]);
        accs[nf] = MFMA(ql[kc], kh8[kc], accs[nf]);
        accs[nf] = MFMA(qh[kc], kl8[kc], accs[nf]);
      }
    }
#pragma unroll
    for (int nf = 0; nf < 4; ++nf) accs[nf] *= SCALE_;

    float corr[4], rsum[4];
#pragma unroll
    for (int r = 0; r < 4; ++r) {
      float t0 = fmaxf(fmaxf(accs[0][r], accs[1][r]), fmaxf(accs[2][r], accs[3][r]));
      t0 = fmaxf(t0, __shfl_xor(t0, 1));
      t0 = fmaxf(t0, __shfl_xor(t0, 2));
      t0 = fmaxf(t0, __shfl_xor(t0, 4));
      t0 = fmaxf(t0, __shfl_xor(t0, 8));
      float mnew = fmaxf(m_run[r], t0);
      corr[r] = __expf(m_run[r] - mnew);
      m_run[r] = mnew;
      rsum[r] = 0.f;
    }
#pragma unroll
    for (int nf = 0; nf < 4; ++nf)
#pragma unroll
      for (int r = 0; r < 4; ++r) {
        float p = __expf(accs[nf][r] - m_run[r]);
        rsum[r] += p;
        u16 ph, pl;
        split2(p, ph, pl);
        Ph[wid][lg*4 + r][nf*16 + lr] = ph;
        Pl[wid][lg*4 + r][nf*16 + lr] = pl;
      }
#pragma unroll
    for (int r = 0; r < 4; ++r) {
      float s = rsum[r];
      s += __shfl_xor(s, 1); s += __shfl_xor(s, 2);
      s += __shfl_xor(s, 4); s += __shfl_xor(s, 8);
      l_run[r] = l_run[r] * corr[r] + s;
    }
#pragma unroll
    for (int df = 0; df < 8; ++df)
#pragma unroll
      for (int r = 0; r < 4; ++r) acc_o[df][r] *= corr[r];

    __syncthreads();

    if (t < 15) {
#pragma unroll
      for (int i = 0; i < 4; ++i) {
        int idx = wid * 4 + i;
        const u16* src = (idx < 16) ? (gKh + (t+1)*8192 + idx*512)
                                    : (gKl + (t+1)*8192 + (idx-16)*512);
        u16* dst = Klds + ((idx < 16) ? idx*512 : 8192 + (idx-16)*512);
        gload_lds16(src + loff, dst);
      }
    }

    s16x8 pa_h[2], pa_l[2];
#pragma unroll
    for (int kc = 0; kc < 2; ++kc) {
      pa_h[kc] = *reinterpret_cast<const s16x8*>(&Ph[wid][lr][kc*32 + lg*8]);
      pa_l[kc] = *reinterpret_cast<const s16x8*>(&Pl[wid][lr][kc*32 + lg*8]);
    }
#pragma unroll
    for (int df = 0; df < 8; ++df) {
      s16x8 vh8[2], vl8[2];
#pragma unroll
      for (int kc = 0; kc < 2; ++kc) {
        vh8[kc] = *reinterpret_cast<const s16x8*>(&Vlds[kc*4096 + df*512 + loff]);
        vl8[kc] = *reinterpret_cast<const s16x8*>(&Vlds[8192 + kc*4096 + df*512 + loff]);
      }
#pragma unroll
      for (int kc = 0; kc < 2; ++kc) {
        acc_o[df] = MFMA(pa_h[kc], vh8[kc], acc_o[df]);
        acc_o[df] = MFMA(pa_l[kc], vh8[kc], acc_o[df]);
        acc_o[df] = MFMA(pa_h[kc], vl8[kc], acc_o[df]);
      }
    }
    __syncthreads();
  }

  float inv_l[4];
#pragma unroll
  for (int r = 0; r < 4; ++r) inv_l[r] = 1.f / l_run[r];
#pragma unroll
  for (int df = 0; df < 8; ++df)
#pragma unroll
    for (int r = 0; r < 4; ++r) {
      int row = qt * 128 + wid * 16 + lg * 4 + r;
      ob[((size_t)((b * S_ + row) * HQ_ + h)) * HD_ + df*16 + lr] = acc_o[df][r] * inv_l[r];
    }
}

// ---------------------------------------------------------------------------
extern "C" void kernel_launch(void* const* d_in, const int* in_sizes, int n_in,
                              void* d_out, int out_size, void* d_ws, size_t ws_size,
                              hipStream_t stream)
{
  const float* hs   = (const float*)d_in[0];
  const float* cosT = (const float*)d_in[1];
  const float* sinT = (const float*)d_in[2];
  const float* Wq   = (const float*)d_in[3];
  const float* Wk   = (const float*)d_in[4];
  const float* Wv   = (const float*)d_in[5];
  const float* Wo   = (const float*)d_in[6];
  float* out = (float*)d_out;

  float* qb = (float*)d_ws;                 // 8388608 f32
  float* kb = qb + 8388608;                 // 2097152
  float* vb = kb + 2097152;                 // 2097152
  float* ab = vb + 2097152;                 // 8388608
  u16*   FR = (u16*)(ab + 8388608);

  const size_t WS212 = 222298112ULL;        // base 84MB + XA 32MB + Wcat 96MB
  const size_t WS208 = 218103808ULL;        // round-8 tier (known present)

  if (ws_size >= WS212) {
    u16* XAh = FR;                          // 8388608 u16
    u16* XAl = FR + 8388608;
    u16* WBh = FR + 16777216;               // 25165824 u16 (concat N=6144 plane)
    u16* WBl = FR + 41943040;               // 25165824 u16
    // reuse regions (dead after gemm_qkv3):
    u16* KFh = FR + 16777216;               // 2097152 each
    u16* KFl = FR + 18874368;
    u16* VFh = FR + 20971520;
    u16* VFl = FR + 23068672;
    u16* WOh = FR + 25165824;               // 16777216
    u16* WOl = FR + 41943040;               // 16777216

    frag_a<<<dim3(64,16), 256, 0, stream>>>(hs, XAh, XAl);
    frag_b2<<<dim3(128,64), 256, 0, stream>>>(Wq, WBh, WBl, 4096, 0, 384, 0);
    frag_b2<<<dim3(128,16), 256, 0, stream>>>(Wk, WBh, WBl, 1024, 0, 384, 256);
    frag_b2<<<dim3(128,16), 256, 0, stream>>>(Wv, WBh, WBl, 1024, 0, 384, 320);
    gemm_qkv3<<<256, 512, 0, stream>>>(XAh, XAl, WBh, WBl, qb, kb, vb);
    frag_kv<<<1024, 256, 0, stream>>>(kb, vb, cosT, sinT, KFh, KFl, VFh, VFl);
    frag_b2<<<dim3(128,64), 256, 0, stream>>>(Wo, WOh, WOl, 4096, 0, 256, 0);
    attn3<<<dim3(8, 64), 512, 0, stream>>>(qb, cosT, sinT, KFh, KFl, VFh, VFl, ab);
    frag_a<<<dim3(64,16), 256, 0, stream>>>(ab, XAh, XAl);
    gemm_out2<<<256, 512, 0, stream>>>(XAh, XAl, WOh, WOl, out, qb);
    add_out<<<8192, 256, 0, stream>>>(out, qb);
  } else {
    // round-8 verified path (requires WS208, known present)
    u16* XAh = FR;
    u16* XAl = FR + 8388608;
    u16* WA  = FR + 16777216;
    frag_a<<<dim3(64,16), 256, 0, stream>>>(hs, XAh, XAl);
    frag_b2<<<dim3(128,64), 256, 0, stream>>>(Wq, WA,           WA+16777216, 4096, 0, 256, 0);
    frag_b2<<<dim3(128,16), 256, 0, stream>>>(Wk, WA+33554432,  WA+37748736, 1024, 0, 64, 0);
    frag_b2<<<dim3(128,16), 256, 0, stream>>>(Wv, WA+41943040,  WA+46137344, 1024, 0, 64, 0);
    gemm_qkv2<<<192, 512, 0, stream>>>(XAh, XAl, WA, qb, kb, vb);
    frag_kv<<<1024, 256, 0, stream>>>(kb, vb, cosT, sinT,
                                      WA, WA+2097152, WA+4194304, WA+6291456);
    frag_b2<<<dim3(128,64), 256, 0, stream>>>(Wo, WA+8388608, WA+25165824, 4096, 0, 256, 0);
    attn3<<<dim3(8, 64), 512, 0, stream>>>(qb, cosT, sinT,
                                           WA, WA+2097152, WA+4194304, WA+6291456, ab);
    frag_a<<<dim3(64,16), 256, 0, stream>>>(ab, XAh, XAl);
    gemm_out2<<<256, 512, 0, stream>>>(XAh, XAl, WA+8388608, WA+25165824, out, qb);
    add_out<<<8192, 256, 0, stream>>>(out, qb);
  }
}

// Round 10
// 642.655 us; speedup vs baseline: 1.6302x; 1.0745x over previous
//
#include <hip/hip_runtime.h>

#define B_   2
#define S_   1024
#define D_   4096
#define HQ_  32
#define HKV_ 8
#define HD_  128
#define SCALE_ 0.08838834764831845f

typedef unsigned short u16;
typedef __attribute__((ext_vector_type(8))) short s16x8;
typedef __attribute__((ext_vector_type(4))) short s16x4;
typedef __attribute__((ext_vector_type(4))) float f32x4;

#define MFMA(a,b,c) __builtin_amdgcn_mfma_f32_16x16x32_bf16((a),(b),(c),0,0,0)

__device__ __forceinline__ u16 bf16_rne(float x) {
  unsigned u = __float_as_uint(x);
  u += 0x7fffu + ((u >> 16) & 1u);
  return (u16)(u >> 16);
}
__device__ __forceinline__ float bf16_up(u16 h) {
  return __uint_as_float(((unsigned)h) << 16);
}
__device__ __forceinline__ void split2(float x, u16& h, u16& l) {
  h = bf16_rne(x);
  l = bf16_rne(x - bf16_up(h));
}

__device__ __forceinline__ void cvt_hi_lo(float a, float b, unsigned& hi, unsigned& lo) {
  unsigned h, l;
  asm("v_cvt_pk_bf16_f32 %0, %1, %2" : "=v"(h) : "v"(a), "v"(b));
  float ra = __uint_as_float(h << 16);
  float rb = __uint_as_float(h & 0xffff0000u);
  float la = a - ra, lb = b - rb;
  asm("v_cvt_pk_bf16_f32 %0, %1, %2" : "=v"(l) : "v"(la), "v"(lb));
  hi = h; lo = l;
}
__device__ __forceinline__ void pack8(float4 x, float4 y, uint4& h, uint4& l) {
  unsigned h0,h1,h2,h3,l0,l1,l2,l3;
  cvt_hi_lo(x.x, x.y, h0, l0);
  cvt_hi_lo(x.z, x.w, h1, l1);
  cvt_hi_lo(y.x, y.y, h2, l2);
  cvt_hi_lo(y.z, y.w, h3, l3);
  h = make_uint4(h0,h1,h2,h3); l = make_uint4(l0,l1,l2,l3);
}

typedef const __attribute__((address_space(1))) void* gas_ptr;
typedef __attribute__((address_space(3))) void* las_ptr;
__device__ __forceinline__ void gload_lds16(const void* g, void* l) {
  __builtin_amdgcn_global_load_lds((gas_ptr)g, (las_ptr)l, 16, 0, 0);
}

// ===========================================================================
// frag_b2 (verified): weights (K x N fp32) -> [kt64][nt-global][kk2][512].
// ===========================================================================
__global__ __launch_bounds__(256) void frag_b2(
    const float* __restrict__ W, u16* __restrict__ dh, u16* __restrict__ dl,
    int N, int n0, int Ntot16, int ntoff)
{
  __shared__ float T[32][68];
  const int kt = blockIdx.x, nbk = blockIdx.y;
  const int tid = threadIdx.x;
#pragma unroll
  for (int rep = 0; rep < 2; ++rep) {
    int idx = tid + rep * 256;
    int row = idx >> 4, c4 = (idx & 15) * 4;
    float4 v = *reinterpret_cast<const float4*>(&W[(size_t)(kt*32 + row) * N + n0 + nbk*64 + c4]);
    *reinterpret_cast<float4*>(&T[row][c4]) = v;
  }
  __syncthreads();
  int c = tid;
  int nt = c >> 6, l = c & 63;
  const size_t base = (((size_t)(kt >> 1) * Ntot16 + ntoff + nbk*4 + nt) * 2 + (kt & 1)) * 512;
  u16 hh[8], ll[8];
#pragma unroll
  for (int j = 0; j < 8; ++j) split2(T[(l >> 4)*8 + j][nt*16 + (l & 15)], hh[j], ll[j]);
  *reinterpret_cast<s16x8*>(&dh[base + (size_t)l * 8]) =
    (s16x8){(short)hh[0],(short)hh[1],(short)hh[2],(short)hh[3],
            (short)hh[4],(short)hh[5],(short)hh[6],(short)hh[7]};
  *reinterpret_cast<s16x8*>(&dl[base + (size_t)l * 8]) =
    (s16x8){(short)ll[0],(short)ll[1],(short)ll[2],(short)ll[3],
            (short)ll[4],(short)ll[5],(short)ll[6],(short)ll[7]};
}

// ===========================================================================
// frag_a (verified): A (M x 4096 fp32) -> [kt64][mt 128][kk2][512] planes.
// ===========================================================================
__global__ __launch_bounds__(256) void frag_a(
    const float* __restrict__ src, u16* __restrict__ dh, u16* __restrict__ dl)
{
  __shared__ float T[128][68];
  const int kt = blockIdx.x;
  const int mb = blockIdx.y;
  const int tid = threadIdx.x;
#pragma unroll
  for (int rep = 0; rep < 8; ++rep) {
    int idx = tid + rep * 256;
    int row = idx >> 4, c4 = (idx & 15) * 4;
    float4 v = *reinterpret_cast<const float4*>(&src[(size_t)(mb*128 + row) * 4096 + kt*64 + c4]);
    *reinterpret_cast<float4*>(&T[row][c4]) = v;
  }
  __syncthreads();
#pragma unroll
  for (int rep = 0; rep < 4; ++rep) {
    int c = tid + rep * 256;
    int mt = c >> 7, rem = c & 127, kk = rem >> 6, l = rem & 63;
    u16 hh[8], ll[8];
#pragma unroll
    for (int j = 0; j < 8; ++j)
      split2(T[mt*16 + (l & 15)][kk*32 + (l >> 4)*8 + j], hh[j], ll[j]);
    size_t off = (((size_t)(kt*128 + mb*8 + mt)) * 2 + kk) * 512 + (size_t)l * 8;
    *reinterpret_cast<s16x8*>(&dh[off]) =
      (s16x8){(short)hh[0],(short)hh[1],(short)hh[2],(short)hh[3],
              (short)hh[4],(short)hh[5],(short)hh[6],(short)hh[7]};
    *reinterpret_cast<s16x8*>(&dl[off]) =
      (s16x8){(short)ll[0],(short)ll[1],(short)ll[2],(short)ll[3],
              (short)ll[4],(short)ll[5],(short)ll[6],(short)ll[7]};
  }
}

// ===========================================================================
// gemm256_core<NF,RQ> v2: 256 x (NF*64) tile, 8 waves, BK=32 K-steps.
// Per step: stage ALL FOUR planes {Ah,Al,Bh,Bl} of tile t+1 (each plane
// fetched from global exactly ONCE), then 3 passes from tile t:
// AhBh, AlBh, AhBl (72*NF/3 MFMA per wave). One barrier per step.
// LDS: A dbuf 2x32KB + B dbuf 2x(NF*8KB) -> NF=3: 112KB, NF=4: 128KB.
// ===========================================================================
template<int NF, bool RQ>
__device__ __forceinline__ void gemm256_core(
    const u16* __restrict__ PAh, const u16* __restrict__ PAl,
    const u16* __restrict__ PBh, const u16* __restrict__ PBl,
    float* __restrict__ C0, float* __restrict__ C1, float* __restrict__ C2,
    int ldc0, int Nt16, int mb, int nb, int k0, int nk, u16* L)
{
  const int tid  = threadIdx.x;
  const int lane = tid & 63;
  const int wid  = tid >> 6;
  const int loff = lane * 8;
  const int wm8  = (wid >> 2) * 8;
  const int wnf  = (wid & 3) * NF;

  u16* A0 = L;                    // [16 mt][512] hi, +8192 lo
  u16* A1 = L + 16384;
  u16* B0 = L + 32768;            // [4NF nt][512] hi, +NF*2048 lo
  u16* B1 = L + 32768 + NF*4096;

  f32x4 acc[8][NF];
#pragma unroll
  for (int i = 0; i < 8; ++i)
#pragma unroll
    for (int j = 0; j < NF; ++j) acc[i][j] = (f32x4){0.f,0.f,0.f,0.f};

  auto STAGE = [&](int t, u16* la_, u16* lb_) {
    const int kt64 = t >> 1, kk = t & 1;
    const size_t aSlab = (size_t)kt64 * 131072;
    const size_t bSlab = (size_t)kt64 * ((size_t)Nt16 * 1024);
    const int NCH = 32 + 8*NF;
#pragma unroll
    for (int c = wid; c < NCH; c += 8) {
      const u16* src; u16* dst;
      if (c < 16) {
        src = PAh + aSlab + (((size_t)(mb*16 + c))*2 + kk)*512;
        dst = la_ + c*512;
      } else if (c < 32) {
        int m = c - 16;
        src = PAl + aSlab + (((size_t)(mb*16 + m))*2 + kk)*512;
        dst = la_ + 8192 + m*512;
      } else if (c < 32 + 4*NF) {
        int n = c - 32;
        src = PBh + bSlab + (((size_t)(nb*4*NF + n))*2 + kk)*512;
        dst = lb_ + n*512;
      } else {
        int n = c - 32 - 4*NF;
        src = PBl + bSlab + (((size_t)(nb*4*NF + n))*2 + kk)*512;
        dst = lb_ + NF*2048 + n*512;
      }
      gload_lds16(src + loff, dst);
    }
  };

  STAGE(k0, (k0 & 1) ? A1 : A0, (k0 & 1) ? B1 : B0);
  __syncthreads();

  for (int t = k0; t < k0 + nk; ++t) {
    u16* la = (t & 1) ? A1 : A0;
    u16* lb = (t & 1) ? B1 : B0;
    if (t + 1 < k0 + nk)
      STAGE(t + 1, (t & 1) ? A0 : A1, (t & 1) ? B0 : B1);

    s16x8 ah[8], al[8], bh[NF], bl[NF];
#pragma unroll
    for (int mf = 0; mf < 8; ++mf)
      ah[mf] = *reinterpret_cast<const s16x8*>(&la[(wm8+mf)*512 + loff]);
#pragma unroll
    for (int nf = 0; nf < NF; ++nf)
      bh[nf] = *reinterpret_cast<const s16x8*>(&lb[(wnf+nf)*512 + loff]);
    __builtin_amdgcn_s_setprio(1);
#pragma unroll
    for (int nf = 0; nf < NF; ++nf)
#pragma unroll
      for (int mf = 0; mf < 8; ++mf)
        acc[mf][nf] = MFMA(ah[mf], bh[nf], acc[mf][nf]);
    __builtin_amdgcn_s_setprio(0);
#pragma unroll
    for (int mf = 0; mf < 8; ++mf)
      al[mf] = *reinterpret_cast<const s16x8*>(&la[8192 + (wm8+mf)*512 + loff]);
    __builtin_amdgcn_s_setprio(1);
#pragma unroll
    for (int nf = 0; nf < NF; ++nf)
#pragma unroll
      for (int mf = 0; mf < 8; ++mf)
        acc[mf][nf] = MFMA(al[mf], bh[nf], acc[mf][nf]);
    __builtin_amdgcn_s_setprio(0);
#pragma unroll
    for (int nf = 0; nf < NF; ++nf)
      bl[nf] = *reinterpret_cast<const s16x8*>(&lb[NF*2048 + (wnf+nf)*512 + loff]);
    __builtin_amdgcn_s_setprio(1);
#pragma unroll
    for (int nf = 0; nf < NF; ++nf)
#pragma unroll
      for (int mf = 0; mf < 8; ++mf)
        acc[mf][nf] = MFMA(ah[mf], bl[nf], acc[mf][nf]);
    __builtin_amdgcn_s_setprio(0);
    __syncthreads();
  }

  const int lg = lane >> 4, lr = lane & 15;
  const int rowb = mb*256 + (wid >> 2) * 128;
#pragma unroll
  for (int mf = 0; mf < 8; ++mf)
#pragma unroll
    for (int nf = 0; nf < NF; ++nf)
#pragma unroll
      for (int r = 0; r < 4; ++r) {
        int row = rowb + mf*16 + lg*4 + r;
        float v = acc[mf][nf][r];
        if constexpr (RQ) {
          int gcol = nb*(NF*64) + (wid & 3)*(NF*16) + nf*16 + lr;
          if (gcol < 4096)      C0[(size_t)row * 4096 + gcol] = v;
          else if (gcol < 5120) C1[(size_t)row * 1024 + (gcol - 4096)] = v;
          else                  C2[(size_t)row * 1024 + (gcol - 5120)] = v;
        } else {
          int col = nb*(NF*64) + (wid & 3)*(NF*16) + nf*16 + lr;
          C0[(size_t)row * ldc0 + col] = v;
        }
      }
}

// ---- fused-N QKV, 256x192 tiles, 256 blocks ----
__global__ __launch_bounds__(512) void gemm_qkv3(
    const u16* __restrict__ XAh, const u16* __restrict__ XAl,
    const u16* __restrict__ WBh, const u16* __restrict__ WBl,
    float* __restrict__ qb, float* __restrict__ kb, float* __restrict__ vb)
{
  __shared__ __attribute__((aligned(16))) u16 L[57344];
  int id = blockIdx.x;
  int swz = (id & 7) * 32 + (id >> 3);
  int mb = swz >> 5, nb = swz & 31;
  gemm256_core<3, true>(XAh, XAl, WBh, WBl, qb, kb, vb, 0, 384, mb, nb, 0, 128, L);
}

// ---- round-8 layout QKV (fallback tier) ----
__global__ __launch_bounds__(512) void gemm_qkv2(
    const u16* __restrict__ XAh, const u16* __restrict__ XAl,
    const u16* __restrict__ WA,
    float* __restrict__ qb, float* __restrict__ kb, float* __restrict__ vb)
{
  __shared__ __attribute__((aligned(16))) u16 L[65536];
  int id = blockIdx.x;
  int swz = (id & 7) * 24 + (id >> 3);
  const u16 *Bh, *Bl; float* C; int ldc, Nt16, mb, nb;
  if (swz < 128)      { Bh = WA;          Bl = WA+16777216; C = qb; ldc = 4096; Nt16 = 256; mb = swz & 7;  nb = swz >> 3; }
  else if (swz < 160) { int u = swz-128; Bh = WA+33554432; Bl = WA+37748736; C = kb; ldc = 1024; Nt16 = 64; mb = u & 7; nb = u >> 3; }
  else                { int u = swz-160; Bh = WA+41943040; Bl = WA+46137344; C = vb; ldc = 1024; Nt16 = 64; mb = u & 7; nb = u >> 3; }
  gemm256_core<4, false>(XAh, XAl, Bh, Bl, C, nullptr, nullptr, ldc, Nt16, mb, nb, 0, 128, L);
}

// ---- OUT: 256 blocks, K-split x2, add pass ----
__global__ __launch_bounds__(512) void gemm_out2(
    const u16* __restrict__ ABh, const u16* __restrict__ ABl,
    const u16* __restrict__ WOh, const u16* __restrict__ WOl,
    float* __restrict__ outp, float* __restrict__ c2)
{
  __shared__ __attribute__((aligned(16))) u16 L[65536];
  int id = blockIdx.x;
  int swz = (id & 7) * 32 + (id >> 3);
  int u = swz & 127, s = swz >> 7;
  int mb = u & 7, nb = u >> 3;
  gemm256_core<4, false>(ABh, ABl, WOh, WOl, s ? c2 : outp, nullptr, nullptr,
                         4096, 256, mb, nb, s*64, 64, L);
}

__global__ __launch_bounds__(256) void add_out(
    float* __restrict__ o, const float* __restrict__ c2)
{
  int i = blockIdx.x * 256 + threadIdx.x;
  float4 a = reinterpret_cast<float4*>(o)[i];
  float4 b = reinterpret_cast<const float4*>(c2)[i];
  a.x += b.x; a.y += b.y; a.z += b.z; a.w += b.w;
  reinterpret_cast<float4*>(o)[i] = a;
}

// ===========================================================================
// frag_kv (verified): post-GEMM K,V -> fragment planes, K-RoPE fused.
// ===========================================================================
__global__ __launch_bounds__(256) void frag_kv(
    const float* __restrict__ kb, const float* __restrict__ vb,
    const float* __restrict__ cosT, const float* __restrict__ sinT,
    u16* __restrict__ KFh, u16* __restrict__ KFl,
    u16* __restrict__ VFh, u16* __restrict__ VFl)
{
  __shared__ float T[32][132];
  const int bid  = blockIdx.x;
  const int isV  = bid >> 9;
  const int bkvh = (bid >> 5) & 15;
  const int chnk = bid & 31;
  const int tid  = threadIdx.x;
  const int b    = bkvh >> 3, kvh = bkvh & 7;

  const float* src = isV ? vb : kb;
  {
    int r0 = tid >> 5, c4 = (tid & 31) * 4;
    float sgn = (c4 < 64) ? -1.f : 1.f;
#pragma unroll
    for (int it = 0; it < 4; ++it) {
      int row = r0 + it * 8;
      int srow = chnk*32 + row;
      const float* rp = &src[(((size_t)(b * S_ + srow)) * HKV_ + kvh) * HD_];
      float4 v = *reinterpret_cast<const float4*>(rp + c4);
      if (!isV) {
        float4 p  = *reinterpret_cast<const float4*>(rp + (c4 ^ 64));
        float4 cc = *reinterpret_cast<const float4*>(&cosT[((size_t)(b*S_ + srow))*HD_ + c4]);
        float4 ss = *reinterpret_cast<const float4*>(&sinT[((size_t)(b*S_ + srow))*HD_ + c4]);
        v.x = v.x*cc.x + sgn*p.x*ss.x;
        v.y = v.y*cc.y + sgn*p.y*ss.y;
        v.z = v.z*cc.z + sgn*p.z*ss.z;
        v.w = v.w*cc.w + sgn*p.w*ss.w;
      }
      *reinterpret_cast<float4*>(&T[row][c4]) = v;
    }
  }
  __syncthreads();
#pragma unroll
  for (int rep = 0; rep < 2; ++rep) {
    int c2 = tid + rep * 256;
    int l = c2 & 63;
    u16 hh[8], ll[8];
    if (!isV) {
      int f = c2 >> 6, st_loc = f >> 2, dt = f & 3;
#pragma unroll
      for (int j = 0; j < 8; ++j)
        split2(T[st_loc*16 + (l & 15)][dt*32 + (l >> 4)*8 + j], hh[j], ll[j]);
      size_t off = ((size_t)bkvh*64 + chnk*2) * 2048 + (size_t)c2 * 8;
      *reinterpret_cast<s16x8*>(&KFh[off]) =
        (s16x8){(short)hh[0],(short)hh[1],(short)hh[2],(short)hh[3],
                (short)hh[4],(short)hh[5],(short)hh[6],(short)hh[7]};
      *reinterpret_cast<s16x8*>(&KFl[off]) =
        (s16x8){(short)ll[0],(short)ll[1],(short)ll[2],(short)ll[3],
                (short)ll[4],(short)ll[5],(short)ll[6],(short)ll[7]};
    } else {
      int dt16 = c2 >> 6;
#pragma unroll
      for (int j = 0; j < 8; ++j)
        split2(T[(l >> 4)*8 + j][dt16*16 + (l & 15)], hh[j], ll[j]);
      size_t off = ((size_t)bkvh*32 + chnk) * 4096 + (size_t)c2 * 8;
      *reinterpret_cast<s16x8*>(&VFh[off]) =
        (s16x8){(short)hh[0],(short)hh[1],(short)hh[2],(short)hh[3],
                (short)hh[4],(short)hh[5],(short)hh[6],(short)hh[7]};
      *reinterpret_cast<s16x8*>(&VFl[off]) =
        (s16x8){(short)ll[0],(short)ll[1],(short)ll[2],(short)ll[3],
                (short)ll[4],(short)ll[5],(short)ll[6],(short)ll[7]};
    }
  }
}

// ===========================================================================
// attn3 (verified): fragment-staged flash attention, Q-RoPE fused.
// ===========================================================================
__global__ __launch_bounds__(512) void attn3(
    const float* __restrict__ qb,
    const float* __restrict__ cosT, const float* __restrict__ sinT,
    const u16* __restrict__ KFh, const u16* __restrict__ KFl,
    const u16* __restrict__ VFh, const u16* __restrict__ VFl,
    float* __restrict__ ob)
{
  __shared__ __attribute__((aligned(16))) u16 Klds[16384];
  __shared__ __attribute__((aligned(16))) u16 Vlds[16384];
  __shared__ u16 Ph[8][16][68], Pl[8][16][68];

  const int tid  = threadIdx.x;
  const int lane = tid & 63;
  const int wid  = tid >> 6;
  const int lr   = lane & 15;
  const int lg   = lane >> 4;
  const int loff = lane * 8;
  const int qt   = blockIdx.x;
  const int bh   = blockIdx.y;
  const int b    = bh >> 5, h = bh & 31;
  const int bkvh = b * 8 + (h >> 2);

  s16x8 qh[4], ql[4];
  {
    const int qrow = qt * 128 + wid * 16 + lr;
    const float* qp = qb + ((size_t)((b * S_ + qrow) * HQ_ + h)) * HD_;
    const float* cp = cosT + ((size_t)(b * S_ + qrow)) * HD_;
    const float* sp = sinT + ((size_t)(b * S_ + qrow)) * HD_;
#pragma unroll
    for (int kc = 0; kc < 4; ++kc) {
      const int d0 = kc * 32 + lg * 8;
      const float sgn = (d0 < 64) ? -1.f : 1.f;
      float4 v0 = *reinterpret_cast<const float4*>(qp + d0);
      float4 v1 = *reinterpret_cast<const float4*>(qp + d0 + 4);
      float4 p0 = *reinterpret_cast<const float4*>(qp + (d0 ^ 64));
      float4 p1 = *reinterpret_cast<const float4*>(qp + (d0 ^ 64) + 4);
      float4 c0 = *reinterpret_cast<const float4*>(cp + d0);
      float4 c1 = *reinterpret_cast<const float4*>(cp + d0 + 4);
      float4 s0 = *reinterpret_cast<const float4*>(sp + d0);
      float4 s1 = *reinterpret_cast<const float4*>(sp + d0 + 4);
      float4 r0, r1;
      r0.x = v0.x*c0.x + sgn*p0.x*s0.x;  r0.y = v0.y*c0.y + sgn*p0.y*s0.y;
      r0.z = v0.z*c0.z + sgn*p0.z*s0.z;  r0.w = v0.w*c0.w + sgn*p0.w*s0.w;
      r1.x = v1.x*c1.x + sgn*p1.x*s1.x;  r1.y = v1.y*c1.y + sgn*p1.y*s1.y;
      r1.z = v1.z*c1.z + sgn*p1.z*s1.z;  r1.w = v1.w*c1.w + sgn*p1.w*s1.w;
      uint4 h4, l4; pack8(r0, r1, h4, l4);
      qh[kc] = *reinterpret_cast<s16x8*>(&h4);
      ql[kc] = *reinterpret_cast<s16x8*>(&l4);
    }
  }

  f32x4 acc_o[8];
#pragma unroll
  for (int df = 0; df < 8; ++df) acc_o[df] = (f32x4){0.f, 0.f, 0.f, 0.f};
  float m_run[4] = {-1e30f, -1e30f, -1e30f, -1e30f};
  float l_run[4] = {0.f, 0.f, 0.f, 0.f};

  const u16* gKh = KFh + (size_t)bkvh * 131072;
  const u16* gKl = KFl + (size_t)bkvh * 131072;
  const u16* gVh = VFh + (size_t)bkvh * 131072;
  const u16* gVl = VFl + (size_t)bkvh * 131072;

#pragma unroll
  for (int i = 0; i < 4; ++i) {
    int idx = wid * 4 + i;
    const u16* src = (idx < 16) ? (gKh + idx*512) : (gKl + (idx-16)*512);
    u16* dst = Klds + ((idx < 16) ? idx*512 : 8192 + (idx-16)*512);
    gload_lds16(src + loff, dst);
  }
  __syncthreads();

  for (int t = 0; t < 16; ++t) {
#pragma unroll
    for (int i = 0; i < 4; ++i) {
      int idx = wid * 4 + i;
      const u16* src = (idx < 16) ? (gVh + t*8192 + idx*512)
                                  : (gVl + t*8192 + (idx-16)*512);
      u16* dst = Vlds + ((idx < 16) ? idx*512 : 8192 + (idx-16)*512);
      gload_lds16(src + loff, dst);
    }

    f32x4 accs[4];
#pragma unroll
    for (int nf = 0; nf < 4; ++nf) {
      accs[nf] = (f32x4){0.f, 0.f, 0.f, 0.f};
      s16x8 kh8[4], kl8[4];
#pragma unroll
      for (int kc = 0; kc < 4; ++kc) {
        kh8[kc] = *reinterpret_cast<const s16x8*>(&Klds[nf*2048 + kc*512 + loff]);
        kl8[kc] = *reinterpret_cast<const s16x8*>(&Klds[8192 + nf*2048 + kc*512 + loff]);
      }
#pragma unroll
      for (int kc = 0; kc < 4; ++kc) {
        accs[nf] = MFMA(qh[kc], kh8[kc], accs[nf]);
        accs[nf] = MFMA(ql[kc], kh8[kc], accs[nf]);
        accs[nf] = MFMA(qh[kc], kl8[kc], accs[nf]);
      }
    }
#pragma unroll
    for (int nf = 0; nf < 4; ++nf) accs[nf] *= SCALE_;

    float corr[4], rsum[4];
#pragma unroll
    for (int r = 0; r < 4; ++r) {
      float t0 = fmaxf(fmaxf(accs[0][r], accs[1][r]), fmaxf(accs[2][r], accs[3][r]));
      t0 = fmaxf(t0, __shfl_xor(t0, 1));
      t0 = fmaxf(t0, __shfl_xor(t0, 2));
      t0 = fmaxf(t0, __shfl_xor(t0, 4));
      t0 = fmaxf(t0, __shfl_xor(t0, 8));
      float mnew = fmaxf(m_run[r], t0);
      corr[r] = __expf(m_run[r] - mnew);
      m_run[r] = mnew;
      rsum[r] = 0.f;
    }
#pragma unroll
    for (int nf = 0; nf < 4; ++nf)
#pragma unroll
      for (int r = 0; r < 4; ++r) {
        float p = __expf(accs[nf][r] - m_run[r]);
        rsum[r] += p;
        u16 ph, pl;
        split2(p, ph, pl);
        Ph[wid][lg*4 + r][nf*16 + lr] = ph;
        Pl[wid][lg*4 + r][nf*16 + lr] = pl;
      }
#pragma unroll
    for (int r = 0; r < 4; ++r) {
      float s = rsum[r];
      s += __shfl_xor(s, 1); s += __shfl_xor(s, 2);
      s += __shfl_xor(s, 4); s += __shfl_xor(s, 8);
      l_run[r] = l_run[r] * corr[r] + s;
    }
#pragma unroll
    for (int df = 0; df < 8; ++df)
#pragma unroll
      for (int r = 0; r < 4; ++r) acc_o[df][r] *= corr[r];

    __syncthreads();

    if (t < 15) {
#pragma unroll
      for (int i = 0; i < 4; ++i) {
        int idx = wid * 4 + i;
        const u16* src = (idx < 16) ? (gKh + (t+1)*8192 + idx*512)
                                    : (gKl + (t+1)*8192 + (idx-16)*512);
        u16* dst = Klds + ((idx < 16) ? idx*512 : 8192 + (idx-16)*512);
        gload_lds16(src + loff, dst);
      }
    }

    s16x8 pa_h[2], pa_l[2];
#pragma unroll
    for (int kc = 0; kc < 2; ++kc) {
      pa_h[kc] = *reinterpret_cast<const s16x8*>(&Ph[wid][lr][kc*32 + lg*8]);
      pa_l[kc] = *reinterpret_cast<const s16x8*>(&Pl[wid][lr][kc*32 + lg*8]);
    }
#pragma unroll
    for (int df = 0; df < 8; ++df) {
      s16x8 vh8[2], vl8[2];
#pragma unroll
      for (int kc = 0; kc < 2; ++kc) {
        vh8[kc] = *reinterpret_cast<const s16x8*>(&Vlds[kc*4096 + df*512 + loff]);
        vl8[kc] = *reinterpret_cast<const s16x8*>(&Vlds[8192 + kc*4096 + df*512 + loff]);
      }
#pragma unroll
      for (int kc = 0; kc < 2; ++kc) {
        acc_o[df] = MFMA(pa_h[kc], vh8[kc], acc_o[df]);
        acc_o[df] = MFMA(pa_l[kc], vh8[kc], acc_o[df]);
        acc_o[df] = MFMA(pa_h[kc], vl8[kc], acc_o[df]);
      }
    }
    __syncthreads();
  }

  float inv_l[4];
#pragma unroll
  for (int r = 0; r < 4; ++r) inv_l[r] = 1.f / l_run[r];
#pragma unroll
  for (int df = 0; df < 8; ++df)
#pragma unroll
    for (int r = 0; r < 4; ++r) {
      int row = qt * 128 + wid * 16 + lg * 4 + r;
      ob[((size_t)((b * S_ + row) * HQ_ + h)) * HD_ + df*16 + lr] = acc_o[df][r] * inv_l[r];
    }
}

// ---------------------------------------------------------------------------
extern "C" void kernel_launch(void* const* d_in, const int* in_sizes, int n_in,
                              void* d_out, int out_size, void* d_ws, size_t ws_size,
                              hipStream_t stream)
{
  const float* hs   = (const float*)d_in[0];
  const float* cosT = (const float*)d_in[1];
  const float* sinT = (const float*)d_in[2];
  const float* Wq   = (const float*)d_in[3];
  const float* Wk   = (const float*)d_in[4];
  const float* Wv   = (const float*)d_in[5];
  const float* Wo   = (const float*)d_in[6];
  float* out = (float*)d_out;

  float* qb = (float*)d_ws;                 // 8388608 f32
  float* kb = qb + 8388608;                 // 2097152
  float* vb = kb + 2097152;                 // 2097152
  float* ab = vb + 2097152;                 // 8388608
  u16*   FR = (u16*)(ab + 8388608);

  const size_t WS212 = 222298112ULL;
  const size_t WS208 = 218103808ULL;

  if (ws_size >= WS212) {
    u16* XAh = FR;
    u16* XAl = FR + 8388608;
    u16* WBh = FR + 16777216;
    u16* WBl = FR + 41943040;
    u16* KFh = FR + 16777216;
    u16* KFl = FR + 18874368;
    u16* VFh = FR + 20971520;
    u16* VFl = FR + 23068672;
    u16* WOh = FR + 25165824;
    u16* WOl = FR + 41943040;

    frag_a<<<dim3(64,16), 256, 0, stream>>>(hs, XAh, XAl);
    frag_b2<<<dim3(128,64), 256, 0, stream>>>(Wq, WBh, WBl, 4096, 0, 384, 0);
    frag_b2<<<dim3(128,16), 256, 0, stream>>>(Wk, WBh, WBl, 1024, 0, 384, 256);
    frag_b2<<<dim3(128,16), 256, 0, stream>>>(Wv, WBh, WBl, 1024, 0, 384, 320);
    gemm_qkv3<<<256, 512, 0, stream>>>(XAh, XAl, WBh, WBl, qb, kb, vb);
    frag_kv<<<1024, 256, 0, stream>>>(kb, vb, cosT, sinT, KFh, KFl, VFh, VFl);
    frag_b2<<<dim3(128,64), 256, 0, stream>>>(Wo, WOh, WOl, 4096, 0, 256, 0);
    attn3<<<dim3(8, 64), 512, 0, stream>>>(qb, cosT, sinT, KFh, KFl, VFh, VFl, ab);
    frag_a<<<dim3(64,16), 256, 0, stream>>>(ab, XAh, XAl);
    gemm_out2<<<256, 512, 0, stream>>>(XAh, XAl, WOh, WOl, out, qb);
    add_out<<<8192, 256, 0, stream>>>(out, qb);
  } else {
    u16* XAh = FR;
    u16* XAl = FR + 8388608;
    u16* WA  = FR + 16777216;
    frag_a<<<dim3(64,16), 256, 0, stream>>>(hs, XAh, XAl);
    frag_b2<<<dim3(128,64), 256, 0, stream>>>(Wq, WA,           WA+16777216, 4096, 0, 256, 0);
    frag_b2<<<dim3(128,16), 256, 0, stream>>>(Wk, WA+33554432,  WA+37748736, 1024, 0, 64, 0);
    frag_b2<<<dim3(128,16), 256, 0, stream>>>(Wv, WA+41943040,  WA+46137344, 1024, 0, 64, 0);
    gemm_qkv2<<<192, 512, 0, stream>>>(XAh, XAl, WA, qb, kb, vb);
    frag_kv<<<1024, 256, 0, stream>>>(kb, vb, cosT, sinT,
                                      WA, WA+2097152, WA+4194304, WA+6291456);
    frag_b2<<<dim3(128,64), 256, 0, stream>>>(Wo, WA+8388608, WA+25165824, 4096, 0, 256, 0);
    attn3<<<dim3(8, 64), 512, 0, stream>>>(qb, cosT, sinT,
                                           WA, WA+2097152, WA+4194304, WA+6291456, ab);
    frag_a<<<dim3(64,16), 256, 0, stream>>>(ab, XAh, XAl);
    gemm_out2<<<256, 512, 0, stream>>>(XAh, XAl, WA+8388608, WA+25165824, out, qb);
    add_out<<<8192, 256, 0, stream>>>(out, qb);
  }
}